// Round 1
// baseline (2338.732 us; speedup 1.0000x reference)
//
#include <hip/hip_runtime.h>
#include <hip/hip_bf16.h>
#include <math.h>

#define NEGV -1000000000.0f

static constexpr int B_ = 16, N_ = 128, BN_ = 2048;
static constexpr int E_ = 384, H_ = 512, D_ = 512, A_ = 512, P_ = 128, V_ = 8000;

// ---------------- workspace layout (float offsets) ----------------
static constexpr size_t OFF_X     = 0;                                  // [2048][384]
static constexpr size_t SZ_X      = (size_t)BN_ * E_;
static constexpr size_t OFF_XPROJ = OFF_X + SZ_X;                       // 3 x [2048][2048]
static constexpr size_t SZ_XP1    = (size_t)BN_ * 2048;
static constexpr size_t OFF_EHS   = OFF_XPROJ + 3 * SZ_XP1;             // [2048][1024]
static constexpr size_t SZ_EHS    = (size_t)BN_ * 1024;
static constexpr size_t OFF_CAT   = OFF_EHS + SZ_EHS;                   // [2048][1536] dec_h | context
static constexpr size_t SZ_CAT    = (size_t)BN_ * 1536;
static constexpr size_t OFF_DT    = OFF_CAT + SZ_CAT;                   // [2048][512]
static constexpr size_t OFF_ET    = OFF_DT + (size_t)BN_ * 512;         // [2048][512]
static constexpr size_t OFF_CB    = OFF_ET + (size_t)BN_ * 512;         // [2048][512]
static constexpr size_t OFF_WGO   = OFF_CB + (size_t)BN_ * 512;         // [2048][512]
static constexpr size_t OFF_BASE  = OFF_WGO + (size_t)BN_ * 512;        // [2048][128]
static constexpr size_t OFF_HBUF  = OFF_BASE + (size_t)BN_ * 128;       // [3][2][16][512]
static constexpr size_t SZ_HBUF   = (size_t)3 * 2 * 16 * 512;
static constexpr size_t OFF_CNT   = OFF_HBUF + SZ_HBUF;                 // 384 ints

// ---------------- helpers ----------------
__device__ inline float wave_sum(float v) {
#pragma unroll
  for (int o = 32; o; o >>= 1) v += __shfl_xor(v, o);
  return v;
}
__device__ inline float wave_max(float v) {
#pragma unroll
  for (int o = 32; o; o >>= 1) v = fmaxf(v, __shfl_xor(v, o));
  return v;
}
__device__ inline float fast_tanh(float x) {
  // tanh(x) = 1 - 2/(1+exp(2x)); saturates correctly at +/-inf
  return 1.f - 2.f / (1.f + __expf(2.f * x));
}

// ---------------- embedding gather ----------------
__global__ __launch_bounds__(256) void embed_kernel(
    const int* __restrict__ ids, const float* __restrict__ emb, float* __restrict__ x) {
  const int row = blockIdx.x;
  const int id = ids[row];
  for (int e = threadIdx.x; e < E_; e += 256)
    x[(size_t)row * E_ + e] = emb[(size_t)id * E_ + e];
}

// ---------------- generic fp32 GEMM: C = act(A @ W^T + bias) [+mask] ----------------
// A[M][lda] row-major, W[N][ldw] row-major, tiles 64x64, K % 16 == 0, M,N % 64 == 0
template <int ACT, bool MASK>
__global__ __launch_bounds__(256) void gemm_kernel(
    const float* __restrict__ A, int lda,
    const float* __restrict__ W, int ldw,
    const float* __restrict__ bias,
    float* __restrict__ C, int ldc,
    int M, int N, int K,
    const int* __restrict__ mask, int ldm) {
  __shared__ float As[16][68];
  __shared__ float Ws[16][68];
  const int tid = threadIdx.x;
  const int tx = tid & 15, ty = tid >> 4;
  const int m0 = blockIdx.y * 64, n0 = blockIdx.x * 64;
  const int r = tid >> 2, q4 = (tid & 3) << 2;
  float acc[4][4] = {};
  const float* Ap = A + (size_t)(m0 + r) * lda + q4;
  const float* Wp = W + (size_t)(n0 + r) * ldw + q4;
  for (int kc = 0; kc < K; kc += 16) {
    const float a0 = Ap[kc + 0], a1 = Ap[kc + 1], a2 = Ap[kc + 2], a3 = Ap[kc + 3];
    const float w0 = Wp[kc + 0], w1 = Wp[kc + 1], w2 = Wp[kc + 2], w3 = Wp[kc + 3];
    __syncthreads();
    As[q4 + 0][r] = a0; As[q4 + 1][r] = a1; As[q4 + 2][r] = a2; As[q4 + 3][r] = a3;
    Ws[q4 + 0][r] = w0; Ws[q4 + 1][r] = w1; Ws[q4 + 2][r] = w2; Ws[q4 + 3][r] = w3;
    __syncthreads();
#pragma unroll
    for (int k = 0; k < 16; ++k) {
      const float4 av = *reinterpret_cast<const float4*>(&As[k][ty << 2]);
      const float4 wv = *reinterpret_cast<const float4*>(&Ws[k][tx << 2]);
      const float aa[4] = {av.x, av.y, av.z, av.w};
      const float ww[4] = {wv.x, wv.y, wv.z, wv.w};
#pragma unroll
      for (int i = 0; i < 4; ++i)
#pragma unroll
        for (int j = 0; j < 4; ++j) acc[i][j] = fmaf(aa[i], ww[j], acc[i][j]);
    }
  }
#pragma unroll
  for (int i = 0; i < 4; ++i) {
    const int m = m0 + (ty << 2) + i;
#pragma unroll
    for (int j = 0; j < 4; ++j) {
      const int n = n0 + (tx << 2) + j;
      float v = acc[i][j] + (bias ? bias[n] : 0.f);
      if (ACT == 1) v = tanhf(v);
      if (MASK) {
        if (mask[(size_t)m * ldm + n] == 0) v = NEGV;
      }
      C[(size_t)m * ldc + n] = v;
    }
  }
}

// ---------------- fused 3-LSTM recurrence, weight-stationary, spin-synced ----------------
// grid = 192 (3 lstm x 64 slices); 256 threads = 16 batch x 8 dims x 2 k-halves
// dyn LDS = 32*516 + 16*516 + 512 floats = 101120 B
__global__ __launch_bounds__(256) void lstm_kernel(
    const float* __restrict__ xproj,
    const float* __restrict__ Whh_f, const float* __restrict__ Whh_b,
    const float* __restrict__ Whh_d,
    float* __restrict__ ehs, float* __restrict__ cat,
    float* __restrict__ hbuf, int* __restrict__ cnt) {
  const int lstm = blockIdx.x >> 6;
  const int w = blockIdx.x & 63;
  const float* Whh = (lstm == 0) ? Whh_f : ((lstm == 1) ? Whh_b : Whh_d);
  const float* xp = xproj + (size_t)lstm * BN_ * 2048;
  extern __shared__ float sm[];
  float* wts = sm;               // [32][516]
  float* hsh = sm + 32 * 516;    // [16][516]
  float* part = hsh + 16 * 516;  // [8][16][4]
  const int tid = threadIdx.x;
  const int b = tid & 15, dl = (tid >> 4) & 7, kh = tid >> 7;
  const int dg = (w << 3) + dl;
  // load this slice's 32 weight rows (4 gates x 8 dims) into LDS
  for (int lr = 0; lr < 32; ++lr) {
    const int g = lr >> 3, d2 = lr & 7;
    const float* src = Whh + (size_t)(g * 512 + (w << 3) + d2) * 512;
    for (int j = tid; j < 512; j += 256) wts[lr * 516 + j] = src[j];
  }
  float c = 0.f;
  const bool rev = (lstm == 1);
  int* mycnt = cnt + lstm * 128;
  const int k0 = kh << 8;
  const float* w0p = &wts[(0 * 8 + dl) * 516 + k0];
  const float* w1p = &wts[(1 * 8 + dl) * 516 + k0];
  const float* w2p = &wts[(2 * 8 + dl) * 516 + k0];
  const float* w3p = &wts[(3 * 8 + dl) * 516 + k0];
  const float* hrow = &hsh[b * 516 + k0];
  for (int s = 0; s < 128; ++s) {
    const int t = rev ? 127 - s : s;
    if (s > 0) {
      if (tid == 0) {
        while (__hip_atomic_load(&mycnt[s - 1], __ATOMIC_RELAXED, __HIP_MEMORY_SCOPE_AGENT) < 64)
          __builtin_amdgcn_s_sleep(2);
        (void)__hip_atomic_load(&mycnt[s - 1], __ATOMIC_ACQUIRE, __HIP_MEMORY_SCOPE_AGENT);
      }
      __syncthreads();
      const float* hb = hbuf + ((size_t)lstm * 2 + ((s - 1) & 1)) * (16 * 512);
      for (int idx = tid; idx < 16 * 512; idx += 256)
        hsh[(idx >> 9) * 516 + (idx & 511)] = hb[idx];
    } else {
      for (int idx = tid; idx < 16 * 512; idx += 256)
        hsh[(idx >> 9) * 516 + (idx & 511)] = 0.f;
    }
    __syncthreads();
    float xg0 = 0, xg1 = 0, xg2 = 0, xg3 = 0;
    if (kh == 0) {
      const size_t ro = (size_t)(b * 128 + t) * 2048;
      xg0 = xp[ro + dg];        xg1 = xp[ro + 512 + dg];
      xg2 = xp[ro + 1024 + dg]; xg3 = xp[ro + 1536 + dg];
    }
    float acc0 = 0, acc1 = 0, acc2 = 0, acc3 = 0;
    for (int k = 0; k < 256; k += 4) {
      const float4 hv = *reinterpret_cast<const float4*>(&hrow[k]);
      const float4 v0 = *reinterpret_cast<const float4*>(&w0p[k]);
      const float4 v1 = *reinterpret_cast<const float4*>(&w1p[k]);
      const float4 v2 = *reinterpret_cast<const float4*>(&w2p[k]);
      const float4 v3 = *reinterpret_cast<const float4*>(&w3p[k]);
      acc0 = fmaf(hv.x, v0.x, acc0); acc0 = fmaf(hv.y, v0.y, acc0);
      acc0 = fmaf(hv.z, v0.z, acc0); acc0 = fmaf(hv.w, v0.w, acc0);
      acc1 = fmaf(hv.x, v1.x, acc1); acc1 = fmaf(hv.y, v1.y, acc1);
      acc1 = fmaf(hv.z, v1.z, acc1); acc1 = fmaf(hv.w, v1.w, acc1);
      acc2 = fmaf(hv.x, v2.x, acc2); acc2 = fmaf(hv.y, v2.y, acc2);
      acc2 = fmaf(hv.z, v2.z, acc2); acc2 = fmaf(hv.w, v2.w, acc2);
      acc3 = fmaf(hv.x, v3.x, acc3); acc3 = fmaf(hv.y, v3.y, acc3);
      acc3 = fmaf(hv.z, v3.z, acc3); acc3 = fmaf(hv.w, v3.w, acc3);
    }
    if (kh == 1) {
      float* pp = &part[((dl << 4) + b) << 2];
      pp[0] = acc0; pp[1] = acc1; pp[2] = acc2; pp[3] = acc3;
    }
    __syncthreads();
    if (kh == 0) {
      const float* pp = &part[((dl << 4) + b) << 2];
      const float gi = acc0 + pp[0] + xg0;
      const float gf = acc1 + pp[1] + xg1;
      const float gg = acc2 + pp[2] + xg2;
      const float go = acc3 + pp[3] + xg3;
      const float si = 1.f / (1.f + expf(-gi));
      const float sf = 1.f / (1.f + expf(-gf));
      const float tg = tanhf(gg);
      const float so = 1.f / (1.f + expf(-go));
      c = fmaf(sf, c, si * tg);
      const float h = so * tanhf(c);
      hbuf[((size_t)lstm * 2 + (s & 1)) * (16 * 512) + b * 512 + dg] = h;
      const size_t orow = (size_t)(b * 128 + t);
      if (lstm == 0)      ehs[orow * 1024 + dg] = h;
      else if (lstm == 1) ehs[orow * 1024 + 512 + dg] = h;
      else                cat[orow * 1536 + dg] = h;
    }
    __syncthreads();  // drains all waves' stores (vmcnt0) before publish
    if (tid == 0)
      (void)__hip_atomic_fetch_add(&mycnt[s], 1, __ATOMIC_RELEASE, __HIP_MEMORY_SCOPE_AGENT);
  }
}

// ---------------- attention: score + softmax + context, one block per (b,t) ----------------
__global__ __launch_bounds__(256) void attn_kernel(
    const float* __restrict__ dterm, const float* __restrict__ eterm,
    const float* __restrict__ v_att, const int* __restrict__ src_mask,
    const float* __restrict__ ehs, float* __restrict__ cat) {
  const int bt = blockIdx.x;
  const int b = bt >> 7;
  const int tid = threadIdx.x;
  __shared__ float dt[512], vs[512], al[128], red[2 * 128], rtmp[2];
  dt[tid] = dterm[(size_t)bt * 512 + tid];
  dt[tid + 256] = dterm[(size_t)bt * 512 + 256 + tid];
  vs[tid] = v_att[tid];
  vs[tid + 256] = v_att[256 + tid];
  __syncthreads();
  const int nn = tid & 127, hh = tid >> 7;
  {
    const float* et = eterm + (size_t)(b * 128 + nn) * 512 + (hh << 8);
    const float* dth = dt + (hh << 8);
    const float* vsh = vs + (hh << 8);
    float p = 0.f;
    for (int a = 0; a < 256; ++a) p = fmaf(vsh[a], fast_tanh(dth[a] + et[a]), p);
    red[hh * 128 + nn] = p;
  }
  __syncthreads();
  if (tid < 128) {
    float s = red[tid] + red[128 + tid];
    if (src_mask[b * 128 + tid] == 0) s = NEGV;
    al[tid] = s;
  }
  __syncthreads();
  if (tid < 64) {
    float m = fmaxf(al[tid], al[tid + 64]);
    m = wave_max(m);
    if (tid == 0) rtmp[0] = m;
  }
  __syncthreads();
  if (tid < 128) al[tid] = expf(al[tid] - rtmp[0]);
  __syncthreads();
  if (tid < 64) {
    float s2 = al[tid] + al[tid + 64];
    s2 = wave_sum(s2);
    if (tid == 0) rtmp[1] = 1.f / s2;
  }
  __syncthreads();
  const float inv = rtmp[1];
  for (int h = tid; h < 1024; h += 256) {
    float a0 = 0.f;
    const float* eb = ehs + (size_t)(b * 128) * 1024 + h;
    for (int n = 0; n < 128; ++n) a0 = fmaf(al[n], eb[(size_t)n * 1024], a0);
    cat[(size_t)bt * 1536 + 512 + h] = a0 * inv;
  }
}

// ---------------- pointer head assembly, one block per (b,t) ----------------
__global__ __launch_bounds__(256) void pointer_kernel(
    const float* __restrict__ base, const float* __restrict__ wgout,
    const float* __restrict__ ptr_W, const float* __restrict__ ps_W,
    const float* __restrict__ ps_b, const int* __restrict__ src_mask,
    float* __restrict__ out0) {
  const int bt = blockIdx.x;
  const int b = bt >> 7, t = bt & 127;
  const int tid = threadIdx.x;
  __shared__ float r0[4], r1[4], r2[4], fin[3];
  float off_p = 0.f, diag_p = 0.f, sent_p;
  if (tid < 128) {
    const float ba = base[(size_t)bt * 128 + tid];
    const float pw = ps_W[tid];
    off_p = tanhf(ba) * pw;
    diag_p = tanhf(ba + ptr_W[tid * 513 + 512]) * pw;
  }
  sent_p = wgout[(size_t)bt * 512 + tid] + wgout[(size_t)bt * 512 + 256 + tid];
  off_p = wave_sum(off_p);
  diag_p = wave_sum(diag_p);
  sent_p = wave_sum(sent_p);
  const int wid = tid >> 6, lane = tid & 63;
  if (lane == 0) { r0[wid] = off_p; r1[wid] = diag_p; r2[wid] = sent_p; }
  __syncthreads();
  if (tid == 0) {
    const float psb = ps_b[0];
    fin[0] = r0[0] + r0[1] + r0[2] + r0[3] + psb;
    fin[1] = r1[0] + r1[1] + r1[2] + r1[3] + psb;
    fin[2] = r2[0] + r2[1] + r2[2] + r2[3];
  }
  __syncthreads();
  const float s_off = fin[0], s_diag = fin[1], sent = fin[2];
  if (tid < 129) {
    float v;
    if (tid == 128) v = sent;
    else {
      v = (tid == t) ? s_diag : s_off;
      if (src_mask[b * 128 + tid] == 0) v = NEGV;
    }
    out0[(size_t)bt * 129 + tid] = v;
  }
}

// ---------------- launch ----------------
extern "C" void kernel_launch(void* const* d_in, const int* in_sizes, int n_in,
                              void* d_out, int out_size, void* d_ws, size_t ws_size,
                              hipStream_t stream) {
  const int* src_ids   = (const int*)d_in[0];
  const int* src_mask  = (const int*)d_in[1];
  const int* cmask     = (const int*)d_in[2];
  const float* emb     = (const float*)d_in[3];
  const float* Wih_f   = (const float*)d_in[4];
  const float* Whh_f   = (const float*)d_in[5];
  const float* b_f     = (const float*)d_in[6];
  const float* Wih_b   = (const float*)d_in[7];
  const float* Whh_b   = (const float*)d_in[8];
  const float* b_b     = (const float*)d_in[9];
  const float* Wih_d   = (const float*)d_in[10];
  const float* Whh_d   = (const float*)d_in[11];
  const float* b_d     = (const float*)d_in[12];
  const float* W1      = (const float*)d_in[13];
  const float* W2      = (const float*)d_in[14];
  const float* v_att   = (const float*)d_in[15];
  const float* comb_W  = (const float*)d_in[16];
  const float* comb_b  = (const float*)d_in[17];
  const float* vocab_W = (const float*)d_in[18];
  const float* vocab_b = (const float*)d_in[19];
  const float* Wg_W    = (const float*)d_in[20];
  const float* Wg_b    = (const float*)d_in[21];
  const float* ptr_W   = (const float*)d_in[22];
  const float* ptr_b   = (const float*)d_in[23];
  const float* ps_W    = (const float*)d_in[24];
  const float* ps_b    = (const float*)d_in[25];
  (void)in_sizes; (void)n_in; (void)out_size; (void)ws_size;

  float* ws = (float*)d_ws;
  float* x      = ws + OFF_X;
  float* xproj  = ws + OFF_XPROJ;
  float* ehs    = ws + OFF_EHS;
  float* cat    = ws + OFF_CAT;
  float* dterm  = ws + OFF_DT;
  float* eterm  = ws + OFF_ET;
  float* comb   = ws + OFF_CB;
  float* wgout  = ws + OFF_WGO;
  float* base   = ws + OFF_BASE;
  float* hbuf   = ws + OFF_HBUF;
  int*   cnt    = (int*)(ws + OFF_CNT);

  float* out0 = (float*)d_out;                    // pointer_logits [16][128][129]
  float* out1 = out0 + (size_t)BN_ * 129;         // vocab_logits   [16][128][8000]

  hipMemsetAsync(cnt, 0, 384 * sizeof(int), stream);

  embed_kernel<<<BN_, 256, 0, stream>>>(src_ids, emb, x);

  // input projections (bias folded here)
  gemm_kernel<0, false><<<dim3(32, 32), 256, 0, stream>>>(
      x, E_, Wih_f, E_, b_f, xproj + 0 * SZ_XP1, 2048, BN_, 2048, E_, nullptr, 0);
  gemm_kernel<0, false><<<dim3(32, 32), 256, 0, stream>>>(
      x, E_, Wih_b, E_, b_b, xproj + 1 * SZ_XP1, 2048, BN_, 2048, E_, nullptr, 0);
  gemm_kernel<0, false><<<dim3(32, 32), 256, 0, stream>>>(
      x, E_, Wih_d, E_, b_d, xproj + 2 * SZ_XP1, 2048, BN_, 2048, E_, nullptr, 0);

  hipFuncSetAttribute((const void*)lstm_kernel,
                      hipFuncAttributeMaxDynamicSharedMemorySize, 101120);
  lstm_kernel<<<192, 256, 101120, stream>>>(xproj, Whh_f, Whh_b, Whh_d, ehs, cat, hbuf, cnt);

  // dterm = dec_h @ W1^T ; eterm = enc_hs @ W2^T (no bias)
  gemm_kernel<0, false><<<dim3(8, 32), 256, 0, stream>>>(
      cat, 1536, W1, 512, nullptr, dterm, 512, BN_, 512, 512, nullptr, 0);
  gemm_kernel<0, false><<<dim3(8, 32), 256, 0, stream>>>(
      ehs, 1024, W2, 1024, nullptr, eterm, 512, BN_, 512, 1024, nullptr, 0);

  attn_kernel<<<BN_, 256, 0, stream>>>(dterm, eterm, v_att, src_mask, ehs, cat);

  // combined = tanh(cat @ comb_W^T + comb_b)
  gemm_kernel<1, false><<<dim3(8, 32), 256, 0, stream>>>(
      cat, 1536, comb_W, 1536, comb_b, comb, 512, BN_, 512, 1536, nullptr, 0);

  // vocab logits with confusionset mask fused
  gemm_kernel<0, true><<<dim3(125, 32), 256, 0, stream>>>(
      comb, 512, vocab_W, 512, vocab_b, out1, V_, BN_, V_, 512, cmask, V_);

  // wgout = tanh(comb @ Wg_W^T + Wg_b)
  gemm_kernel<1, false><<<dim3(8, 32), 256, 0, stream>>>(
      comb, 512, Wg_W, 512, Wg_b, wgout, 512, BN_, 512, 512, nullptr, 0);

  // base = comb @ ptr_W[:, :512]^T + ptr_b   (ldw = 513)
  gemm_kernel<0, false><<<dim3(2, 32), 256, 0, stream>>>(
      comb, 512, ptr_W, 513, ptr_b, base, 128, BN_, 128, 512, nullptr, 0);

  pointer_kernel<<<BN_, 256, 0, stream>>>(base, wgout, ptr_W, ps_W, ps_b, src_mask, out0);
}

// Round 2
// 1161.267 us; speedup vs baseline: 2.0139x; 2.0139x over previous
//
#include <hip/hip_runtime.h>
#include <hip/hip_bf16.h>
#include <math.h>

#define NEGV -1000000000.0f

static constexpr int B_ = 16, N_ = 128, BN_ = 2048;
static constexpr int E_ = 384, V_ = 8000;

typedef __attribute__((ext_vector_type(8))) short short8v;
typedef __attribute__((ext_vector_type(4))) float f32x4;

// ---------------- helpers ----------------
__device__ inline float wave_sum(float v) {
#pragma unroll
  for (int o = 32; o; o >>= 1) v += __shfl_xor(v, o);
  return v;
}
__device__ inline float wave_max(float v) {
#pragma unroll
  for (int o = 32; o; o >>= 1) v = fmaxf(v, __shfl_xor(v, o));
  return v;
}
__device__ inline float fast_tanh(float x) {
  return 1.f - 2.f / (1.f + __expf(2.f * x));
}
__device__ __forceinline__ void gl16(const void* g, void* l) {
  __builtin_amdgcn_global_load_lds((const __attribute__((address_space(1))) void*)g,
                                   (__attribute__((address_space(3))) void*)l, 16, 0, 0);
}

// ---------------- embedding gather -> bf16 ----------------
__global__ __launch_bounds__(256) void embed_kernel(
    const int* __restrict__ ids, const float* __restrict__ emb,
    __hip_bfloat16* __restrict__ xb) {
  const int row = blockIdx.x;
  const int id = ids[row];
  for (int e = threadIdx.x; e < E_; e += 256)
    xb[(size_t)row * E_ + e] = __float2bfloat16(emb[(size_t)id * E_ + e]);
}

// ---------------- multi-segment fp32 -> bf16 cast ----------------
struct CastArgs {
  const float* s[12];
  unsigned long long d[12];
  int base[12];
  int total;
};
__global__ __launch_bounds__(256) void cast_kernel(CastArgs a) {
  const int nq = a.total >> 2;
  for (int q = blockIdx.x * 256 + threadIdx.x; q < nq; q += gridDim.x * 256) {
    const int e = q << 2;
    int k = 11;
    while (e < a.base[k]) --k;
    const int i = e - a.base[k];
    __hip_bfloat16* dst = (__hip_bfloat16*)a.d[k] + i;
    if (k == 11) {  // ptr_W: pack [128][513] cols 0..511 -> [128][512]
      const int row = i >> 9, col = i & 511;
      const float* sp = a.s[k] + (size_t)row * 513 + col;
#pragma unroll
      for (int u = 0; u < 4; ++u) dst[u] = __float2bfloat16(sp[u]);
    } else {
      float4 v = *(const float4*)(a.s[k] + i);
      __hip_bfloat16 h0 = __float2bfloat16(v.x), h1 = __float2bfloat16(v.y);
      __hip_bfloat16 h2 = __float2bfloat16(v.z), h3 = __float2bfloat16(v.w);
      ushort4 u4 = {*(unsigned short*)&h0, *(unsigned short*)&h1,
                    *(unsigned short*)&h2, *(unsigned short*)&h3};
      *(ushort4*)dst = u4;
    }
  }
}

// ---------------- bf16 MFMA GEMM: out = act(A @ W^T + bias) [+mask] ----------------
// A[M][lda] bf16, W[N][ldw] bf16 row-major. 128x128 tile, BK=32, 4 waves.
// C (fp32) and/or Cb (bf16) outputs, either nullable. M%128==0; N tail clamped.
template <int ACT, bool MASK>
__global__ __launch_bounds__(256) void bgemm_kernel(
    const __hip_bfloat16* __restrict__ A, int lda,
    const __hip_bfloat16* __restrict__ W, int ldw,
    const float* __restrict__ bias,
    float* __restrict__ C, int ldc,
    __hip_bfloat16* __restrict__ Cb, int ldcb,
    int M, int N, int K,
    const int* __restrict__ mask, int ldm) {
  __shared__ __hip_bfloat16 Al[2][4096];
  __shared__ __hip_bfloat16 Bl[2][4096];
  const int tid = threadIdx.x;
  const int wid = tid >> 6, lane = tid & 63;
  const int m0 = blockIdx.y * 128, n0 = blockIdx.x * 128;
  const int nkt = K >> 5;
  const int rm = (wid >> 1) << 6, rn = (wid & 1) << 6;
  const int lrow = lane & 15, kq = lane >> 4;
  const int fs = ((lrow >> 1) & 3) << 4;

  f32x4 acc[4][4];
#pragma unroll
  for (int i = 0; i < 4; ++i)
#pragma unroll
    for (int j = 0; j < 4; ++j) acc[i][j] = {0.f, 0.f, 0.f, 0.f};

  auto stage = [&](int bi, int kt) {
#pragma unroll
    for (int c = 0; c < 2; ++c) {
      const int p = ((c * 4 + wid) << 6) + lane;
      const int row = p >> 2, cb = (p & 3) << 4;
      const int sw = ((row >> 1) & 3) << 4;
      const unsigned loff = (unsigned)__builtin_amdgcn_readfirstlane((c * 4 + wid) << 10);
      {
        const char* src = (const char*)A + ((size_t)(m0 + row) * lda + (size_t)kt * 32) * 2 + (cb ^ sw);
        gl16(src, (char*)&Al[bi][0] + loff);
      }
      {
        int gr = n0 + row;
        if (gr >= N) gr = N - 1;
        const char* src = (const char*)W + ((size_t)gr * ldw + (size_t)kt * 32) * 2 + (cb ^ sw);
        gl16(src, (char*)&Bl[bi][0] + loff);
      }
    }
  };
  auto compute = [&](int bi) {
    const char* Ab = (const char*)&Al[bi][0];
    const char* Bb = (const char*)&Bl[bi][0];
    const int roff = (kq << 4) ^ fs;
    short8v a[4], b[4];
#pragma unroll
    for (int i = 0; i < 4; ++i)
      a[i] = *(const short8v*)(Ab + (rm + i * 16 + lrow) * 64 + roff);
#pragma unroll
    for (int j = 0; j < 4; ++j)
      b[j] = *(const short8v*)(Bb + (rn + j * 16 + lrow) * 64 + roff);
#pragma unroll
    for (int i = 0; i < 4; ++i)
#pragma unroll
      for (int j = 0; j < 4; ++j)
        acc[i][j] = __builtin_amdgcn_mfma_f32_16x16x32_bf16(a[i], b[j], acc[i][j], 0, 0, 0);
  };

  stage(0, 0);
  for (int kt = 0; kt < nkt; ++kt) {
    __syncthreads();
    if (kt + 1 < nkt) stage((kt + 1) & 1, kt + 1);
    compute(kt & 1);
  }

#pragma unroll
  for (int i = 0; i < 4; ++i) {
#pragma unroll
    for (int r = 0; r < 4; ++r) {
      const int m = m0 + rm + i * 16 + kq * 4 + r;
#pragma unroll
      for (int j = 0; j < 4; ++j) {
        const int n = n0 + rn + j * 16 + lrow;
        if (n < N) {
          float v = acc[i][j][r] + (bias ? bias[n] : 0.f);
          if (ACT == 1) v = tanhf(v);
          if (MASK) {
            if (mask[(size_t)m * ldm + n] == 0) v = NEGV;
          }
          if (C) C[(size_t)m * ldc + n] = v;
          if (Cb) Cb[(size_t)m * ldcb + n] = __float2bfloat16(v);
        }
      }
    }
  }
}

// ---------------- fused 3-LSTM recurrence: bf16 MFMA, weight-stationary ----------------
// grid 96 = 3 lstm x 32 slices. Block owns 16 h-dims x 4 gates (64 W rows).
// dyn LDS: W 64KB (swizzled) + h 16KB (swizzled) + gates 4KB = 86016 B.
__global__ __launch_bounds__(256) void lstm_kernel(
    const __hip_bfloat16* __restrict__ xp16,   // [3][2048][2048]
    const __hip_bfloat16* __restrict__ whh16,  // [3][2048][512]
    __hip_bfloat16* __restrict__ ehsb, __hip_bfloat16* __restrict__ catb,
    __hip_bfloat16* __restrict__ hbuf, int* __restrict__ flg) {
  const int l = blockIdx.x >> 5, g = blockIdx.x & 31;
  const int tid = threadIdx.x, lane = tid & 63, wid = tid >> 6;
  extern __shared__ char sm[];
  char* smW = sm;                                  // 65536
  char* smH = sm + 65536;                          // 16384
  float* gl = (float*)(sm + 65536 + 16384);        // 4096

  const __hip_bfloat16* wsrc = whh16 + (size_t)l * 2048 * 512;
  for (int p = tid; p < 4096; p += 256) {
    const int r = p >> 6, cb = (p & 63) << 4;
    const int grow = ((r >> 4) << 9) + (g << 4) + (r & 15);
    float4 v = *(const float4*)((const char*)(wsrc + (size_t)grow * 512) + cb);
    *(float4*)(smW + r * 1024 + (cb ^ ((r & 7) << 4))) = v;
  }

  const int d = tid >> 4, b = tid & 15;
  const int dg = (g << 4) + d;
  const int lrow = lane & 15, kq = lane >> 4;
  const int swz = (lrow & 7) << 4;
  const char* aB = smW + (wid * 16 + lrow) * 1024;
  const char* bB = smH + lrow * 1024;
  const bool rev = (l == 1);
  const __hip_bfloat16* xl = xp16 + (size_t)l * 2048 * 2048;
  float c = 0.f;

  for (int s = 0; s < 128; ++s) {
    const int t = rev ? 127 - s : s;
    const size_t xro = (size_t)(b * 128 + t) * 2048 + dg;
    const float xgi = __bfloat162float(xl[xro]);
    const float xgf = __bfloat162float(xl[xro + 512]);
    const float xgg = __bfloat162float(xl[xro + 1024]);
    const float xgo = __bfloat162float(xl[xro + 1536]);

    if (s > 0) {
      if (tid < 32) {
        const int* fp = flg + ((size_t)(l * 128 + (s - 1)) * 32 + tid) * 16;
        while (__hip_atomic_load(fp, __ATOMIC_RELAXED, __HIP_MEMORY_SCOPE_AGENT) == 0)
          __builtin_amdgcn_s_sleep(1);
        (void)__hip_atomic_load(fp, __ATOMIC_ACQUIRE, __HIP_MEMORY_SCOPE_AGENT);
      }
      __syncthreads();
      const char* hb = (const char*)(hbuf + ((size_t)l * 2 + ((s - 1) & 1)) * 8192);
#pragma unroll
      for (int cc = 0; cc < 4; ++cc) {
        const int e = cc * 2048 + tid * 8;
        const int row = e >> 9, col = e & 511;
        float4 v = *(const float4*)(hb + ((size_t)row * 512 + col) * 2);
        *(float4*)(smH + row * 1024 + ((col * 2) ^ ((row & 7) << 4))) = v;
      }
    } else {
#pragma unroll
      for (int cc = 0; cc < 4; ++cc) {
        const int e = cc * 2048 + tid * 8;
        const int row = e >> 9, col = e & 511;
        *(float4*)(smH + row * 1024 + ((col * 2) ^ ((row & 7) << 4))) =
            make_float4(0.f, 0.f, 0.f, 0.f);
      }
    }
    __syncthreads();

    f32x4 acc0 = {0.f, 0.f, 0.f, 0.f}, acc1 = {0.f, 0.f, 0.f, 0.f};
#pragma unroll
    for (int kt = 0; kt < 16; kt += 2) {
      const int off0 = ((kt * 64 + (kq << 4)) ^ swz);
      const int off1 = (((kt + 1) * 64 + (kq << 4)) ^ swz);
      short8v a0 = *(const short8v*)(aB + off0);
      short8v b0 = *(const short8v*)(bB + off0);
      short8v a1 = *(const short8v*)(aB + off1);
      short8v b1 = *(const short8v*)(bB + off1);
      acc0 = __builtin_amdgcn_mfma_f32_16x16x32_bf16(a0, b0, acc0, 0, 0, 0);
      acc1 = __builtin_amdgcn_mfma_f32_16x16x32_bf16(a1, b1, acc1, 0, 0, 0);
    }
    f32x4 acc = acc0 + acc1;
#pragma unroll
    for (int r = 0; r < 4; ++r)
      gl[wid * 256 + (kq * 4 + r) * 16 + lrow] = acc[r];
    __syncthreads();

    const float gi = gl[d * 16 + b] + xgi;
    const float gf = gl[256 + d * 16 + b] + xgf;
    const float gg = gl[512 + d * 16 + b] + xgg;
    const float go = gl[768 + d * 16 + b] + xgo;
    const float si = 1.f / (1.f + __expf(-gi));
    const float sf = 1.f / (1.f + __expf(-gf));
    const float tg = tanhf(gg);
    const float so = 1.f / (1.f + __expf(-go));
    c = fmaf(sf, c, si * tg);
    const float h = so * tanhf(c);
    __hip_bfloat16 hb16 = __float2bfloat16(h);
    hbuf[((size_t)l * 2 + (s & 1)) * 8192 + (size_t)b * 512 + dg] = hb16;
    const size_t orow = (size_t)(b * 128 + t);
    if (l == 0)      ehsb[orow * 1024 + dg] = hb16;
    else if (l == 1) ehsb[orow * 1024 + 512 + dg] = hb16;
    else             catb[orow * 1536 + dg] = hb16;
    __syncthreads();  // drains stores (vmcnt0) before publish
    if (tid == 0)
      __hip_atomic_store(flg + ((size_t)(l * 128 + s) * 32 + g) * 16, 1,
                         __ATOMIC_RELEASE, __HIP_MEMORY_SCOPE_AGENT);
  }
}

// ---------------- attention: score + softmax + context, one block per (b,t) ----------------
__global__ __launch_bounds__(256) void attn_kernel(
    const float* __restrict__ dterm, const float* __restrict__ eterm,
    const float* __restrict__ v_att, const int* __restrict__ src_mask,
    const __hip_bfloat16* __restrict__ ehsb, __hip_bfloat16* __restrict__ catb) {
  const int bt = blockIdx.x;
  const int b = bt >> 7;
  const int tid = threadIdx.x;
  __shared__ float dt[512], vs[512], al[128], red[2 * 128], rtmp[2];
  dt[tid] = dterm[(size_t)bt * 512 + tid];
  dt[tid + 256] = dterm[(size_t)bt * 512 + 256 + tid];
  vs[tid] = v_att[tid];
  vs[tid + 256] = v_att[256 + tid];
  __syncthreads();
  const int nn = tid & 127, hh = tid >> 7;
  {
    const float* et = eterm + (size_t)(b * 128 + nn) * 512 + (hh << 8);
    const float* dth = dt + (hh << 8);
    const float* vsh = vs + (hh << 8);
    float p = 0.f;
    for (int a = 0; a < 256; ++a) p = fmaf(vsh[a], fast_tanh(dth[a] + et[a]), p);
    red[hh * 128 + nn] = p;
  }
  __syncthreads();
  if (tid < 128) {
    float s = red[tid] + red[128 + tid];
    if (src_mask[b * 128 + tid] == 0) s = NEGV;
    al[tid] = s;
  }
  __syncthreads();
  if (tid < 64) {
    float m = fmaxf(al[tid], al[tid + 64]);
    m = wave_max(m);
    if (tid == 0) rtmp[0] = m;
  }
  __syncthreads();
  if (tid < 128) al[tid] = expf(al[tid] - rtmp[0]);
  __syncthreads();
  if (tid < 64) {
    float s2 = al[tid] + al[tid + 64];
    s2 = wave_sum(s2);
    if (tid == 0) rtmp[1] = 1.f / s2;
  }
  __syncthreads();
  const float inv = rtmp[1];
  for (int h = tid; h < 1024; h += 256) {
    float a0 = 0.f;
    const __hip_bfloat16* eb = ehsb + (size_t)(b * 128) * 1024 + h;
    for (int n = 0; n < 128; ++n)
      a0 = fmaf(al[n], __bfloat162float(eb[(size_t)n * 1024]), a0);
    catb[(size_t)bt * 1536 + 512 + h] = __float2bfloat16(a0 * inv);
  }
}

// ---------------- pointer head assembly ----------------
__global__ __launch_bounds__(256) void pointer_kernel(
    const float* __restrict__ base, const float* __restrict__ wgout,
    const float* __restrict__ ptr_W, const float* __restrict__ ps_W,
    const float* __restrict__ ps_b, const int* __restrict__ src_mask,
    float* __restrict__ out0) {
  const int bt = blockIdx.x;
  const int b = bt >> 7, t = bt & 127;
  const int tid = threadIdx.x;
  __shared__ float r0[4], r1[4], r2[4], fin[3];
  float off_p = 0.f, diag_p = 0.f, sent_p;
  if (tid < 128) {
    const float ba = base[(size_t)bt * 128 + tid];
    const float pw = ps_W[tid];
    off_p = tanhf(ba) * pw;
    diag_p = tanhf(ba + ptr_W[tid * 513 + 512]) * pw;
  }
  sent_p = wgout[(size_t)bt * 512 + tid] + wgout[(size_t)bt * 512 + 256 + tid];
  off_p = wave_sum(off_p);
  diag_p = wave_sum(diag_p);
  sent_p = wave_sum(sent_p);
  const int wid = tid >> 6, lane = tid & 63;
  if (lane == 0) { r0[wid] = off_p; r1[wid] = diag_p; r2[wid] = sent_p; }
  __syncthreads();
  if (tid == 0) {
    const float psb = ps_b[0];
    fin[0] = r0[0] + r0[1] + r0[2] + r0[3] + psb;
    fin[1] = r1[0] + r1[1] + r1[2] + r1[3] + psb;
    fin[2] = r2[0] + r2[1] + r2[2] + r2[3];
  }
  __syncthreads();
  const float s_off = fin[0], s_diag = fin[1], sent = fin[2];
  if (tid < 129) {
    float v;
    if (tid == 128) v = sent;
    else {
      v = (tid == t) ? s_diag : s_off;
      if (src_mask[b * 128 + tid] == 0) v = NEGV;
    }
    out0[(size_t)bt * 129 + tid] = v;
  }
}

// ---------------- launch ----------------
extern "C" void kernel_launch(void* const* d_in, const int* in_sizes, int n_in,
                              void* d_out, int out_size, void* d_ws, size_t ws_size,
                              hipStream_t stream) {
  const int* src_ids   = (const int*)d_in[0];
  const int* src_mask  = (const int*)d_in[1];
  const int* cmask     = (const int*)d_in[2];
  const float* emb     = (const float*)d_in[3];
  const float* Wih_f   = (const float*)d_in[4];
  const float* Whh_f   = (const float*)d_in[5];
  const float* b_f     = (const float*)d_in[6];
  const float* Wih_b   = (const float*)d_in[7];
  const float* Whh_b   = (const float*)d_in[8];
  const float* b_b     = (const float*)d_in[9];
  const float* Wih_d   = (const float*)d_in[10];
  const float* Whh_d   = (const float*)d_in[11];
  const float* b_d     = (const float*)d_in[12];
  const float* W1      = (const float*)d_in[13];
  const float* W2      = (const float*)d_in[14];
  const float* v_att   = (const float*)d_in[15];
  const float* comb_W  = (const float*)d_in[16];
  const float* comb_b  = (const float*)d_in[17];
  const float* vocab_W = (const float*)d_in[18];
  const float* vocab_b = (const float*)d_in[19];
  const float* Wg_W    = (const float*)d_in[20];
  const float* Wg_b    = (const float*)d_in[21];
  const float* ptr_W   = (const float*)d_in[22];
  const float* ptr_b   = (const float*)d_in[23];
  const float* ps_W    = (const float*)d_in[24];
  const float* ps_b    = (const float*)d_in[25];
  (void)in_sizes; (void)n_in; (void)out_size; (void)ws_size;

  char* wsb = (char*)d_ws;
  size_t o = 0;
  auto alloc = [&](size_t bytes) { char* p = wsb + o; o = (o + bytes + 255) & ~(size_t)255; return p; };
  __hip_bfloat16* xb      = (__hip_bfloat16*)alloc((size_t)BN_ * E_ * 2);
  __hip_bfloat16* xproj16 = (__hip_bfloat16*)alloc((size_t)3 * BN_ * 2048 * 2);
  __hip_bfloat16* ehsb    = (__hip_bfloat16*)alloc((size_t)BN_ * 1024 * 2);
  __hip_bfloat16* catb    = (__hip_bfloat16*)alloc((size_t)BN_ * 1536 * 2);
  float* dterm            = (float*)alloc((size_t)BN_ * 512 * 4);
  float* eterm            = (float*)alloc((size_t)BN_ * 512 * 4);
  __hip_bfloat16* combb   = (__hip_bfloat16*)alloc((size_t)BN_ * 512 * 2);
  float* wgout            = (float*)alloc((size_t)BN_ * 512 * 4);
  float* baseb            = (float*)alloc((size_t)BN_ * 128 * 4);
  __hip_bfloat16* hbuf    = (__hip_bfloat16*)alloc((size_t)3 * 2 * 16 * 512 * 2);
  int* flg                = (int*)alloc((size_t)3 * 128 * 32 * 16 * 4);
  __hip_bfloat16* wihf16  = (__hip_bfloat16*)alloc((size_t)2048 * 384 * 2);
  __hip_bfloat16* wihb16  = (__hip_bfloat16*)alloc((size_t)2048 * 384 * 2);
  __hip_bfloat16* wihd16  = (__hip_bfloat16*)alloc((size_t)2048 * 384 * 2);
  __hip_bfloat16* whh16   = (__hip_bfloat16*)alloc((size_t)3 * 2048 * 512 * 2);
  __hip_bfloat16* w1_16   = (__hip_bfloat16*)alloc((size_t)512 * 512 * 2);
  __hip_bfloat16* w2_16   = (__hip_bfloat16*)alloc((size_t)512 * 1024 * 2);
  __hip_bfloat16* combw16 = (__hip_bfloat16*)alloc((size_t)512 * 1536 * 2);
  __hip_bfloat16* vocw16  = (__hip_bfloat16*)alloc((size_t)8000 * 512 * 2);
  __hip_bfloat16* wgw16   = (__hip_bfloat16*)alloc((size_t)512 * 512 * 2);
  __hip_bfloat16* ptrw16  = (__hip_bfloat16*)alloc((size_t)128 * 512 * 2);

  float* out0 = (float*)d_out;
  float* out1 = out0 + (size_t)BN_ * 129;

  hipMemsetAsync(flg, 0, (size_t)3 * 128 * 32 * 16 * 4, stream);
  embed_kernel<<<BN_, 256, 0, stream>>>(src_ids, emb, xb);

  CastArgs ca;
  const float* srcs[12] = {Wih_f, Wih_b, Wih_d, Whh_f, Whh_b, Whh_d,
                           W1, W2, comb_W, vocab_W, Wg_W, ptr_W};
  __hip_bfloat16* dsts[12] = {wihf16, wihb16, wihd16, whh16, whh16 + 2048 * 512,
                              whh16 + 2 * 2048 * 512, w1_16, w2_16, combw16,
                              vocw16, wgw16, ptrw16};
  int ns[12] = {2048 * 384, 2048 * 384, 2048 * 384, 2048 * 512, 2048 * 512,
                2048 * 512, 512 * 512, 512 * 1024, 512 * 1536, 8000 * 512,
                512 * 512, 128 * 512};
  int acc = 0;
  for (int k = 0; k < 12; ++k) {
    ca.s[k] = srcs[k];
    ca.d[k] = (unsigned long long)dsts[k];
    ca.base[k] = acc;
    acc += ns[k];
  }
  ca.total = acc;
  cast_kernel<<<2048, 256, 0, stream>>>(ca);

  // input projections (bias folded), bf16 out
  bgemm_kernel<0, false><<<dim3(16, 16), 256, 0, stream>>>(
      xb, E_, wihf16, E_, b_f, nullptr, 0, xproj16, 2048, BN_, 2048, E_, nullptr, 0);
  bgemm_kernel<0, false><<<dim3(16, 16), 256, 0, stream>>>(
      xb, E_, wihb16, E_, b_b, nullptr, 0, xproj16 + (size_t)BN_ * 2048, 2048, BN_, 2048, E_, nullptr, 0);
  bgemm_kernel<0, false><<<dim3(16, 16), 256, 0, stream>>>(
      xb, E_, wihd16, E_, b_d, nullptr, 0, xproj16 + (size_t)2 * BN_ * 2048, 2048, BN_, 2048, E_, nullptr, 0);

  hipFuncSetAttribute((const void*)lstm_kernel,
                      hipFuncAttributeMaxDynamicSharedMemorySize, 86016);
  lstm_kernel<<<96, 256, 86016, stream>>>(xproj16, whh16, ehsb, catb, hbuf, flg);

  // dterm = dec_h @ W1^T ; eterm = enc_hs @ W2^T
  bgemm_kernel<0, false><<<dim3(4, 16), 256, 0, stream>>>(
      catb, 1536, w1_16, 512, nullptr, dterm, 512, nullptr, 0, BN_, 512, 512, nullptr, 0);
  bgemm_kernel<0, false><<<dim3(4, 16), 256, 0, stream>>>(
      ehsb, 1024, w2_16, 1024, nullptr, eterm, 512, nullptr, 0, BN_, 512, 1024, nullptr, 0);

  attn_kernel<<<BN_, 256, 0, stream>>>(dterm, eterm, v_att, src_mask, ehsb, catb);

  // combined = tanh(cat @ comb_W^T + comb_b) -> bf16
  bgemm_kernel<1, false><<<dim3(4, 16), 256, 0, stream>>>(
      catb, 1536, combw16, 1536, comb_b, nullptr, 0, combb, 512, BN_, 512, 1536, nullptr, 0);

  // vocab logits + confusionset mask
  bgemm_kernel<0, true><<<dim3(63, 16), 256, 0, stream>>>(
      combb, 512, vocw16, 512, vocab_b, out1, V_, nullptr, 0, BN_, V_, 512, cmask, V_);

  // wgout = tanh(comb @ Wg^T + b)
  bgemm_kernel<1, false><<<dim3(4, 16), 256, 0, stream>>>(
      combb, 512, wgw16, 512, Wg_b, wgout, 512, nullptr, 0, BN_, 512, 512, nullptr, 0);

  // base = comb @ ptr_W[:,:512]^T + ptr_b
  bgemm_kernel<0, false><<<dim3(1, 16), 256, 0, stream>>>(
      combb, 512, ptrw16, 512, ptr_b, baseb, 128, nullptr, 0, BN_, 128, 512, nullptr, 0);

  pointer_kernel<<<BN_, 256, 0, stream>>>(baseb, wgout, ptr_W, ps_W, ps_b, src_mask, out0);
}

// Round 3
// 817.626 us; speedup vs baseline: 2.8604x; 1.4203x over previous
//
#include <hip/hip_runtime.h>
#include <hip/hip_bf16.h>
#include <math.h>

#define NEGV -1000000000.0f

static constexpr int B_ = 16, N_ = 128, BN_ = 2048;
static constexpr int E_ = 384, V_ = 8000;

typedef __attribute__((ext_vector_type(8))) short short8v;
typedef __attribute__((ext_vector_type(4))) float f32x4;

// ---------------- helpers ----------------
__device__ inline float wave_sum(float v) {
#pragma unroll
  for (int o = 32; o; o >>= 1) v += __shfl_xor(v, o);
  return v;
}
__device__ inline float wave_max(float v) {
#pragma unroll
  for (int o = 32; o; o >>= 1) v = fmaxf(v, __shfl_xor(v, o));
  return v;
}
__device__ inline float fast_tanh(float x) {
  return 1.f - 2.f / (1.f + __expf(2.f * x));
}
__device__ __forceinline__ void gl16(const void* g, void* l) {
  __builtin_amdgcn_global_load_lds((const __attribute__((address_space(1))) void*)g,
                                   (__attribute__((address_space(3))) void*)l, 16, 0, 0);
}

// ---------------- embedding gather -> bf16 ----------------
__global__ __launch_bounds__(256) void embed_kernel(
    const int* __restrict__ ids, const float* __restrict__ emb,
    __hip_bfloat16* __restrict__ xb) {
  const int row = blockIdx.x;
  const int id = ids[row];
  for (int e = threadIdx.x; e < E_; e += 256)
    xb[(size_t)row * E_ + e] = __float2bfloat16(emb[(size_t)id * E_ + e]);
}

// ---------------- multi-segment fp32 -> bf16 cast ----------------
struct CastArgs {
  const float* s[12];
  unsigned long long d[12];
  int base[12];
  int total;
};
__global__ __launch_bounds__(256) void cast_kernel(CastArgs a) {
  const int nq = a.total >> 2;
  for (int q = blockIdx.x * 256 + threadIdx.x; q < nq; q += gridDim.x * 256) {
    const int e = q << 2;
    int k = 11;
    while (e < a.base[k]) --k;
    const int i = e - a.base[k];
    __hip_bfloat16* dst = (__hip_bfloat16*)a.d[k] + i;
    if (k == 11) {  // ptr_W: pack [128][513] cols 0..511 -> [128][512]
      const int row = i >> 9, col = i & 511;
      const float* sp = a.s[k] + (size_t)row * 513 + col;
#pragma unroll
      for (int u = 0; u < 4; ++u) dst[u] = __float2bfloat16(sp[u]);
    } else {
      float4 v = *(const float4*)(a.s[k] + i);
      __hip_bfloat16 h0 = __float2bfloat16(v.x), h1 = __float2bfloat16(v.y);
      __hip_bfloat16 h2 = __float2bfloat16(v.z), h3 = __float2bfloat16(v.w);
      ushort4 u4 = {*(unsigned short*)&h0, *(unsigned short*)&h1,
                    *(unsigned short*)&h2, *(unsigned short*)&h3};
      *(ushort4*)dst = u4;
    }
  }
}

// ---------------- bf16 MFMA GEMM: out = act(A @ W^T + bias) [+mask] ----------------
// A[M][lda] bf16, W[N][ldw] bf16 row-major. 128x128 tile, BK=32, 4 waves.
// C (fp32) and/or Cb (bf16) outputs, either nullable. M%128==0; N tail clamped.
template <int ACT, bool MASK>
__global__ __launch_bounds__(256) void bgemm_kernel(
    const __hip_bfloat16* __restrict__ A, int lda,
    const __hip_bfloat16* __restrict__ W, int ldw,
    const float* __restrict__ bias,
    float* __restrict__ C, int ldc,
    __hip_bfloat16* __restrict__ Cb, int ldcb,
    int M, int N, int K,
    const int* __restrict__ mask, int ldm) {
  __shared__ __hip_bfloat16 Al[2][4096];
  __shared__ __hip_bfloat16 Bl[2][4096];
  const int tid = threadIdx.x;
  const int wid = tid >> 6, lane = tid & 63;
  const int m0 = blockIdx.y * 128, n0 = blockIdx.x * 128;
  const int nkt = K >> 5;
  const int rm = (wid >> 1) << 6, rn = (wid & 1) << 6;
  const int lrow = lane & 15, kq = lane >> 4;
  const int fs = ((lrow >> 1) & 3) << 4;

  f32x4 acc[4][4];
#pragma unroll
  for (int i = 0; i < 4; ++i)
#pragma unroll
    for (int j = 0; j < 4; ++j) acc[i][j] = {0.f, 0.f, 0.f, 0.f};

  auto stage = [&](int bi, int kt) {
#pragma unroll
    for (int c = 0; c < 2; ++c) {
      const int p = ((c * 4 + wid) << 6) + lane;
      const int row = p >> 2, cb = (p & 3) << 4;
      const int sw = ((row >> 1) & 3) << 4;
      const unsigned loff = (unsigned)__builtin_amdgcn_readfirstlane((c * 4 + wid) << 10);
      {
        const char* src = (const char*)A + ((size_t)(m0 + row) * lda + (size_t)kt * 32) * 2 + (cb ^ sw);
        gl16(src, (char*)&Al[bi][0] + loff);
      }
      {
        int gr = n0 + row;
        if (gr >= N) gr = N - 1;
        const char* src = (const char*)W + ((size_t)gr * ldw + (size_t)kt * 32) * 2 + (cb ^ sw);
        gl16(src, (char*)&Bl[bi][0] + loff);
      }
    }
  };
  auto compute = [&](int bi) {
    const char* Ab = (const char*)&Al[bi][0];
    const char* Bb = (const char*)&Bl[bi][0];
    const int roff = (kq << 4) ^ fs;
    short8v a[4], b[4];
#pragma unroll
    for (int i = 0; i < 4; ++i)
      a[i] = *(const short8v*)(Ab + (rm + i * 16 + lrow) * 64 + roff);
#pragma unroll
    for (int j = 0; j < 4; ++j)
      b[j] = *(const short8v*)(Bb + (rn + j * 16 + lrow) * 64 + roff);
#pragma unroll
    for (int i = 0; i < 4; ++i)
#pragma unroll
      for (int j = 0; j < 4; ++j)
        acc[i][j] = __builtin_amdgcn_mfma_f32_16x16x32_bf16(a[i], b[j], acc[i][j], 0, 0, 0);
  };

  stage(0, 0);
  for (int kt = 0; kt < nkt; ++kt) {
    __syncthreads();
    if (kt + 1 < nkt) stage((kt + 1) & 1, kt + 1);
    compute(kt & 1);
  }

#pragma unroll
  for (int i = 0; i < 4; ++i) {
#pragma unroll
    for (int r = 0; r < 4; ++r) {
      const int m = m0 + rm + i * 16 + kq * 4 + r;
#pragma unroll
      for (int j = 0; j < 4; ++j) {
        const int n = n0 + rn + j * 16 + lrow;
        if (n < N) {
          float v = acc[i][j][r] + (bias ? bias[n] : 0.f);
          if (ACT == 1) v = tanhf(v);
          if (MASK) {
            if (mask[(size_t)m * ldm + n] == 0) v = NEGV;
          }
          if (C) C[(size_t)m * ldc + n] = v;
          if (Cb) Cb[(size_t)m * ldcb + n] = __float2bfloat16(v);
        }
      }
    }
  }
}

// ---------------- fused 3-LSTM recurrence: bf16 MFMA, weight-stationary ----------------
// grid 96 = 3 lstm x 32 slices. Block owns 16 h-dims x 4 gates (64 W rows).
// Sync: RELAXED flags + sc0sc1 (coherence-point) data transfers. No
// acquire/release -> no buffer_inv/buffer_wbl2 cache maintenance per step.
// dyn LDS: W 64KB (swizzled) + h 16KB (swizzled) + gates 4KB = 86016 B.
__global__ __launch_bounds__(256) void lstm_kernel(
    const __hip_bfloat16* __restrict__ xp16,   // [3][2048][2048]
    const __hip_bfloat16* __restrict__ whh16,  // [3][2048][512]
    __hip_bfloat16* __restrict__ ehsb, __hip_bfloat16* __restrict__ catb,
    __hip_bfloat16* __restrict__ hbuf, int* __restrict__ flg) {
  const int l = blockIdx.x >> 5, g = blockIdx.x & 31;
  const int tid = threadIdx.x, lane = tid & 63, wid = tid >> 6;
  extern __shared__ char sm[];
  char* smW = sm;                                  // 65536
  char* smH = sm + 65536;                          // 16384
  float* gl = (float*)(sm + 65536 + 16384);        // 4096

  const __hip_bfloat16* wsrc = whh16 + (size_t)l * 2048 * 512;
  for (int p = tid; p < 4096; p += 256) {
    const int r = p >> 6, cb = (p & 63) << 4;
    const int grow = ((r >> 4) << 9) + (g << 4) + (r & 15);
    float4 v = *(const float4*)((const char*)(wsrc + (size_t)grow * 512) + cb);
    *(float4*)(smW + r * 1024 + (cb ^ ((r & 7) << 4))) = v;
  }

  const int d = tid >> 4, b = tid & 15;
  const int dg = (g << 4) + d;
  const int lrow = lane & 15, kq = lane >> 4;
  const int swz = (lrow & 7) << 4;
  const char* aB = smW + (wid * 16 + lrow) * 1024;
  const char* bB = smH + lrow * 1024;
  const bool rev = (l == 1);
  const __hip_bfloat16* xl = xp16 + (size_t)l * 2048 * 2048;
  float c = 0.f;

  for (int s = 0; s < 128; ++s) {
    const int t = rev ? 127 - s : s;
    const size_t xro = (size_t)(b * 128 + t) * 2048 + dg;
    const float xgi = __bfloat162float(xl[xro]);
    const float xgf = __bfloat162float(xl[xro + 512]);
    const float xgg = __bfloat162float(xl[xro + 1024]);
    const float xgo = __bfloat162float(xl[xro + 1536]);

    if (s > 0) {
      if (tid < 32) {
        const int* fp = flg + ((size_t)(l * 128 + (s - 1)) * 32 + tid) * 16;
        while (__hip_atomic_load(fp, __ATOMIC_RELAXED, __HIP_MEMORY_SCOPE_AGENT) == 0)
          __builtin_amdgcn_s_sleep(1);
      }
      __syncthreads();
      // flags set => producers' sc0sc1 stores already at coherence point;
      // sc0sc1 loads bypass (potentially stale) L1/L2.
      const char* hb = (const char*)(hbuf + ((size_t)l * 2 + ((s - 1) & 1)) * 8192);
      float4 d0, d1, d2, d3;
      const unsigned o0 = (unsigned)(tid * 16);
      asm volatile(
          "global_load_dwordx4 %0, %4, %8 sc0 sc1\n\t"
          "global_load_dwordx4 %1, %5, %8 sc0 sc1\n\t"
          "global_load_dwordx4 %2, %6, %8 sc0 sc1\n\t"
          "global_load_dwordx4 %3, %7, %8 sc0 sc1\n\t"
          "s_waitcnt vmcnt(0)"
          : "=&v"(d0), "=&v"(d1), "=&v"(d2), "=&v"(d3)
          : "v"(o0), "v"(o0 + 4096u), "v"(o0 + 8192u), "v"(o0 + 12288u), "s"(hb)
          : "memory");
      const float4 dd[4] = {d0, d1, d2, d3};
#pragma unroll
      for (int cc = 0; cc < 4; ++cc) {
        const int e = cc * 2048 + tid * 8;
        const int row = e >> 9, col = e & 511;
        *(float4*)(smH + row * 1024 + ((col * 2) ^ ((row & 7) << 4))) = dd[cc];
      }
    } else {
#pragma unroll
      for (int cc = 0; cc < 4; ++cc) {
        const int e = cc * 2048 + tid * 8;
        const int row = e >> 9, col = e & 511;
        *(float4*)(smH + row * 1024 + ((col * 2) ^ ((row & 7) << 4))) =
            make_float4(0.f, 0.f, 0.f, 0.f);
      }
    }
    __syncthreads();

    f32x4 acc0 = {0.f, 0.f, 0.f, 0.f}, acc1 = {0.f, 0.f, 0.f, 0.f};
#pragma unroll
    for (int kt = 0; kt < 16; kt += 2) {
      const int off0 = ((kt * 64 + (kq << 4)) ^ swz);
      const int off1 = (((kt + 1) * 64 + (kq << 4)) ^ swz);
      short8v a0 = *(const short8v*)(aB + off0);
      short8v b0 = *(const short8v*)(bB + off0);
      short8v a1 = *(const short8v*)(aB + off1);
      short8v b1 = *(const short8v*)(bB + off1);
      acc0 = __builtin_amdgcn_mfma_f32_16x16x32_bf16(a0, b0, acc0, 0, 0, 0);
      acc1 = __builtin_amdgcn_mfma_f32_16x16x32_bf16(a1, b1, acc1, 0, 0, 0);
    }
    f32x4 acc = acc0 + acc1;
#pragma unroll
    for (int r = 0; r < 4; ++r)
      gl[wid * 256 + (kq * 4 + r) * 16 + lrow] = acc[r];
    __syncthreads();

    const float gi = gl[d * 16 + b] + xgi;
    const float gf = gl[256 + d * 16 + b] + xgf;
    const float gg = gl[512 + d * 16 + b] + xgg;
    const float go = gl[768 + d * 16 + b] + xgo;
    const float si = 1.f / (1.f + __expf(-gi));
    const float sf = 1.f / (1.f + __expf(-gf));
    const float tg = tanhf(gg);
    const float so = 1.f / (1.f + __expf(-go));
    c = fmaf(sf, c, si * tg);
    const float h = so * tanhf(c);
    __hip_bfloat16 hb16 = __float2bfloat16(h);
    {
      // h slice store straight to coherence point (no dirty L2 line)
      char* hdst = (char*)(hbuf + ((size_t)l * 2 + (s & 1)) * 8192);
      const unsigned off = (unsigned)((b * 512 + dg) * 2);
      unsigned hv = *(unsigned short*)&hb16;
      asm volatile("global_store_short %0, %1, %2 sc0 sc1"
                   :: "v"(off), "v"(hv), "s"(hdst) : "memory");
    }
    const size_t orow = (size_t)(b * 128 + t);
    if (l == 0)      ehsb[orow * 1024 + dg] = hb16;
    else if (l == 1) ehsb[orow * 1024 + 512 + dg] = hb16;
    else             catb[orow * 1536 + dg] = hb16;
    asm volatile("s_waitcnt vmcnt(0)" ::: "memory");  // h stores acked at coherence pt
    __syncthreads();
    if (tid == 0)
      __hip_atomic_store(flg + ((size_t)(l * 128 + s) * 32 + g) * 16, 1,
                         __ATOMIC_RELAXED, __HIP_MEMORY_SCOPE_AGENT);
  }
}

// ---------------- attention: score + softmax + context, one block per (b,t) ----------------
__global__ __launch_bounds__(256) void attn_kernel(
    const float* __restrict__ dterm, const float* __restrict__ eterm,
    const float* __restrict__ v_att, const int* __restrict__ src_mask,
    const __hip_bfloat16* __restrict__ ehsb, __hip_bfloat16* __restrict__ catb) {
  const int bt = blockIdx.x;
  const int b = bt >> 7;
  const int tid = threadIdx.x;
  __shared__ float dt[512], vs[512], al[128], red[2 * 128], rtmp[2];
  dt[tid] = dterm[(size_t)bt * 512 + tid];
  dt[tid + 256] = dterm[(size_t)bt * 512 + 256 + tid];
  vs[tid] = v_att[tid];
  vs[tid + 256] = v_att[256 + tid];
  __syncthreads();
  const int nn = tid & 127, hh = tid >> 7;
  {
    const float* et = eterm + (size_t)(b * 128 + nn) * 512 + (hh << 8);
    const float* dth = dt + (hh << 8);
    const float* vsh = vs + (hh << 8);
    float p = 0.f;
    for (int a = 0; a < 256; ++a) p = fmaf(vsh[a], fast_tanh(dth[a] + et[a]), p);
    red[hh * 128 + nn] = p;
  }
  __syncthreads();
  if (tid < 128) {
    float s = red[tid] + red[128 + tid];
    if (src_mask[b * 128 + tid] == 0) s = NEGV;
    al[tid] = s;
  }
  __syncthreads();
  if (tid < 64) {
    float m = fmaxf(al[tid], al[tid + 64]);
    m = wave_max(m);
    if (tid == 0) rtmp[0] = m;
  }
  __syncthreads();
  if (tid < 128) al[tid] = expf(al[tid] - rtmp[0]);
  __syncthreads();
  if (tid < 64) {
    float s2 = al[tid] + al[tid + 64];
    s2 = wave_sum(s2);
    if (tid == 0) rtmp[1] = 1.f / s2;
  }
  __syncthreads();
  const float inv = rtmp[1];
  for (int h = tid; h < 1024; h += 256) {
    float a0 = 0.f;
    const __hip_bfloat16* eb = ehsb + (size_t)(b * 128) * 1024 + h;
    for (int n = 0; n < 128; ++n)
      a0 = fmaf(al[n], __bfloat162float(eb[(size_t)n * 1024]), a0);
    catb[(size_t)bt * 1536 + 512 + h] = __float2bfloat16(a0 * inv);
  }
}

// ---------------- pointer head assembly ----------------
__global__ __launch_bounds__(256) void pointer_kernel(
    const float* __restrict__ base, const float* __restrict__ wgout,
    const float* __restrict__ ptr_W, const float* __restrict__ ps_W,
    const float* __restrict__ ps_b, const int* __restrict__ src_mask,
    float* __restrict__ out0) {
  const int bt = blockIdx.x;
  const int b = bt >> 7, t = bt & 127;
  const int tid = threadIdx.x;
  __shared__ float r0[4], r1[4], r2[4], fin[3];
  float off_p = 0.f, diag_p = 0.f, sent_p;
  if (tid < 128) {
    const float ba = base[(size_t)bt * 128 + tid];
    const float pw = ps_W[tid];
    off_p = tanhf(ba) * pw;
    diag_p = tanhf(ba + ptr_W[tid * 513 + 512]) * pw;
  }
  sent_p = wgout[(size_t)bt * 512 + tid] + wgout[(size_t)bt * 512 + 256 + tid];
  off_p = wave_sum(off_p);
  diag_p = wave_sum(diag_p);
  sent_p = wave_sum(sent_p);
  const int wid = tid >> 6, lane = tid & 63;
  if (lane == 0) { r0[wid] = off_p; r1[wid] = diag_p; r2[wid] = sent_p; }
  __syncthreads();
  if (tid == 0) {
    const float psb = ps_b[0];
    fin[0] = r0[0] + r0[1] + r0[2] + r0[3] + psb;
    fin[1] = r1[0] + r1[1] + r1[2] + r1[3] + psb;
    fin[2] = r2[0] + r2[1] + r2[2] + r2[3];
  }
  __syncthreads();
  const float s_off = fin[0], s_diag = fin[1], sent = fin[2];
  if (tid < 129) {
    float v;
    if (tid == 128) v = sent;
    else {
      v = (tid == t) ? s_diag : s_off;
      if (src_mask[b * 128 + tid] == 0) v = NEGV;
    }
    out0[(size_t)bt * 129 + tid] = v;
  }
}

// ---------------- launch ----------------
extern "C" void kernel_launch(void* const* d_in, const int* in_sizes, int n_in,
                              void* d_out, int out_size, void* d_ws, size_t ws_size,
                              hipStream_t stream) {
  const int* src_ids   = (const int*)d_in[0];
  const int* src_mask  = (const int*)d_in[1];
  const int* cmask     = (const int*)d_in[2];
  const float* emb     = (const float*)d_in[3];
  const float* Wih_f   = (const float*)d_in[4];
  const float* Whh_f   = (const float*)d_in[5];
  const float* b_f     = (const float*)d_in[6];
  const float* Wih_b   = (const float*)d_in[7];
  const float* Whh_b   = (const float*)d_in[8];
  const float* b_b     = (const float*)d_in[9];
  const float* Wih_d   = (const float*)d_in[10];
  const float* Whh_d   = (const float*)d_in[11];
  const float* b_d     = (const float*)d_in[12];
  const float* W1      = (const float*)d_in[13];
  const float* W2      = (const float*)d_in[14];
  const float* v_att   = (const float*)d_in[15];
  const float* comb_W  = (const float*)d_in[16];
  const float* comb_b  = (const float*)d_in[17];
  const float* vocab_W = (const float*)d_in[18];
  const float* vocab_b = (const float*)d_in[19];
  const float* Wg_W    = (const float*)d_in[20];
  const float* Wg_b    = (const float*)d_in[21];
  const float* ptr_W   = (const float*)d_in[22];
  const float* ptr_b   = (const float*)d_in[23];
  const float* ps_W    = (const float*)d_in[24];
  const float* ps_b    = (const float*)d_in[25];
  (void)in_sizes; (void)n_in; (void)out_size; (void)ws_size;

  char* wsb = (char*)d_ws;
  size_t o = 0;
  auto alloc = [&](size_t bytes) { char* p = wsb + o; o = (o + bytes + 255) & ~(size_t)255; return p; };
  __hip_bfloat16* xb      = (__hip_bfloat16*)alloc((size_t)BN_ * E_ * 2);
  __hip_bfloat16* xproj16 = (__hip_bfloat16*)alloc((size_t)3 * BN_ * 2048 * 2);
  __hip_bfloat16* ehsb    = (__hip_bfloat16*)alloc((size_t)BN_ * 1024 * 2);
  __hip_bfloat16* catb    = (__hip_bfloat16*)alloc((size_t)BN_ * 1536 * 2);
  float* dterm            = (float*)alloc((size_t)BN_ * 512 * 4);
  float* eterm            = (float*)alloc((size_t)BN_ * 512 * 4);
  __hip_bfloat16* combb   = (__hip_bfloat16*)alloc((size_t)BN_ * 512 * 2);
  float* wgout            = (float*)alloc((size_t)BN_ * 512 * 4);
  float* baseb            = (float*)alloc((size_t)BN_ * 128 * 4);
  __hip_bfloat16* hbuf    = (__hip_bfloat16*)alloc((size_t)3 * 2 * 16 * 512 * 2);
  int* flg                = (int*)alloc((size_t)3 * 128 * 32 * 16 * 4);
  __hip_bfloat16* wihf16  = (__hip_bfloat16*)alloc((size_t)2048 * 384 * 2);
  __hip_bfloat16* wihb16  = (__hip_bfloat16*)alloc((size_t)2048 * 384 * 2);
  __hip_bfloat16* wihd16  = (__hip_bfloat16*)alloc((size_t)2048 * 384 * 2);
  __hip_bfloat16* whh16   = (__hip_bfloat16*)alloc((size_t)3 * 2048 * 512 * 2);
  __hip_bfloat16* w1_16   = (__hip_bfloat16*)alloc((size_t)512 * 512 * 2);
  __hip_bfloat16* w2_16   = (__hip_bfloat16*)alloc((size_t)512 * 1024 * 2);
  __hip_bfloat16* combw16 = (__hip_bfloat16*)alloc((size_t)512 * 1536 * 2);
  __hip_bfloat16* vocw16  = (__hip_bfloat16*)alloc((size_t)8000 * 512 * 2);
  __hip_bfloat16* wgw16   = (__hip_bfloat16*)alloc((size_t)512 * 512 * 2);
  __hip_bfloat16* ptrw16  = (__hip_bfloat16*)alloc((size_t)128 * 512 * 2);

  float* out0 = (float*)d_out;
  float* out1 = out0 + (size_t)BN_ * 129;

  hipMemsetAsync(flg, 0, (size_t)3 * 128 * 32 * 16 * 4, stream);
  embed_kernel<<<BN_, 256, 0, stream>>>(src_ids, emb, xb);

  CastArgs ca;
  const float* srcs[12] = {Wih_f, Wih_b, Wih_d, Whh_f, Whh_b, Whh_d,
                           W1, W2, comb_W, vocab_W, Wg_W, ptr_W};
  __hip_bfloat16* dsts[12] = {wihf16, wihb16, wihd16, whh16, whh16 + 2048 * 512,
                              whh16 + 2 * 2048 * 512, w1_16, w2_16, combw16,
                              vocw16, wgw16, ptrw16};
  int ns[12] = {2048 * 384, 2048 * 384, 2048 * 384, 2048 * 512, 2048 * 512,
                2048 * 512, 512 * 512, 512 * 1024, 512 * 1536, 8000 * 512,
                512 * 512, 128 * 512};
  int acc = 0;
  for (int k = 0; k < 12; ++k) {
    ca.s[k] = srcs[k];
    ca.d[k] = (unsigned long long)dsts[k];
    ca.base[k] = acc;
    acc += ns[k];
  }
  ca.total = acc;
  cast_kernel<<<2048, 256, 0, stream>>>(ca);

  // input projections (bias folded), bf16 out
  bgemm_kernel<0, false><<<dim3(16, 16), 256, 0, stream>>>(
      xb, E_, wihf16, E_, b_f, nullptr, 0, xproj16, 2048, BN_, 2048, E_, nullptr, 0);
  bgemm_kernel<0, false><<<dim3(16, 16), 256, 0, stream>>>(
      xb, E_, wihb16, E_, b_b, nullptr, 0, xproj16 + (size_t)BN_ * 2048, 2048, BN_, 2048, E_, nullptr, 0);
  bgemm_kernel<0, false><<<dim3(16, 16), 256, 0, stream>>>(
      xb, E_, wihd16, E_, b_d, nullptr, 0, xproj16 + (size_t)2 * BN_ * 2048, 2048, BN_, 2048, E_, nullptr, 0);

  hipFuncSetAttribute((const void*)lstm_kernel,
                      hipFuncAttributeMaxDynamicSharedMemorySize, 86016);
  lstm_kernel<<<96, 256, 86016, stream>>>(xproj16, whh16, ehsb, catb, hbuf, flg);

  // dterm = dec_h @ W1^T ; eterm = enc_hs @ W2^T
  bgemm_kernel<0, false><<<dim3(4, 16), 256, 0, stream>>>(
      catb, 1536, w1_16, 512, nullptr, dterm, 512, nullptr, 0, BN_, 512, 512, nullptr, 0);
  bgemm_kernel<0, false><<<dim3(4, 16), 256, 0, stream>>>(
      ehsb, 1024, w2_16, 1024, nullptr, eterm, 512, nullptr, 0, BN_, 512, 1024, nullptr, 0);

  attn_kernel<<<BN_, 256, 0, stream>>>(dterm, eterm, v_att, src_mask, ehsb, catb);

  // combined = tanh(cat @ comb_W^T + comb_b) -> bf16
  bgemm_kernel<1, false><<<dim3(4, 16), 256, 0, stream>>>(
      catb, 1536, combw16, 1536, comb_b, nullptr, 0, combb, 512, BN_, 512, 1536, nullptr, 0);

  // vocab logits + confusionset mask
  bgemm_kernel<0, true><<<dim3(63, 16), 256, 0, stream>>>(
      combb, 512, vocw16, 512, vocab_b, out1, V_, nullptr, 0, BN_, V_, 512, cmask, V_);

  // wgout = tanh(comb @ Wg^T + b)
  bgemm_kernel<1, false><<<dim3(4, 16), 256, 0, stream>>>(
      combb, 512, wgw16, 512, Wg_b, wgout, 512, nullptr, 0, BN_, 512, 512, nullptr, 0);

  // base = comb @ ptr_W[:,:512]^T + ptr_b
  bgemm_kernel<0, false><<<dim3(1, 16), 256, 0, stream>>>(
      combb, 512, ptrw16, 512, ptr_b, baseb, 128, nullptr, 0, BN_, 128, 512, nullptr, 0);

  pointer_kernel<<<BN_, 256, 0, stream>>>(baseb, wgout, ptr_W, ps_W, ps_b, src_mask, out0);
}

// Round 4
// 766.032 us; speedup vs baseline: 3.0530x; 1.0674x over previous
//
#include <hip/hip_runtime.h>
#include <hip/hip_bf16.h>
#include <math.h>

#define NEGV -1000000000.0f

static constexpr int B_ = 16, N_ = 128, BN_ = 2048;
static constexpr int E_ = 384, V_ = 8000;

typedef __attribute__((ext_vector_type(8))) short short8v;
typedef __attribute__((ext_vector_type(4))) float f32x4;
typedef __attribute__((ext_vector_type(4))) int i32x4;

// ---------------- helpers ----------------
__device__ inline float wave_sum(float v) {
#pragma unroll
  for (int o = 32; o; o >>= 1) v += __shfl_xor(v, o);
  return v;
}
__device__ inline float wave_max(float v) {
#pragma unroll
  for (int o = 32; o; o >>= 1) v = fmaxf(v, __shfl_xor(v, o));
  return v;
}
__device__ inline float fast_tanh(float x) {
  return 1.f - 2.f / (1.f + __expf(2.f * x));
}
__device__ inline float fast_sig(float x) {
  return 1.f / (1.f + __expf(-x));
}
__device__ __forceinline__ void gl16(const void* g, void* l) {
  __builtin_amdgcn_global_load_lds((const __attribute__((address_space(1))) void*)g,
                                   (__attribute__((address_space(3))) void*)l, 16, 0, 0);
}

// ---------------- embedding gather -> bf16 ----------------
__global__ __launch_bounds__(256) void embed_kernel(
    const int* __restrict__ ids, const float* __restrict__ emb,
    __hip_bfloat16* __restrict__ xb) {
  const int row = blockIdx.x;
  const int id = ids[row];
  for (int e = threadIdx.x; e < E_; e += 256)
    xb[(size_t)row * E_ + e] = __float2bfloat16(emb[(size_t)id * E_ + e]);
}

// ---------------- multi-segment fp32 -> bf16 cast ----------------
struct CastArgs {
  const float* s[12];
  unsigned long long d[12];
  int base[12];
  int total;
};
__global__ __launch_bounds__(256) void cast_kernel(CastArgs a) {
  const int nq = a.total >> 2;
  for (int q = blockIdx.x * 256 + threadIdx.x; q < nq; q += gridDim.x * 256) {
    const int e = q << 2;
    int k = 11;
    while (e < a.base[k]) --k;
    const int i = e - a.base[k];
    __hip_bfloat16* dst = (__hip_bfloat16*)a.d[k] + i;
    if (k == 11) {  // ptr_W: pack [128][513] cols 0..511 -> [128][512]
      const int row = i >> 9, col = i & 511;
      const float* sp = a.s[k] + (size_t)row * 513 + col;
#pragma unroll
      for (int u = 0; u < 4; ++u) dst[u] = __float2bfloat16(sp[u]);
    } else {
      float4 v = *(const float4*)(a.s[k] + i);
      __hip_bfloat16 h0 = __float2bfloat16(v.x), h1 = __float2bfloat16(v.y);
      __hip_bfloat16 h2 = __float2bfloat16(v.z), h3 = __float2bfloat16(v.w);
      ushort4 u4 = {*(unsigned short*)&h0, *(unsigned short*)&h1,
                    *(unsigned short*)&h2, *(unsigned short*)&h3};
      *(ushort4*)dst = u4;
    }
  }
}

// ---------------- bf16 MFMA GEMM: out = act(A @ W^T + bias) [+mask] ----------------
// A[M][lda] bf16, W[N][ldw] bf16 row-major. 128x128 tile, BK=32, 4 waves.
// TROUT=1: write Cb transposed as etT[((m>>7)*512 + n)*128 + (m&127)].
// Batched via blockIdx.z with element strides aB/wB/cB (Cb only).
template <int ACT, bool MASK, int TROUT>
__global__ __launch_bounds__(256) void bgemm_kernel(
    const __hip_bfloat16* __restrict__ A, int lda,
    const __hip_bfloat16* __restrict__ W, int ldw,
    const float* __restrict__ bias,
    float* __restrict__ C, int ldc,
    __hip_bfloat16* __restrict__ Cb, int ldcb,
    int M, int N, int K,
    const int* __restrict__ mask, int ldm,
    long aBs, long wBs, long cBs) {
  __shared__ __hip_bfloat16 Al[2][4096];
  __shared__ __hip_bfloat16 Bl[2][4096];
  A += (size_t)blockIdx.z * aBs;
  W += (size_t)blockIdx.z * wBs;
  const int tid = threadIdx.x;
  const int wid = tid >> 6, lane = tid & 63;
  const int m0 = blockIdx.y * 128, n0 = blockIdx.x * 128;
  const int nkt = K >> 5;
  const int rm = (wid >> 1) << 6, rn = (wid & 1) << 6;
  const int lrow = lane & 15, kq = lane >> 4;
  const int fs = ((lrow >> 1) & 3) << 4;

  f32x4 acc[4][4];
#pragma unroll
  for (int i = 0; i < 4; ++i)
#pragma unroll
    for (int j = 0; j < 4; ++j) acc[i][j] = {0.f, 0.f, 0.f, 0.f};

  auto stage = [&](int bi, int kt) {
#pragma unroll
    for (int c = 0; c < 2; ++c) {
      const int p = ((c * 4 + wid) << 6) + lane;
      const int row = p >> 2, cb = (p & 3) << 4;
      const int sw = ((row >> 1) & 3) << 4;
      const unsigned loff = (unsigned)__builtin_amdgcn_readfirstlane((c * 4 + wid) << 10);
      {
        const char* src = (const char*)A + ((size_t)(m0 + row) * lda + (size_t)kt * 32) * 2 + (cb ^ sw);
        gl16(src, (char*)&Al[bi][0] + loff);
      }
      {
        int gr = n0 + row;
        if (gr >= N) gr = N - 1;
        const char* src = (const char*)W + ((size_t)gr * ldw + (size_t)kt * 32) * 2 + (cb ^ sw);
        gl16(src, (char*)&Bl[bi][0] + loff);
      }
    }
  };
  auto compute = [&](int bi) {
    const char* Ab = (const char*)&Al[bi][0];
    const char* Bb = (const char*)&Bl[bi][0];
    const int roff = (kq << 4) ^ fs;
    short8v a[4], b[4];
#pragma unroll
    for (int i = 0; i < 4; ++i)
      a[i] = *(const short8v*)(Ab + (rm + i * 16 + lrow) * 64 + roff);
#pragma unroll
    for (int j = 0; j < 4; ++j)
      b[j] = *(const short8v*)(Bb + (rn + j * 16 + lrow) * 64 + roff);
#pragma unroll
    for (int i = 0; i < 4; ++i)
#pragma unroll
      for (int j = 0; j < 4; ++j)
        acc[i][j] = __builtin_amdgcn_mfma_f32_16x16x32_bf16(a[i], b[j], acc[i][j], 0, 0, 0);
  };

  stage(0, 0);
  for (int kt = 0; kt < nkt; ++kt) {
    __syncthreads();
    if (kt + 1 < nkt) stage((kt + 1) & 1, kt + 1);
    compute(kt & 1);
  }

#pragma unroll
  for (int i = 0; i < 4; ++i) {
#pragma unroll
    for (int r = 0; r < 4; ++r) {
      const int m = m0 + rm + i * 16 + kq * 4 + r;
#pragma unroll
      for (int j = 0; j < 4; ++j) {
        const int n = n0 + rn + j * 16 + lrow;
        if (n < N) {
          float v = acc[i][j][r] + (bias ? bias[n] : 0.f);
          if (ACT == 1) v = tanhf(v);
          if (MASK) {
            if (mask[(size_t)m * ldm + n] == 0) v = NEGV;
          }
          if (TROUT == 1) {
            Cb[(((size_t)(m >> 7) * 512 + n) << 7) + (m & 127)] = __float2bfloat16(v);
          } else {
            if (C) C[(size_t)m * ldc + n] = v;
            if (Cb) Cb[(size_t)m * ldcb + n + (size_t)blockIdx.z * cBs] = __float2bfloat16(v);
          }
        }
      }
    }
  }
}

// ---------------- fused 3-LSTM recurrence: bf16 MFMA, weight-stationary ----------------
// grid 96 = 3 lstm x 32 slices. Block owns 16 h-dims x 4 gates (64 W rows).
// h exchange: LDS-packed 512B per block, stored via 32 sc0sc1 dwordx4 by wave0
// only (only wave0 pays the coherence-point ack); wave1 polls relaxed flags.
// dyn LDS: W 64KB + h 16KB + gl 4480B + hout 512B = 86912 B.
__global__ __launch_bounds__(256) void lstm_kernel(
    const __hip_bfloat16* __restrict__ xp16,   // [3][2048][2048]
    const __hip_bfloat16* __restrict__ whh16,  // [3][2048][512]
    __hip_bfloat16* __restrict__ ehsb, __hip_bfloat16* __restrict__ ehsT,
    __hip_bfloat16* __restrict__ catb,
    __hip_bfloat16* __restrict__ hbuf, int* __restrict__ flg) {
  const int l = blockIdx.x >> 5, g = blockIdx.x & 31;
  const int tid = threadIdx.x, lane = tid & 63, wid = tid >> 6;
  extern __shared__ char sm[];
  char* smW = sm;                                   // 65536
  char* smH = sm + 65536;                           // 16384
  float* gl = (float*)(sm + 65536 + 16384);         // 4*280*4 = 4480
  __hip_bfloat16* hout = (__hip_bfloat16*)(sm + 65536 + 16384 + 4480);  // 512

  const __hip_bfloat16* wsrc = whh16 + (size_t)l * 2048 * 512;
  for (int p = tid; p < 4096; p += 256) {
    const int r = p >> 6, cb = (p & 63) << 4;
    const int grow = ((r >> 4) << 9) + (g << 4) + (r & 15);
    float4 v = *(const float4*)((const char*)(wsrc + (size_t)grow * 512) + cb);
    *(float4*)(smW + r * 1024 + (cb ^ ((r & 7) << 4))) = v;
  }

  const int d = tid & 15, b = tid >> 4;
  const int dg = (g << 4) + d;
  const int lrow = lane & 15, kq = lane >> 4;
  const int swz = (lrow & 7) << 4;
  const char* aB = smW + (wid * 16 + lrow) * 1024;
  const char* bB = smH + lrow * 1024;
  const bool rev = (l == 1);
  const __hip_bfloat16* xl = xp16 + (size_t)l * 2048 * 2048;
  float c = 0.f;

  for (int s = 0; s < 128; ++s) {
    const int t = rev ? 127 - s : s;
    const size_t xro = (size_t)(b * 128 + t) * 2048 + dg;
    const float xgi = __bfloat162float(xl[xro]);
    const float xgf = __bfloat162float(xl[xro + 512]);
    const float xgg = __bfloat162float(xl[xro + 1024]);
    const float xgo = __bfloat162float(xl[xro + 1536]);

    if (s > 0) {
      if (tid >= 64 && tid < 96) {
        const int* fp = flg + ((size_t)(l * 128 + (s - 1)) * 32 + (tid - 64)) * 16;
        while (__hip_atomic_load(fp, __ATOMIC_RELAXED, __HIP_MEMORY_SCOPE_AGENT) == 0)
          __builtin_amdgcn_s_sleep(1);
      }
      __syncthreads();
      // flags set => producers' sc0sc1 stores already at coherence point.
      const char* hb = (const char*)(hbuf + ((size_t)(l * 2 + ((s - 1) & 1)) * 32) * 256);
      float4 d0, d1, d2, d3;
      const unsigned o0 = (unsigned)(tid * 16);
      asm volatile(
          "global_load_dwordx4 %0, %4, %8 sc0 sc1\n\t"
          "global_load_dwordx4 %1, %5, %8 sc0 sc1\n\t"
          "global_load_dwordx4 %2, %6, %8 sc0 sc1\n\t"
          "global_load_dwordx4 %3, %7, %8 sc0 sc1\n\t"
          "s_waitcnt vmcnt(0)"
          : "=&v"(d0), "=&v"(d1), "=&v"(d2), "=&v"(d3)
          : "v"(o0), "v"(o0 + 4096u), "v"(o0 + 8192u), "v"(o0 + 12288u), "s"(hb)
          : "memory");
      const float4 dd4[4] = {d0, d1, d2, d3};
#pragma unroll
      for (int cc = 0; cc < 4; ++cc) {
        const int idx = cc * 2048 + tid * 8;  // element in [g'][b][d]
        const int gp = idx >> 8, rem = idx & 255;
        const int bb = rem >> 4, d0e = rem & 15;
        *(float4*)(smH + bb * 1024 + ((gp * 32 + d0e * 2) ^ ((bb & 7) << 4))) = dd4[cc];
      }
    } else {
      for (int idx = tid * 8; idx < 8192; idx += 2048) {
        const int gp = idx >> 8, rem = idx & 255;
        const int bb = rem >> 4, d0e = rem & 15;
        *(float4*)(smH + bb * 1024 + ((gp * 32 + d0e * 2) ^ ((bb & 7) << 4))) =
            make_float4(0.f, 0.f, 0.f, 0.f);
      }
    }
    __syncthreads();

    f32x4 acc0 = {0.f, 0.f, 0.f, 0.f}, acc1 = {0.f, 0.f, 0.f, 0.f};
#pragma unroll
    for (int kt = 0; kt < 16; kt += 2) {
      const int off0 = ((kt * 64 + (kq << 4)) ^ swz);
      const int off1 = (((kt + 1) * 64 + (kq << 4)) ^ swz);
      short8v a0 = *(const short8v*)(aB + off0);
      short8v b0 = *(const short8v*)(bB + off0);
      short8v a1 = *(const short8v*)(aB + off1);
      short8v b1 = *(const short8v*)(bB + off1);
      acc0 = __builtin_amdgcn_mfma_f32_16x16x32_bf16(a0, b0, acc0, 0, 0, 0);
      acc1 = __builtin_amdgcn_mfma_f32_16x16x32_bf16(a1, b1, acc1, 0, 0, 0);
    }
    f32x4 acc = acc0 + acc1;
    // D[row=kq*4+r][col=lrow]: row = dim-within-gate, col = batch
#pragma unroll
    for (int r = 0; r < 4; ++r)
      gl[wid * 280 + (kq * 4 + r) * 17 + lrow] = acc[r];
    __syncthreads();

    const float gi = gl[0 * 280 + d * 17 + b] + xgi;
    const float gf = gl[1 * 280 + d * 17 + b] + xgf;
    const float gg = gl[2 * 280 + d * 17 + b] + xgg;
    const float go = gl[3 * 280 + d * 17 + b] + xgo;
    const float si = fast_sig(gi);
    const float sf = fast_sig(gf);
    const float tg = fast_tanh(gg);
    const float so = fast_sig(go);
    c = fmaf(sf, c, si * tg);
    const float h = so * fast_tanh(c);
    __hip_bfloat16 hb16 = __float2bfloat16(h);
    const size_t orow = (size_t)(b * 128 + t);
    if (l == 0) {
      ehsb[orow * 1024 + dg] = hb16;
      ehsT[((size_t)b * 1024 + dg) * 128 + t] = hb16;
    } else if (l == 1) {
      ehsb[orow * 1024 + 512 + dg] = hb16;
      ehsT[((size_t)b * 1024 + 512 + dg) * 128 + t] = hb16;
    } else {
      catb[orow * 1536 + dg] = hb16;
    }
    hout[tid] = hb16;  // tid = b*16+d
    __syncthreads();
    if (tid < 64) {
      if (tid < 32) {
        f32x4 hv = *(const f32x4*)(hout + tid * 8);
        char* hdst = (char*)(hbuf + ((size_t)((l * 2 + (s & 1)) * 32 + g)) * 256);
        const unsigned off = (unsigned)(tid * 16);
        asm volatile("global_store_dwordx4 %0, %1, %2 sc0 sc1"
                     :: "v"(off), "v"(hv), "s"(hdst) : "memory");
      }
      asm volatile("s_waitcnt vmcnt(0)" ::: "memory");
      if (tid == 0)
        __hip_atomic_store(flg + ((size_t)(l * 128 + s) * 32 + g) * 16, 1,
                           __ATOMIC_RELAXED, __HIP_MEMORY_SCOPE_AGENT);
    }
  }
}

// ---------------- score + softmax -> alpha (bf16), one block per (b,t) ----------------
__global__ __launch_bounds__(256) void score_kernel(
    const float* __restrict__ dterm, const __hip_bfloat16* __restrict__ etT,
    const float* __restrict__ v_att, const int* __restrict__ src_mask,
    __hip_bfloat16* __restrict__ alphab) {
  const int bt = blockIdx.x, b = bt >> 7;
  const int tid = threadIdx.x;
  __shared__ float dt[512], vs[512], red[4][128], al[128], rtmp[2];
  dt[tid] = dterm[(size_t)bt * 512 + tid];
  dt[tid + 256] = dterm[(size_t)bt * 512 + 256 + tid];
  vs[tid] = v_att[tid];
  vs[tid + 256] = v_att[256 + tid];
  __syncthreads();
  const int n0 = (tid & 63) << 1, ah = tid >> 6;
  {
    const __hip_bfloat16* ep = etT + (((size_t)b * 512 + ah * 128) << 7) + n0;
    const float* dp = dt + ah * 128;
    const float* vp = vs + ah * 128;
    float p0 = 0.f, p1 = 0.f;
    for (int a = 0; a < 128; ++a) {
      const unsigned u = *(const unsigned*)(ep + ((size_t)a << 7));
      unsigned u0 = u << 16, u1 = u & 0xffff0000u;
      const float e0 = *(float*)&u0, e1 = *(float*)&u1;
      const float da = dp[a], va = vp[a];
      p0 = fmaf(va, fast_tanh(da + e0), p0);
      p1 = fmaf(va, fast_tanh(da + e1), p1);
    }
    red[ah][n0] = p0;
    red[ah][n0 + 1] = p1;
  }
  __syncthreads();
  if (tid < 128) {
    float s = red[0][tid] + red[1][tid] + red[2][tid] + red[3][tid];
    if (src_mask[b * 128 + tid] == 0) s = NEGV;
    al[tid] = s;
  }
  __syncthreads();
  if (tid < 64) {
    float m = fmaxf(al[tid], al[tid + 64]);
    m = wave_max(m);
    if (tid == 0) rtmp[0] = m;
  }
  __syncthreads();
  if (tid < 128) al[tid] = __expf(al[tid] - rtmp[0]);
  __syncthreads();
  if (tid < 64) {
    float s2 = al[tid] + al[tid + 64];
    s2 = wave_sum(s2);
    if (tid == 0) rtmp[1] = 1.f / s2;
  }
  __syncthreads();
  if (tid < 128)
    alphab[(size_t)bt * 128 + tid] = __float2bfloat16(al[tid] * rtmp[1]);
}

// ---------------- pointer head assembly ----------------
__global__ __launch_bounds__(256) void pointer_kernel(
    const float* __restrict__ base, const float* __restrict__ wgout,
    const float* __restrict__ ptr_W, const float* __restrict__ ps_W,
    const float* __restrict__ ps_b, const int* __restrict__ src_mask,
    float* __restrict__ out0) {
  const int bt = blockIdx.x;
  const int b = bt >> 7, t = bt & 127;
  const int tid = threadIdx.x;
  __shared__ float r0[4], r1[4], r2[4], fin[3];
  float off_p = 0.f, diag_p = 0.f, sent_p;
  if (tid < 128) {
    const float ba = base[(size_t)bt * 128 + tid];
    const float pw = ps_W[tid];
    off_p = tanhf(ba) * pw;
    diag_p = tanhf(ba + ptr_W[tid * 513 + 512]) * pw;
  }
  sent_p = wgout[(size_t)bt * 512 + tid] + wgout[(size_t)bt * 512 + 256 + tid];
  off_p = wave_sum(off_p);
  diag_p = wave_sum(diag_p);
  sent_p = wave_sum(sent_p);
  const int wid = tid >> 6, lane = tid & 63;
  if (lane == 0) { r0[wid] = off_p; r1[wid] = diag_p; r2[wid] = sent_p; }
  __syncthreads();
  if (tid == 0) {
    const float psb = ps_b[0];
    fin[0] = r0[0] + r0[1] + r0[2] + r0[3] + psb;
    fin[1] = r1[0] + r1[1] + r1[2] + r1[3] + psb;
    fin[2] = r2[0] + r2[1] + r2[2] + r2[3];
  }
  __syncthreads();
  const float s_off = fin[0], s_diag = fin[1], sent = fin[2];
  if (tid < 129) {
    float v;
    if (tid == 128) v = sent;
    else {
      v = (tid == t) ? s_diag : s_off;
      if (src_mask[b * 128 + tid] == 0) v = NEGV;
    }
    out0[(size_t)bt * 129 + tid] = v;
  }
}

// ---------------- launch ----------------
extern "C" void kernel_launch(void* const* d_in, const int* in_sizes, int n_in,
                              void* d_out, int out_size, void* d_ws, size_t ws_size,
                              hipStream_t stream) {
  const int* src_ids   = (const int*)d_in[0];
  const int* src_mask  = (const int*)d_in[1];
  const int* cmask     = (const int*)d_in[2];
  const float* emb     = (const float*)d_in[3];
  const float* Wih_f   = (const float*)d_in[4];
  const float* Whh_f   = (const float*)d_in[5];
  const float* b_f     = (const float*)d_in[6];
  const float* Wih_b   = (const float*)d_in[7];
  const float* Whh_b   = (const float*)d_in[8];
  const float* b_b     = (const float*)d_in[9];
  const float* Wih_d   = (const float*)d_in[10];
  const float* Whh_d   = (const float*)d_in[11];
  const float* b_d     = (const float*)d_in[12];
  const float* W1      = (const float*)d_in[13];
  const float* W2      = (const float*)d_in[14];
  const float* v_att   = (const float*)d_in[15];
  const float* comb_W  = (const float*)d_in[16];
  const float* comb_b  = (const float*)d_in[17];
  const float* vocab_W = (const float*)d_in[18];
  const float* vocab_b = (const float*)d_in[19];
  const float* Wg_W    = (const float*)d_in[20];
  const float* Wg_b    = (const float*)d_in[21];
  const float* ptr_W   = (const float*)d_in[22];
  const float* ptr_b   = (const float*)d_in[23];
  const float* ps_W    = (const float*)d_in[24];
  const float* ps_b    = (const float*)d_in[25];
  (void)in_sizes; (void)n_in; (void)out_size; (void)ws_size;

  char* wsb = (char*)d_ws;
  size_t o = 0;
  auto alloc = [&](size_t bytes) { char* p = wsb + o; o = (o + bytes + 255) & ~(size_t)255; return p; };
  __hip_bfloat16* xb      = (__hip_bfloat16*)alloc((size_t)BN_ * E_ * 2);
  __hip_bfloat16* xproj16 = (__hip_bfloat16*)alloc((size_t)3 * BN_ * 2048 * 2);
  __hip_bfloat16* ehsb    = (__hip_bfloat16*)alloc((size_t)BN_ * 1024 * 2);
  __hip_bfloat16* ehsT    = (__hip_bfloat16*)alloc((size_t)16 * 1024 * 128 * 2);
  __hip_bfloat16* catb    = (__hip_bfloat16*)alloc((size_t)BN_ * 1536 * 2);
  float* dterm            = (float*)alloc((size_t)BN_ * 512 * 4);
  __hip_bfloat16* etT     = (__hip_bfloat16*)alloc((size_t)16 * 512 * 128 * 2);
  __hip_bfloat16* alphab  = (__hip_bfloat16*)alloc((size_t)BN_ * 128 * 2);
  __hip_bfloat16* combb   = (__hip_bfloat16*)alloc((size_t)BN_ * 512 * 2);
  float* wgout            = (float*)alloc((size_t)BN_ * 512 * 4);
  float* baseb            = (float*)alloc((size_t)BN_ * 128 * 4);
  __hip_bfloat16* hbuf    = (__hip_bfloat16*)alloc((size_t)3 * 2 * 32 * 256 * 2);
  int* flg                = (int*)alloc((size_t)3 * 128 * 32 * 16 * 4);
  __hip_bfloat16* wihf16  = (__hip_bfloat16*)alloc((size_t)2048 * 384 * 2);
  __hip_bfloat16* wihb16  = (__hip_bfloat16*)alloc((size_t)2048 * 384 * 2);
  __hip_bfloat16* wihd16  = (__hip_bfloat16*)alloc((size_t)2048 * 384 * 2);
  __hip_bfloat16* whh16   = (__hip_bfloat16*)alloc((size_t)3 * 2048 * 512 * 2);
  __hip_bfloat16* w1_16   = (__hip_bfloat16*)alloc((size_t)512 * 512 * 2);
  __hip_bfloat16* w2_16   = (__hip_bfloat16*)alloc((size_t)512 * 1024 * 2);
  __hip_bfloat16* combw16 = (__hip_bfloat16*)alloc((size_t)512 * 1536 * 2);
  __hip_bfloat16* vocw16  = (__hip_bfloat16*)alloc((size_t)8000 * 512 * 2);
  __hip_bfloat16* wgw16   = (__hip_bfloat16*)alloc((size_t)512 * 512 * 2);
  __hip_bfloat16* ptrw16  = (__hip_bfloat16*)alloc((size_t)128 * 512 * 2);

  float* out0 = (float*)d_out;
  float* out1 = out0 + (size_t)BN_ * 129;

  hipMemsetAsync(flg, 0, (size_t)3 * 128 * 32 * 16 * 4, stream);
  embed_kernel<<<BN_, 256, 0, stream>>>(src_ids, emb, xb);

  CastArgs ca;
  const float* srcs[12] = {Wih_f, Wih_b, Wih_d, Whh_f, Whh_b, Whh_d,
                           W1, W2, comb_W, vocab_W, Wg_W, ptr_W};
  __hip_bfloat16* dsts[12] = {wihf16, wihb16, wihd16, whh16, whh16 + 2048 * 512,
                              whh16 + 2 * 2048 * 512, w1_16, w2_16, combw16,
                              vocw16, wgw16, ptrw16};
  int ns[12] = {2048 * 384, 2048 * 384, 2048 * 384, 2048 * 512, 2048 * 512,
                2048 * 512, 512 * 512, 512 * 1024, 512 * 1536, 8000 * 512,
                512 * 512, 128 * 512};
  int acc = 0;
  for (int k = 0; k < 12; ++k) {
    ca.s[k] = srcs[k];
    ca.d[k] = (unsigned long long)dsts[k];
    ca.base[k] = acc;
    acc += ns[k];
  }
  ca.total = acc;
  cast_kernel<<<2048, 256, 0, stream>>>(ca);

  // input projections (bias folded), bf16 out
  bgemm_kernel<0, false, 0><<<dim3(16, 16), 256, 0, stream>>>(
      xb, E_, wihf16, E_, b_f, nullptr, 0, xproj16, 2048, BN_, 2048, E_, nullptr, 0, 0, 0, 0);
  bgemm_kernel<0, false, 0><<<dim3(16, 16), 256, 0, stream>>>(
      xb, E_, wihb16, E_, b_b, nullptr, 0, xproj16 + (size_t)BN_ * 2048, 2048, BN_, 2048, E_, nullptr, 0, 0, 0, 0);
  bgemm_kernel<0, false, 0><<<dim3(16, 16), 256, 0, stream>>>(
      xb, E_, wihd16, E_, b_d, nullptr, 0, xproj16 + (size_t)2 * BN_ * 2048, 2048, BN_, 2048, E_, nullptr, 0, 0, 0, 0);

  hipFuncSetAttribute((const void*)lstm_kernel,
                      hipFuncAttributeMaxDynamicSharedMemorySize, 86912);
  lstm_kernel<<<96, 256, 86912, stream>>>(xproj16, whh16, ehsb, ehsT, catb, hbuf, flg);

  // dterm = dec_h @ W1^T (f32) ; etT = transposed bf16 eterm
  bgemm_kernel<0, false, 0><<<dim3(4, 16), 256, 0, stream>>>(
      catb, 1536, w1_16, 512, nullptr, dterm, 512, nullptr, 0, BN_, 512, 512, nullptr, 0, 0, 0, 0);
  bgemm_kernel<0, false, 1><<<dim3(4, 16), 256, 0, stream>>>(
      ehsb, 1024, w2_16, 1024, nullptr, nullptr, 0, etT, 0, BN_, 512, 1024, nullptr, 0, 0, 0, 0);

  score_kernel<<<BN_, 256, 0, stream>>>(dterm, etT, v_att, src_mask, alphab);

  // context = alpha[b] @ ehsT[b]^T -> catb[:,512:1536] (batched over b)
  bgemm_kernel<0, false, 0><<<dim3(8, 1, 16), 256, 0, stream>>>(
      alphab, 128, ehsT, 128, nullptr, nullptr, 0, catb + 512, 1536,
      128, 1024, 128, nullptr, 0, 128 * 128, 1024 * 128, 128 * 1536);

  // combined = tanh(cat @ comb_W^T + comb_b) -> bf16
  bgemm_kernel<1, false, 0><<<dim3(4, 16), 256, 0, stream>>>(
      catb, 1536, combw16, 1536, comb_b, nullptr, 0, combb, 512, BN_, 512, 1536, nullptr, 0, 0, 0, 0);

  // vocab logits + confusionset mask
  bgemm_kernel<0, true, 0><<<dim3(63, 16), 256, 0, stream>>>(
      combb, 512, vocw16, 512, vocab_b, out1, V_, nullptr, 0, BN_, V_, 512, cmask, V_, 0, 0, 0);

  // wgout = tanh(comb @ Wg^T + b)
  bgemm_kernel<1, false, 0><<<dim3(4, 16), 256, 0, stream>>>(
      combb, 512, wgw16, 512, Wg_b, wgout, 512, nullptr, 0, BN_, 512, 512, nullptr, 0, 0, 0, 0);

  // base = comb @ ptr_W[:,:512]^T + ptr_b
  bgemm_kernel<0, false, 0><<<dim3(1, 16), 256, 0, stream>>>(
      combb, 512, ptrw16, 512, ptr_b, baseb, 128, nullptr, 0, BN_, 128, 512, nullptr, 0, 0, 0, 0);

  pointer_kernel<<<BN_, 256, 0, stream>>>(baseb, wgout, ptr_W, ps_W, ps_b, src_mask, out0);
}

// Round 5
// 751.536 us; speedup vs baseline: 3.1119x; 1.0193x over previous
//
#include <hip/hip_runtime.h>
#include <hip/hip_bf16.h>
#include <math.h>

#define NEGV -1000000000.0f

static constexpr int B_ = 16, N_ = 128, BN_ = 2048;
static constexpr int E_ = 384, V_ = 8000;

typedef __attribute__((ext_vector_type(8))) short short8v;
typedef __attribute__((ext_vector_type(4))) float f32x4;

// ---------------- helpers ----------------
__device__ inline float wave_sum(float v) {
#pragma unroll
  for (int o = 32; o; o >>= 1) v += __shfl_xor(v, o);
  return v;
}
__device__ inline float wave_max(float v) {
#pragma unroll
  for (int o = 32; o; o >>= 1) v = fmaxf(v, __shfl_xor(v, o));
  return v;
}
__device__ inline float fast_tanh(float x) {
  return 1.f - 2.f / (1.f + __expf(2.f * x));
}
__device__ inline float fast_sig(float x) {
  return 1.f / (1.f + __expf(-x));
}
// sentinel check: true iff no bf16 half equals 0x7f7f
__device__ inline int ok16(const float4& f) {
  const unsigned a = __float_as_uint(f.x), b = __float_as_uint(f.y);
  const unsigned c = __float_as_uint(f.z), d = __float_as_uint(f.w);
  int r = 1;
  r &= ((a & 0xffffu) != 0x7f7fu) & ((a >> 16) != 0x7f7fu);
  r &= ((b & 0xffffu) != 0x7f7fu) & ((b >> 16) != 0x7f7fu);
  r &= ((c & 0xffffu) != 0x7f7fu) & ((c >> 16) != 0x7f7fu);
  r &= ((d & 0xffffu) != 0x7f7fu) & ((d >> 16) != 0x7f7fu);
  return r;
}
__device__ __forceinline__ void gl16(const void* g, void* l) {
  __builtin_amdgcn_global_load_lds((const __attribute__((address_space(1))) void*)g,
                                   (__attribute__((address_space(3))) void*)l, 16, 0, 0);
}

// ---------------- embedding gather -> bf16 ----------------
__global__ __launch_bounds__(256) void embed_kernel(
    const int* __restrict__ ids, const float* __restrict__ emb,
    __hip_bfloat16* __restrict__ xb) {
  const int row = blockIdx.x;
  const int id = ids[row];
  for (int e = threadIdx.x; e < E_; e += 256)
    xb[(size_t)row * E_ + e] = __float2bfloat16(emb[(size_t)id * E_ + e]);
}

// ---------------- multi-segment fp32 -> bf16 cast ----------------
struct CastArgs {
  const float* s[12];
  unsigned long long d[12];
  int base[12];
  int total;
};
__global__ __launch_bounds__(256) void cast_kernel(CastArgs a) {
  const int nq = a.total >> 2;
  for (int q = blockIdx.x * 256 + threadIdx.x; q < nq; q += gridDim.x * 256) {
    const int e = q << 2;
    int k = 11;
    while (e < a.base[k]) --k;
    const int i = e - a.base[k];
    __hip_bfloat16* dst = (__hip_bfloat16*)a.d[k] + i;
    if (k == 11) {  // ptr_W: pack [128][513] cols 0..511 -> [128][512]
      const int row = i >> 9, col = i & 511;
      const float* sp = a.s[k] + (size_t)row * 513 + col;
#pragma unroll
      for (int u = 0; u < 4; ++u) dst[u] = __float2bfloat16(sp[u]);
    } else {
      float4 v = *(const float4*)(a.s[k] + i);
      __hip_bfloat16 h0 = __float2bfloat16(v.x), h1 = __float2bfloat16(v.y);
      __hip_bfloat16 h2 = __float2bfloat16(v.z), h3 = __float2bfloat16(v.w);
      ushort4 u4 = {*(unsigned short*)&h0, *(unsigned short*)&h1,
                    *(unsigned short*)&h2, *(unsigned short*)&h3};
      *(ushort4*)dst = u4;
    }
  }
}

// ---------------- bf16 MFMA GEMM: out = act(A @ W^T + bias) [+mask] ----------------
// A[M][lda] bf16, W[N][ldw] bf16 row-major. 128x128 tile, BK=32, 4 waves.
// TROUT=1: write Cb transposed as etT[((m>>7)*512 + n)*128 + (m&127)].
// Batched via blockIdx.z with element strides aB/wB/cB (Cb only).
template <int ACT, bool MASK, int TROUT>
__global__ __launch_bounds__(256) void bgemm_kernel(
    const __hip_bfloat16* __restrict__ A, int lda,
    const __hip_bfloat16* __restrict__ W, int ldw,
    const float* __restrict__ bias,
    float* __restrict__ C, int ldc,
    __hip_bfloat16* __restrict__ Cb, int ldcb,
    int M, int N, int K,
    const int* __restrict__ mask, int ldm,
    long aBs, long wBs, long cBs) {
  __shared__ __hip_bfloat16 Al[2][4096];
  __shared__ __hip_bfloat16 Bl[2][4096];
  A += (size_t)blockIdx.z * aBs;
  W += (size_t)blockIdx.z * wBs;
  const int tid = threadIdx.x;
  const int wid = tid >> 6, lane = tid & 63;
  const int m0 = blockIdx.y * 128, n0 = blockIdx.x * 128;
  const int nkt = K >> 5;
  const int rm = (wid >> 1) << 6, rn = (wid & 1) << 6;
  const int lrow = lane & 15, kq = lane >> 4;
  const int fs = ((lrow >> 1) & 3) << 4;

  f32x4 acc[4][4];
#pragma unroll
  for (int i = 0; i < 4; ++i)
#pragma unroll
    for (int j = 0; j < 4; ++j) acc[i][j] = {0.f, 0.f, 0.f, 0.f};

  auto stage = [&](int bi, int kt) {
#pragma unroll
    for (int c = 0; c < 2; ++c) {
      const int p = ((c * 4 + wid) << 6) + lane;
      const int row = p >> 2, cb = (p & 3) << 4;
      const int sw = ((row >> 1) & 3) << 4;
      const unsigned loff = (unsigned)__builtin_amdgcn_readfirstlane((c * 4 + wid) << 10);
      {
        const char* src = (const char*)A + ((size_t)(m0 + row) * lda + (size_t)kt * 32) * 2 + (cb ^ sw);
        gl16(src, (char*)&Al[bi][0] + loff);
      }
      {
        int gr = n0 + row;
        if (gr >= N) gr = N - 1;
        const char* src = (const char*)W + ((size_t)gr * ldw + (size_t)kt * 32) * 2 + (cb ^ sw);
        gl16(src, (char*)&Bl[bi][0] + loff);
      }
    }
  };
  auto compute = [&](int bi) {
    const char* Ab = (const char*)&Al[bi][0];
    const char* Bb = (const char*)&Bl[bi][0];
    const int roff = (kq << 4) ^ fs;
    short8v a[4], b[4];
#pragma unroll
    for (int i = 0; i < 4; ++i)
      a[i] = *(const short8v*)(Ab + (rm + i * 16 + lrow) * 64 + roff);
#pragma unroll
    for (int j = 0; j < 4; ++j)
      b[j] = *(const short8v*)(Bb + (rn + j * 16 + lrow) * 64 + roff);
#pragma unroll
    for (int i = 0; i < 4; ++i)
#pragma unroll
      for (int j = 0; j < 4; ++j)
        acc[i][j] = __builtin_amdgcn_mfma_f32_16x16x32_bf16(a[i], b[j], acc[i][j], 0, 0, 0);
  };

  stage(0, 0);
  for (int kt = 0; kt < nkt; ++kt) {
    __syncthreads();
    if (kt + 1 < nkt) stage((kt + 1) & 1, kt + 1);
    compute(kt & 1);
  }

#pragma unroll
  for (int i = 0; i < 4; ++i) {
#pragma unroll
    for (int r = 0; r < 4; ++r) {
      const int m = m0 + rm + i * 16 + kq * 4 + r;
#pragma unroll
      for (int j = 0; j < 4; ++j) {
        const int n = n0 + rn + j * 16 + lrow;
        if (n < N) {
          float v = acc[i][j][r] + (bias ? bias[n] : 0.f);
          if (ACT == 1) v = tanhf(v);
          if (MASK) {
            if (mask[(size_t)m * ldm + n] == 0) v = NEGV;
          }
          if (TROUT == 1) {
            Cb[(((size_t)(m >> 7) * 512 + n) << 7) + (m & 127)] = __float2bfloat16(v);
          } else {
            if (C) C[(size_t)m * ldc + n] = v;
            if (Cb) Cb[(size_t)m * ldcb + n + (size_t)blockIdx.z * cBs] = __float2bfloat16(v);
          }
        }
      }
    }
  }
}

// ---------------- fused 3-LSTM recurrence: bf16 MFMA, sentinel-poll sync ----------------
// grid 96 = 3 lstm x 32 slices. Block owns 16 h-dims x 4 gates.
// Whh rows LDS-reordered dim-major (lr = d_local*4 + gate) so MFMA acc[r] =
// gate r of one (d,b) in-register: no gate LDS bounce.
// h exchange: per-step fresh buffers pre-memset to 0x7f7f (impossible for
// |h|<1). Producers: per-lane 2B sc0sc1 stores, fire-and-forget (no vmcnt, no
// flags). Consumers: poll data until no short == sentinel (tear-proof since
// each short is checked). 1 L3 write + 1 poll RT per step.
// dyn LDS: W 64KB + h 16KB = 81920 B.
__global__ __launch_bounds__(256) void lstm_kernel(
    const __hip_bfloat16* __restrict__ xp16,   // [3][2048][2048]
    const __hip_bfloat16* __restrict__ whh16,  // [3][2048][512]
    __hip_bfloat16* __restrict__ ehsb, __hip_bfloat16* __restrict__ ehsT,
    __hip_bfloat16* __restrict__ catb,
    __hip_bfloat16* __restrict__ hbuf) {      // [3][128][32][16][16] bf16
  const int l = blockIdx.x >> 5, g = blockIdx.x & 31;
  const int tid = threadIdx.x, lane = tid & 63, wid = tid >> 6;
  extern __shared__ char sm[];
  char* smW = sm;          // 65536
  char* smH = sm + 65536;  // 16384

  // load weights, reordered: LDS row lr = d_local*4 + gate
  const __hip_bfloat16* wsrc = whh16 + (size_t)l * 2048 * 512;
  for (int p = tid; p < 4096; p += 256) {
    const int r = p >> 6, cb = (p & 63) << 4;
    const int grow = (r & 3) * 512 + (g << 4) + (r >> 2);
    float4 v = *(const float4*)((const char*)(wsrc + (size_t)grow * 512) + cb);
    *(float4*)(smW + r * 1024 + (cb ^ ((r & 7) << 4))) = v;
  }

  const int lrow = lane & 15, kq = lane >> 4;
  const int swz = (lrow & 7) << 4;
  const char* aB = smW + (wid * 16 + lrow) * 1024;
  const char* bB = smH + lrow * 1024;
  const int dl16 = wid * 4 + kq;   // this lane's dim within block
  const int dg = (g << 4) + dl16;  // global dim
  const int bb = lrow;             // this lane's batch
  const bool rev = (l == 1);
  const __hip_bfloat16* xl = xp16 + (size_t)l * 2048 * 2048;
  __hip_bfloat16* hb_l = hbuf + (size_t)l * 128 * 8192;
  float c = 0.f;

  for (int s = 0; s < 128; ++s) {
    const int t = rev ? 127 - s : s;
    const size_t xro = (size_t)(bb * 128 + t) * 2048 + dg;
    const float xgi = __bfloat162float(xl[xro]);
    const float xgf = __bfloat162float(xl[xro + 512]);
    const float xgg = __bfloat162float(xl[xro + 1024]);
    const float xgo = __bfloat162float(xl[xro + 1536]);

    if (s > 0) {
      const char* hsrc = (const char*)(hb_l + (size_t)(s - 1) * 8192);
      float4 d0, d1, d2, d3;
      const unsigned o0 = (unsigned)(tid * 16);
      while (true) {
        asm volatile(
            "global_load_dwordx4 %0, %4, %8 sc0 sc1\n\t"
            "global_load_dwordx4 %1, %5, %8 sc0 sc1\n\t"
            "global_load_dwordx4 %2, %6, %8 sc0 sc1\n\t"
            "global_load_dwordx4 %3, %7, %8 sc0 sc1\n\t"
            "s_waitcnt vmcnt(0)"
            : "=&v"(d0), "=&v"(d1), "=&v"(d2), "=&v"(d3)
            : "v"(o0), "v"(o0 + 4096u), "v"(o0 + 8192u), "v"(o0 + 12288u),
              "s"(hsrc)
            : "memory");
        if (ok16(d0) & ok16(d1) & ok16(d2) & ok16(d3)) break;
        __builtin_amdgcn_s_sleep(1);
      }
      const float4 dd4[4] = {d0, d1, d2, d3};
#pragma unroll
      for (int cc = 0; cc < 4; ++cc) {
        const int e = cc * 2048 + tid * 8;  // elem idx: [g'][b][dl]
        const int gp = e >> 8, bq = (e >> 4) & 15, de = e & 15;
        *(float4*)(smH + bq * 1024 + (((gp * 16 + de) * 2) ^ ((bq & 7) << 4))) = dd4[cc];
      }
    } else {
      for (int e = tid * 8; e < 8192; e += 2048) {
        const int gp = e >> 8, bq = (e >> 4) & 15, de = e & 15;
        *(float4*)(smH + bq * 1024 + (((gp * 16 + de) * 2) ^ ((bq & 7) << 4))) =
            make_float4(0.f, 0.f, 0.f, 0.f);
      }
    }
    __syncthreads();

    f32x4 acc0 = {0.f, 0.f, 0.f, 0.f}, acc1 = {0.f, 0.f, 0.f, 0.f};
#pragma unroll
    for (int kt = 0; kt < 16; kt += 2) {
      const int off0 = ((kt * 64 + (kq << 4)) ^ swz);
      const int off1 = (((kt + 1) * 64 + (kq << 4)) ^ swz);
      short8v a0 = *(const short8v*)(aB + off0);
      short8v b0 = *(const short8v*)(bB + off0);
      short8v a1 = *(const short8v*)(aB + off1);
      short8v b1 = *(const short8v*)(bB + off1);
      acc0 = __builtin_amdgcn_mfma_f32_16x16x32_bf16(a0, b0, acc0, 0, 0, 0);
      acc1 = __builtin_amdgcn_mfma_f32_16x16x32_bf16(a1, b1, acc1, 0, 0, 0);
    }
    const f32x4 acc = acc0 + acc1;  // acc[r] = gate r for (dg, bb)

    const float gi = acc[0] + xgi;
    const float gf = acc[1] + xgf;
    const float gg = acc[2] + xgg;
    const float go = acc[3] + xgo;
    c = fmaf(fast_sig(gf), c, fast_sig(gi) * fast_tanh(gg));
    const float h = fast_sig(go) * fast_tanh(c);
    __hip_bfloat16 hb16 = __float2bfloat16(h);
    {
      // publish h: per-lane 2B store straight to coherence point
      char* hdst = (char*)(hb_l + (size_t)s * 8192 + ((size_t)g << 8));
      const unsigned off = (unsigned)((bb * 16 + dl16) * 2);
      const unsigned hv = (unsigned)*(unsigned short*)&hb16;
      asm volatile("global_store_short %0, %1, %2 sc0 sc1"
                   :: "v"(off), "v"(hv), "s"(hdst) : "memory");
    }
    const size_t orow = (size_t)(bb * 128 + t);
    if (l == 0) {
      ehsb[orow * 1024 + dg] = hb16;
      ehsT[((size_t)bb * 1024 + dg) * 128 + t] = hb16;
    } else if (l == 1) {
      ehsb[orow * 1024 + 512 + dg] = hb16;
      ehsT[((size_t)bb * 1024 + 512 + dg) * 128 + t] = hb16;
    } else {
      catb[orow * 1536 + dg] = hb16;
    }
    __syncthreads();  // smH stable until all waves' MFMA done
  }
}

// ---------------- score + softmax -> alpha (bf16), one block per (b,t) ----------------
__global__ __launch_bounds__(256) void score_kernel(
    const float* __restrict__ dterm, const __hip_bfloat16* __restrict__ etT,
    const float* __restrict__ v_att, const int* __restrict__ src_mask,
    __hip_bfloat16* __restrict__ alphab) {
  const int bt = blockIdx.x, b = bt >> 7;
  const int tid = threadIdx.x;
  __shared__ float dt[512], vs[512], red[4][128], al[128], rtmp[2];
  dt[tid] = dterm[(size_t)bt * 512 + tid];
  dt[tid + 256] = dterm[(size_t)bt * 512 + 256 + tid];
  vs[tid] = v_att[tid];
  vs[tid + 256] = v_att[256 + tid];
  __syncthreads();
  const int n0 = (tid & 63) << 1, ah = tid >> 6;
  {
    const __hip_bfloat16* ep = etT + (((size_t)b * 512 + ah * 128) << 7) + n0;
    const float* dp = dt + ah * 128;
    const float* vp = vs + ah * 128;
    float p0 = 0.f, p1 = 0.f;
    for (int a = 0; a < 128; ++a) {
      const unsigned u = *(const unsigned*)(ep + ((size_t)a << 7));
      unsigned u0 = u << 16, u1 = u & 0xffff0000u;
      const float e0 = *(float*)&u0, e1 = *(float*)&u1;
      const float da = dp[a], va = vp[a];
      p0 = fmaf(va, fast_tanh(da + e0), p0);
      p1 = fmaf(va, fast_tanh(da + e1), p1);
    }
    red[ah][n0] = p0;
    red[ah][n0 + 1] = p1;
  }
  __syncthreads();
  if (tid < 128) {
    float s = red[0][tid] + red[1][tid] + red[2][tid] + red[3][tid];
    if (src_mask[b * 128 + tid] == 0) s = NEGV;
    al[tid] = s;
  }
  __syncthreads();
  if (tid < 64) {
    float m = fmaxf(al[tid], al[tid + 64]);
    m = wave_max(m);
    if (tid == 0) rtmp[0] = m;
  }
  __syncthreads();
  if (tid < 128) al[tid] = __expf(al[tid] - rtmp[0]);
  __syncthreads();
  if (tid < 64) {
    float s2 = al[tid] + al[tid + 64];
    s2 = wave_sum(s2);
    if (tid == 0) rtmp[1] = 1.f / s2;
  }
  __syncthreads();
  if (tid < 128)
    alphab[(size_t)bt * 128 + tid] = __float2bfloat16(al[tid] * rtmp[1]);
}

// ---------------- pointer head assembly ----------------
__global__ __launch_bounds__(256) void pointer_kernel(
    const float* __restrict__ base, const float* __restrict__ wgout,
    const float* __restrict__ ptr_W, const float* __restrict__ ps_W,
    const float* __restrict__ ps_b, const int* __restrict__ src_mask,
    float* __restrict__ out0) {
  const int bt = blockIdx.x;
  const int b = bt >> 7, t = bt & 127;
  const int tid = threadIdx.x;
  __shared__ float r0[4], r1[4], r2[4], fin[3];
  float off_p = 0.f, diag_p = 0.f, sent_p;
  if (tid < 128) {
    const float ba = base[(size_t)bt * 128 + tid];
    const float pw = ps_W[tid];
    off_p = tanhf(ba) * pw;
    diag_p = tanhf(ba + ptr_W[tid * 513 + 512]) * pw;
  }
  sent_p = wgout[(size_t)bt * 512 + tid] + wgout[(size_t)bt * 512 + 256 + tid];
  off_p = wave_sum(off_p);
  diag_p = wave_sum(diag_p);
  sent_p = wave_sum(sent_p);
  const int wid = tid >> 6, lane = tid & 63;
  if (lane == 0) { r0[wid] = off_p; r1[wid] = diag_p; r2[wid] = sent_p; }
  __syncthreads();
  if (tid == 0) {
    const float psb = ps_b[0];
    fin[0] = r0[0] + r0[1] + r0[2] + r0[3] + psb;
    fin[1] = r1[0] + r1[1] + r1[2] + r1[3] + psb;
    fin[2] = r2[0] + r2[1] + r2[2] + r2[3];
  }
  __syncthreads();
  const float s_off = fin[0], s_diag = fin[1], sent = fin[2];
  if (tid < 129) {
    float v;
    if (tid == 128) v = sent;
    else {
      v = (tid == t) ? s_diag : s_off;
      if (src_mask[b * 128 + tid] == 0) v = NEGV;
    }
    out0[(size_t)bt * 129 + tid] = v;
  }
}

// ---------------- launch ----------------
extern "C" void kernel_launch(void* const* d_in, const int* in_sizes, int n_in,
                              void* d_out, int out_size, void* d_ws, size_t ws_size,
                              hipStream_t stream) {
  const int* src_ids   = (const int*)d_in[0];
  const int* src_mask  = (const int*)d_in[1];
  const int* cmask     = (const int*)d_in[2];
  const float* emb     = (const float*)d_in[3];
  const float* Wih_f   = (const float*)d_in[4];
  const float* Whh_f   = (const float*)d_in[5];
  const float* b_f     = (const float*)d_in[6];
  const float* Wih_b   = (const float*)d_in[7];
  const float* Whh_b   = (const float*)d_in[8];
  const float* b_b     = (const float*)d_in[9];
  const float* Wih_d   = (const float*)d_in[10];
  const float* Whh_d   = (const float*)d_in[11];
  const float* b_d     = (const float*)d_in[12];
  const float* W1      = (const float*)d_in[13];
  const float* W2      = (const float*)d_in[14];
  const float* v_att   = (const float*)d_in[15];
  const float* comb_W  = (const float*)d_in[16];
  const float* comb_b  = (const float*)d_in[17];
  const float* vocab_W = (const float*)d_in[18];
  const float* vocab_b = (const float*)d_in[19];
  const float* Wg_W    = (const float*)d_in[20];
  const float* Wg_b    = (const float*)d_in[21];
  const float* ptr_W   = (const float*)d_in[22];
  const float* ptr_b   = (const float*)d_in[23];
  const float* ps_W    = (const float*)d_in[24];
  const float* ps_b    = (const float*)d_in[25];
  (void)in_sizes; (void)n_in; (void)out_size; (void)ws_size;

  char* wsb = (char*)d_ws;
  size_t o = 0;
  auto alloc = [&](size_t bytes) { char* p = wsb + o; o = (o + bytes + 255) & ~(size_t)255; return p; };
  __hip_bfloat16* xb      = (__hip_bfloat16*)alloc((size_t)BN_ * E_ * 2);
  __hip_bfloat16* xproj16 = (__hip_bfloat16*)alloc((size_t)3 * BN_ * 2048 * 2);
  __hip_bfloat16* ehsb    = (__hip_bfloat16*)alloc((size_t)BN_ * 1024 * 2);
  __hip_bfloat16* ehsT    = (__hip_bfloat16*)alloc((size_t)16 * 1024 * 128 * 2);
  __hip_bfloat16* catb    = (__hip_bfloat16*)alloc((size_t)BN_ * 1536 * 2);
  float* dterm            = (float*)alloc((size_t)BN_ * 512 * 4);
  __hip_bfloat16* etT     = (__hip_bfloat16*)alloc((size_t)16 * 512 * 128 * 2);
  __hip_bfloat16* alphab  = (__hip_bfloat16*)alloc((size_t)BN_ * 128 * 2);
  __hip_bfloat16* combb   = (__hip_bfloat16*)alloc((size_t)BN_ * 512 * 2);
  float* wgout            = (float*)alloc((size_t)BN_ * 512 * 4);
  float* baseb            = (float*)alloc((size_t)BN_ * 128 * 4);
  __hip_bfloat16* hbuf    = (__hip_bfloat16*)alloc((size_t)3 * 128 * 8192 * 2);
  __hip_bfloat16* wihf16  = (__hip_bfloat16*)alloc((size_t)2048 * 384 * 2);
  __hip_bfloat16* wihb16  = (__hip_bfloat16*)alloc((size_t)2048 * 384 * 2);
  __hip_bfloat16* wihd16  = (__hip_bfloat16*)alloc((size_t)2048 * 384 * 2);
  __hip_bfloat16* whh16   = (__hip_bfloat16*)alloc((size_t)3 * 2048 * 512 * 2);
  __hip_bfloat16* w1_16   = (__hip_bfloat16*)alloc((size_t)512 * 512 * 2);
  __hip_bfloat16* w2_16   = (__hip_bfloat16*)alloc((size_t)512 * 1024 * 2);
  __hip_bfloat16* combw16 = (__hip_bfloat16*)alloc((size_t)512 * 1536 * 2);
  __hip_bfloat16* vocw16  = (__hip_bfloat16*)alloc((size_t)8000 * 512 * 2);
  __hip_bfloat16* wgw16   = (__hip_bfloat16*)alloc((size_t)512 * 512 * 2);
  __hip_bfloat16* ptrw16  = (__hip_bfloat16*)alloc((size_t)128 * 512 * 2);

  float* out0 = (float*)d_out;
  float* out1 = out0 + (size_t)BN_ * 129;

  // sentinel-init the per-step h buffers (0x7f7f bf16 ~ 6.7e38, |h|<1 never hits it)
  hipMemsetAsync(hbuf, 0x7f, (size_t)3 * 128 * 8192 * 2, stream);
  embed_kernel<<<BN_, 256, 0, stream>>>(src_ids, emb, xb);

  CastArgs ca;
  const float* srcs[12] = {Wih_f, Wih_b, Wih_d, Whh_f, Whh_b, Whh_d,
                           W1, W2, comb_W, vocab_W, Wg_W, ptr_W};
  __hip_bfloat16* dsts[12] = {wihf16, wihb16, wihd16, whh16, whh16 + 2048 * 512,
                              whh16 + 2 * 2048 * 512, w1_16, w2_16, combw16,
                              vocw16, wgw16, ptrw16};
  int ns[12] = {2048 * 384, 2048 * 384, 2048 * 384, 2048 * 512, 2048 * 512,
                2048 * 512, 512 * 512, 512 * 1024, 512 * 1536, 8000 * 512,
                512 * 512, 128 * 512};
  int acc = 0;
  for (int k = 0; k < 12; ++k) {
    ca.s[k] = srcs[k];
    ca.d[k] = (unsigned long long)dsts[k];
    ca.base[k] = acc;
    acc += ns[k];
  }
  ca.total = acc;
  cast_kernel<<<2048, 256, 0, stream>>>(ca);

  // input projections (bias folded), bf16 out
  bgemm_kernel<0, false, 0><<<dim3(16, 16), 256, 0, stream>>>(
      xb, E_, wihf16, E_, b_f, nullptr, 0, xproj16, 2048, BN_, 2048, E_, nullptr, 0, 0, 0, 0);
  bgemm_kernel<0, false, 0><<<dim3(16, 16), 256, 0, stream>>>(
      xb, E_, wihb16, E_, b_b, nullptr, 0, xproj16 + (size_t)BN_ * 2048, 2048, BN_, 2048, E_, nullptr, 0, 0, 0, 0);
  bgemm_kernel<0, false, 0><<<dim3(16, 16), 256, 0, stream>>>(
      xb, E_, wihd16, E_, b_d, nullptr, 0, xproj16 + (size_t)2 * BN_ * 2048, 2048, BN_, 2048, E_, nullptr, 0, 0, 0, 0);

  hipFuncSetAttribute((const void*)lstm_kernel,
                      hipFuncAttributeMaxDynamicSharedMemorySize, 81920);
  lstm_kernel<<<96, 256, 81920, stream>>>(xproj16, whh16, ehsb, ehsT, catb, hbuf);

  // dterm = dec_h @ W1^T (f32) ; etT = transposed bf16 eterm
  bgemm_kernel<0, false, 0><<<dim3(4, 16), 256, 0, stream>>>(
      catb, 1536, w1_16, 512, nullptr, dterm, 512, nullptr, 0, BN_, 512, 512, nullptr, 0, 0, 0, 0);
  bgemm_kernel<0, false, 1><<<dim3(4, 16), 256, 0, stream>>>(
      ehsb, 1024, w2_16, 1024, nullptr, nullptr, 0, etT, 0, BN_, 512, 1024, nullptr, 0, 0, 0, 0);

  score_kernel<<<BN_, 256, 0, stream>>>(dterm, etT, v_att, src_mask, alphab);

  // context = alpha[b] @ ehsT[b]^T -> catb[:,512:1536] (batched over b)
  bgemm_kernel<0, false, 0><<<dim3(8, 1, 16), 256, 0, stream>>>(
      alphab, 128, ehsT, 128, nullptr, nullptr, 0, catb + 512, 1536,
      128, 1024, 128, nullptr, 0, 128 * 128, 1024 * 128, 128 * 1536);

  // combined = tanh(cat @ comb_W^T + comb_b) -> bf16
  bgemm_kernel<1, false, 0><<<dim3(4, 16), 256, 0, stream>>>(
      catb, 1536, combw16, 1536, comb_b, nullptr, 0, combb, 512, BN_, 512, 1536, nullptr, 0, 0, 0, 0);

  // vocab logits + confusionset mask
  bgemm_kernel<0, true, 0><<<dim3(63, 16), 256, 0, stream>>>(
      combb, 512, vocw16, 512, vocab_b, out1, V_, nullptr, 0, BN_, V_, 512, cmask, V_, 0, 0, 0);

  // wgout = tanh(comb @ Wg^T + b)
  bgemm_kernel<1, false, 0><<<dim3(4, 16), 256, 0, stream>>>(
      combb, 512, wgw16, 512, Wg_b, wgout, 512, nullptr, 0, BN_, 512, 512, nullptr, 0, 0, 0, 0);

  // base = comb @ ptr_W[:,:512]^T + ptr_b
  bgemm_kernel<0, false, 0><<<dim3(1, 16), 256, 0, stream>>>(
      combb, 512, ptrw16, 512, ptr_b, baseb, 128, nullptr, 0, BN_, 128, 512, nullptr, 0, 0, 0, 0);

  pointer_kernel<<<BN_, 256, 0, stream>>>(baseb, wgout, ptr_W, ps_W, ps_b, src_mask, out0);
}

// Round 7
// 695.632 us; speedup vs baseline: 3.3620x; 1.0804x over previous
//
#include <hip/hip_runtime.h>
#include <hip/hip_bf16.h>
#include <math.h>

#define NEGV -1000000000.0f

static constexpr int B_ = 16, N_ = 128, BN_ = 2048;
static constexpr int E_ = 384, V_ = 8000;

typedef __attribute__((ext_vector_type(8))) short short8v;
typedef __attribute__((ext_vector_type(4))) float f32x4;

// ---------------- helpers ----------------
__device__ inline float wave_sum(float v) {
#pragma unroll
  for (int o = 32; o; o >>= 1) v += __shfl_xor(v, o);
  return v;
}
__device__ inline float wave_max(float v) {
#pragma unroll
  for (int o = 32; o; o >>= 1) v = fmaxf(v, __shfl_xor(v, o));
  return v;
}
__device__ inline float fast_tanh(float x) {
  return 1.f - 2.f / (1.f + __expf(2.f * x));
}
__device__ inline float fast_sig(float x) {
  return 1.f / (1.f + __expf(-x));
}
__device__ __forceinline__ void gl16(const void* g, void* l) {
  __builtin_amdgcn_global_load_lds((const __attribute__((address_space(1))) void*)g,
                                   (__attribute__((address_space(3))) void*)l, 16, 0, 0);
}

// ---------------- embedding gather -> bf16 ----------------
__global__ __launch_bounds__(256) void embed_kernel(
    const int* __restrict__ ids, const float* __restrict__ emb,
    __hip_bfloat16* __restrict__ xb) {
  const int row = blockIdx.x;
  const int id = ids[row];
  for (int e = threadIdx.x; e < E_; e += 256)
    xb[(size_t)row * E_ + e] = __float2bfloat16(emb[(size_t)id * E_ + e]);
}

// ---------------- multi-segment fp32 -> bf16 cast ----------------
struct CastArgs {
  const float* s[12];
  unsigned long long d[12];
  int base[12];
  int total;
};
__global__ __launch_bounds__(256) void cast_kernel(CastArgs a) {
  const int nq = a.total >> 2;
  for (int q = blockIdx.x * 256 + threadIdx.x; q < nq; q += gridDim.x * 256) {
    const int e = q << 2;
    int k = 11;
    while (e < a.base[k]) --k;
    const int i = e - a.base[k];
    __hip_bfloat16* dst = (__hip_bfloat16*)a.d[k] + i;
    if (k == 11) {  // ptr_W: pack [128][513] cols 0..511 -> [128][512]
      const int row = i >> 9, col = i & 511;
      const float* sp = a.s[k] + (size_t)row * 513 + col;
#pragma unroll
      for (int u = 0; u < 4; ++u) dst[u] = __float2bfloat16(sp[u]);
    } else {
      float4 v = *(const float4*)(a.s[k] + i);
      __hip_bfloat16 h0 = __float2bfloat16(v.x), h1 = __float2bfloat16(v.y);
      __hip_bfloat16 h2 = __float2bfloat16(v.z), h3 = __float2bfloat16(v.w);
      ushort4 u4 = {*(unsigned short*)&h0, *(unsigned short*)&h1,
                    *(unsigned short*)&h2, *(unsigned short*)&h3};
      *(ushort4*)dst = u4;
    }
  }
}

// ---------------- bf16 MFMA GEMM: out = act(A @ W^T + bias) [+mask] ----------------
template <int ACT, bool MASK, int TROUT>
__global__ __launch_bounds__(256) void bgemm_kernel(
    const __hip_bfloat16* __restrict__ A, int lda,
    const __hip_bfloat16* __restrict__ W, int ldw,
    const float* __restrict__ bias,
    float* __restrict__ C, int ldc,
    __hip_bfloat16* __restrict__ Cb, int ldcb,
    int M, int N, int K,
    const int* __restrict__ mask, int ldm,
    long aBs, long wBs, long cBs) {
  __shared__ __hip_bfloat16 Al[2][4096];
  __shared__ __hip_bfloat16 Bl[2][4096];
  A += (size_t)blockIdx.z * aBs;
  W += (size_t)blockIdx.z * wBs;
  const int tid = threadIdx.x;
  const int wid = tid >> 6, lane = tid & 63;
  const int m0 = blockIdx.y * 128, n0 = blockIdx.x * 128;
  const int nkt = K >> 5;
  const int rm = (wid >> 1) << 6, rn = (wid & 1) << 6;
  const int lrow = lane & 15, kq = lane >> 4;
  const int fs = ((lrow >> 1) & 3) << 4;

  f32x4 acc[4][4];
#pragma unroll
  for (int i = 0; i < 4; ++i)
#pragma unroll
    for (int j = 0; j < 4; ++j) acc[i][j] = {0.f, 0.f, 0.f, 0.f};

  auto stage = [&](int bi, int kt) {
#pragma unroll
    for (int c = 0; c < 2; ++c) {
      const int p = ((c * 4 + wid) << 6) + lane;
      const int row = p >> 2, cb = (p & 3) << 4;
      const int sw = ((row >> 1) & 3) << 4;
      const unsigned loff = (unsigned)__builtin_amdgcn_readfirstlane((c * 4 + wid) << 10);
      {
        const char* src = (const char*)A + ((size_t)(m0 + row) * lda + (size_t)kt * 32) * 2 + (cb ^ sw);
        gl16(src, (char*)&Al[bi][0] + loff);
      }
      {
        int gr = n0 + row;
        if (gr >= N) gr = N - 1;
        const char* src = (const char*)W + ((size_t)gr * ldw + (size_t)kt * 32) * 2 + (cb ^ sw);
        gl16(src, (char*)&Bl[bi][0] + loff);
      }
    }
  };
  auto compute = [&](int bi) {
    const char* Ab = (const char*)&Al[bi][0];
    const char* Bb = (const char*)&Bl[bi][0];
    const int roff = (kq << 4) ^ fs;
    short8v a[4], b[4];
#pragma unroll
    for (int i = 0; i < 4; ++i)
      a[i] = *(const short8v*)(Ab + (rm + i * 16 + lrow) * 64 + roff);
#pragma unroll
    for (int j = 0; j < 4; ++j)
      b[j] = *(const short8v*)(Bb + (rn + j * 16 + lrow) * 64 + roff);
#pragma unroll
    for (int i = 0; i < 4; ++i)
#pragma unroll
      for (int j = 0; j < 4; ++j)
        acc[i][j] = __builtin_amdgcn_mfma_f32_16x16x32_bf16(a[i], b[j], acc[i][j], 0, 0, 0);
  };

  stage(0, 0);
  for (int kt = 0; kt < nkt; ++kt) {
    __syncthreads();
    if (kt + 1 < nkt) stage((kt + 1) & 1, kt + 1);
    compute(kt & 1);
  }

#pragma unroll
  for (int i = 0; i < 4; ++i) {
#pragma unroll
    for (int r = 0; r < 4; ++r) {
      const int m = m0 + rm + i * 16 + kq * 4 + r;
#pragma unroll
      for (int j = 0; j < 4; ++j) {
        const int n = n0 + rn + j * 16 + lrow;
        if (n < N) {
          float v = acc[i][j][r] + (bias ? bias[n] : 0.f);
          if (ACT == 1) v = tanhf(v);
          if (MASK) {
            if (mask[(size_t)m * ldm + n] == 0) v = NEGV;
          }
          if (TROUT == 1) {
            Cb[(((size_t)(m >> 7) * 512 + n) << 7) + (m & 127)] = __float2bfloat16(v);
          } else {
            if (C) C[(size_t)m * ldc + n] = v;
            if (Cb) Cb[(size_t)m * ldcb + n + (size_t)blockIdx.z * cBs] = __float2bfloat16(v);
          }
        }
      }
    }
  }
}

// ---------------- fused 3-LSTM recurrence ----------------
// grid 96 = 3 lstm x 32 slices; block owns 16 dims x 4 gates, 16 batches.
// Publish: h chunk (512B) packed in LDS, ONE wave0 dwordx4 sc0sc1 burst ->
// each 64B sector lands atomically. Consumers: per-thread spin on 1 short per
// 64B line (sentinel 0x7f7f impossible for |h|<1), then read own 64B line.
// Own-block region bypasses global entirely (direct LDS inject).
// No output scatters in the loop (see scatter_kernel).
// dyn LDS: W 64KB + h 16KB + hout 512B = 82432 B.
__global__ __launch_bounds__(256) void lstm_kernel(
    const __hip_bfloat16* __restrict__ xp16,   // [3][2048][2048]
    const __hip_bfloat16* __restrict__ whh16,  // [3][2048][512]
    __hip_bfloat16* __restrict__ hbuf) {       // [3][128][32][16b][16d]
  const int l = blockIdx.x >> 5, g = blockIdx.x & 31;
  const int tid = threadIdx.x, lane = tid & 63, wid = tid >> 6;
  extern __shared__ char sm[];
  char* smW = sm;                                   // 65536
  char* smH = sm + 65536;                           // 16384
  __hip_bfloat16* hout = (__hip_bfloat16*)(sm + 65536 + 16384);  // 512

  // load weights, reordered dim-major: LDS row lr = d_local*4 + gate
  const __hip_bfloat16* wsrc = whh16 + (size_t)l * 2048 * 512;
  for (int p = tid; p < 4096; p += 256) {
    const int r = p >> 6, cb = (p & 63) << 4;
    const int grow = (r & 3) * 512 + (g << 4) + (r >> 2);
    float4 v = *(const float4*)((const char*)(wsrc + (size_t)grow * 512) + cb);
    *(float4*)(smW + r * 1024 + (cb ^ ((r & 7) << 4))) = v;
  }

  const int lrow = lane & 15, kq = lane >> 4;
  const int swz = (lrow & 7) << 4;
  const char* aB = smW + (wid * 16 + lrow) * 1024;
  const char* bB = smH + lrow * 1024;
  const int dl16 = wid * 4 + kq;   // this lane's dim within block
  const int dg = (g << 4) + dl16;  // global dim
  const int bb = lrow;             // this lane's batch
  const bool rev = (l == 1);
  const __hip_bfloat16* xl = xp16 + (size_t)l * 2048 * 2048;
  __hip_bfloat16* hb_l = hbuf + (size_t)l * 128 * 8192;
  // staging geometry: this thread owns one 64B line of the 16KB h image
  const int gq = tid >> 3;            // source block g' of my line
  const int b0 = (tid & 7) * 2;       // first of 2 batches in my line
  const int gb = gq * 32;             // byte offset of d0 within batch row
  const int sw0 = (b0 & 7) << 4, sw1 = ((b0 + 1) & 7) << 4;
  float c = 0.f;

  for (int s = 0; s < 128; ++s) {
    const int t = rev ? 127 - s : s;
    const size_t xro = (size_t)(bb * 128 + t) * 2048 + dg;
    const float xgi = __bfloat162float(xl[xro]);
    const float xgf = __bfloat162float(xl[xro + 512]);
    const float xgg = __bfloat162float(xl[xro + 1024]);
    const float xgo = __bfloat162float(xl[xro + 1536]);

    if (s > 0) {
      if (gq != g) {  // own region injected directly last step
        const char* hsrc = (const char*)(hb_l + (size_t)(s - 1) * 8192);
        const unsigned loff = (unsigned)(tid * 64);
        unsigned hv;
        while (true) {
          asm volatile(
              "global_load_ushort %0, %1, %2 sc0 sc1\n\t"
              "s_waitcnt vmcnt(0)"
              : "=&v"(hv) : "v"(loff), "s"(hsrc) : "memory");
          if ((hv & 0xffffu) != 0x7f7fu) break;
          __builtin_amdgcn_s_sleep(1);
        }
        f32x4 q0, q1, q2, q3;
        asm volatile(
            "global_load_dwordx4 %0, %4, %5 sc0 sc1\n\t"
            "global_load_dwordx4 %1, %4, %5 offset:16 sc0 sc1\n\t"
            "global_load_dwordx4 %2, %4, %5 offset:32 sc0 sc1\n\t"
            "global_load_dwordx4 %3, %4, %5 offset:48 sc0 sc1\n\t"
            "s_waitcnt vmcnt(0)"
            : "=&v"(q0), "=&v"(q1), "=&v"(q2), "=&v"(q3)
            : "v"(loff), "s"(hsrc) : "memory");
        *(f32x4*)(smH + b0 * 1024 + (gb ^ sw0)) = q0;
        *(f32x4*)(smH + b0 * 1024 + ((gb + 16) ^ sw0)) = q1;
        *(f32x4*)(smH + (b0 + 1) * 1024 + (gb ^ sw1)) = q2;
        *(f32x4*)(smH + (b0 + 1) * 1024 + ((gb + 16) ^ sw1)) = q3;
      }
    } else {
      const f32x4 z = {0.f, 0.f, 0.f, 0.f};
      *(f32x4*)(smH + b0 * 1024 + (gb ^ sw0)) = z;
      *(f32x4*)(smH + b0 * 1024 + ((gb + 16) ^ sw0)) = z;
      *(f32x4*)(smH + (b0 + 1) * 1024 + (gb ^ sw1)) = z;
      *(f32x4*)(smH + (b0 + 1) * 1024 + ((gb + 16) ^ sw1)) = z;
    }
    __syncthreads();  // A: smH staged

    f32x4 acc0 = {0.f, 0.f, 0.f, 0.f}, acc1 = {0.f, 0.f, 0.f, 0.f};
#pragma unroll
    for (int kt = 0; kt < 16; kt += 2) {
      const int off0 = ((kt * 64 + (kq << 4)) ^ swz);
      const int off1 = (((kt + 1) * 64 + (kq << 4)) ^ swz);
      short8v a0 = *(const short8v*)(aB + off0);
      short8v b0v = *(const short8v*)(bB + off0);
      short8v a1 = *(const short8v*)(aB + off1);
      short8v b1v = *(const short8v*)(bB + off1);
      acc0 = __builtin_amdgcn_mfma_f32_16x16x32_bf16(a0, b0v, acc0, 0, 0, 0);
      acc1 = __builtin_amdgcn_mfma_f32_16x16x32_bf16(a1, b1v, acc1, 0, 0, 0);
    }
    const f32x4 acc = acc0 + acc1;  // acc[r] = gate r for (dg, bb)
    __syncthreads();  // B: all MFMA reads of smH done

    const float gi = acc[0] + xgi;
    const float gf = acc[1] + xgf;
    const float gg = acc[2] + xgg;
    const float go = acc[3] + xgo;
    c = fmaf(fast_sig(gf), c, fast_sig(gi) * fast_tanh(gg));
    const float h = fast_sig(go) * fast_tanh(c);
    __hip_bfloat16 hb16 = __float2bfloat16(h);
    const unsigned short hraw = *(unsigned short*)&hb16;
    hout[bb * 16 + dl16] = hb16;  // pack for wave0 burst
    // direct LDS inject of own region for next step
    *(unsigned short*)(smH + bb * 1024 +
                       ((((g << 4) + dl16) * 2) ^ ((bb & 7) << 4))) = hraw;
    __syncthreads();  // C: hout complete
    if (tid < 32) {
      f32x4 hv4 = *(const f32x4*)((const char*)hout + tid * 16);
      char* hdst = (char*)(hb_l + (size_t)s * 8192);
      asm volatile("global_store_dwordx4 %0, %1, %2 sc0 sc1"
                   :: "v"((unsigned)((g << 9) + tid * 16)), "v"(hv4), "s"(hdst)
                   : "memory");
    }
    // no drain: store ack folds into next step's spin vmcnt
  }
}

// ---------------- scatter: hbuf -> ehsb / ehsT / catb ----------------
// block = (l, b, dgrp of 64 dims); reads hbuf via sc0 sc1 (hbuf was written
// coherence-point-direct; L2 may hold stale sentinel lines from the memset).
__global__ __launch_bounds__(256) void scatter_kernel(
    const __hip_bfloat16* __restrict__ hbuf,
    __hip_bfloat16* __restrict__ ehsb, __hip_bfloat16* __restrict__ ehsT,
    __hip_bfloat16* __restrict__ catb) {
  const int bid = blockIdx.x;
  const int l = bid >> 7, b = (bid >> 3) & 15, dgrp = bid & 7;
  const int tid = threadIdx.x;
  __shared__ unsigned short tile[64][130];
  const int t4 = tid >> 6, dl = tid & 63;
  const bool rev = (l == 1);
  const char* hb = (const char*)(hbuf + (size_t)l * 128 * 8192);
  for (int tt = 0; tt < 128; tt += 4) {
    const int t = tt + t4;
    const int s = rev ? 127 - t : t;
    const unsigned off = (unsigned)(s * 16384 + (dgrp * 4 + (dl >> 4)) * 512 +
                                    b * 32 + (dl & 15) * 2);
    unsigned hv;
    asm volatile("global_load_ushort %0, %1, %2 sc0 sc1\n\ts_waitcnt vmcnt(0)"
                 : "=&v"(hv) : "v"(off), "s"(hb) : "memory");
    tile[dl][t] = (unsigned short)hv;
  }
  __syncthreads();
  if (l < 2) {
    const int r = tid >> 2, seg = tid & 3;
    ushort4* dstT = (ushort4*)(ehsT + ((size_t)b * 1024 + l * 512 + dgrp * 64 + r) * 128 + seg * 32);
    const unsigned short* srcT = &tile[r][seg * 32];
#pragma unroll
    for (int q = 0; q < 8; ++q) dstT[q] = *(const ushort4*)(srcT + q * 4);
    const int t2 = tid >> 1, half = tid & 1;
    unsigned short buf[32];
#pragma unroll
    for (int q = 0; q < 32; ++q) buf[q] = tile[half * 32 + q][t2];
    ushort4* dstB = (ushort4*)(ehsb + ((size_t)(b * 128 + t2)) * 1024 + l * 512 + dgrp * 64 + half * 32);
#pragma unroll
    for (int q = 0; q < 8; ++q) dstB[q] = *(const ushort4*)(buf + q * 4);
  } else {
    const int t2 = tid >> 1, half = tid & 1;
    unsigned short buf[32];
#pragma unroll
    for (int q = 0; q < 32; ++q) buf[q] = tile[half * 32 + q][t2];
    ushort4* dstB = (ushort4*)(catb + ((size_t)(b * 128 + t2)) * 1536 + dgrp * 64 + half * 32);
#pragma unroll
    for (int q = 0; q < 8; ++q) dstB[q] = *(const ushort4*)(buf + q * 4);
  }
}

// ---------------- score + softmax -> alpha (bf16), one block per (b,t) ----------------
__global__ __launch_bounds__(256) void score_kernel(
    const float* __restrict__ dterm, const __hip_bfloat16* __restrict__ etT,
    const float* __restrict__ v_att, const int* __restrict__ src_mask,
    __hip_bfloat16* __restrict__ alphab) {
  const int bt = blockIdx.x, b = bt >> 7;
  const int tid = threadIdx.x;
  __shared__ float dt[512], vs[512], red[4][128], al[128], rtmp[2];
  dt[tid] = dterm[(size_t)bt * 512 + tid];
  dt[tid + 256] = dterm[(size_t)bt * 512 + 256 + tid];
  vs[tid] = v_att[tid];
  vs[tid + 256] = v_att[256 + tid];
  __syncthreads();
  const int n0 = (tid & 63) << 1, ah = tid >> 6;
  {
    const __hip_bfloat16* ep = etT + (((size_t)b * 512 + ah * 128) << 7) + n0;
    const float* dp = dt + ah * 128;
    const float* vp = vs + ah * 128;
    float p0 = 0.f, p1 = 0.f;
    for (int a = 0; a < 128; ++a) {
      const unsigned u = *(const unsigned*)(ep + ((size_t)a << 7));
      unsigned u0 = u << 16, u1 = u & 0xffff0000u;
      const float e0 = *(float*)&u0, e1 = *(float*)&u1;
      const float da = dp[a], va = vp[a];
      p0 = fmaf(va, fast_tanh(da + e0), p0);
      p1 = fmaf(va, fast_tanh(da + e1), p1);
    }
    red[ah][n0] = p0;
    red[ah][n0 + 1] = p1;
  }
  __syncthreads();
  if (tid < 128) {
    float s = red[0][tid] + red[1][tid] + red[2][tid] + red[3][tid];
    if (src_mask[b * 128 + tid] == 0) s = NEGV;
    al[tid] = s;
  }
  __syncthreads();
  if (tid < 64) {
    float m = fmaxf(al[tid], al[tid + 64]);
    m = wave_max(m);
    if (tid == 0) rtmp[0] = m;
  }
  __syncthreads();
  if (tid < 128) al[tid] = __expf(al[tid] - rtmp[0]);
  __syncthreads();
  if (tid < 64) {
    float s2 = al[tid] + al[tid + 64];
    s2 = wave_sum(s2);
    if (tid == 0) rtmp[1] = 1.f / s2;
  }
  __syncthreads();
  if (tid < 128)
    alphab[(size_t)bt * 128 + tid] = __float2bfloat16(al[tid] * rtmp[1]);
}

// ---------------- pointer head assembly ----------------
__global__ __launch_bounds__(256) void pointer_kernel(
    const float* __restrict__ base, const float* __restrict__ wgout,
    const float* __restrict__ ptr_W, const float* __restrict__ ps_W,
    const float* __restrict__ ps_b, const int* __restrict__ src_mask,
    float* __restrict__ out0) {
  const int bt = blockIdx.x;
  const int b = bt >> 7, t = bt & 127;
  const int tid = threadIdx.x;
  __shared__ float r0[4], r1[4], r2[4], fin[3];
  float off_p = 0.f, diag_p = 0.f, sent_p;
  if (tid < 128) {
    const float ba = base[(size_t)bt * 128 + tid];
    const float pw = ps_W[tid];
    off_p = tanhf(ba) * pw;
    diag_p = tanhf(ba + ptr_W[tid * 513 + 512]) * pw;
  }
  sent_p = wgout[(size_t)bt * 512 + tid] + wgout[(size_t)bt * 512 + 256 + tid];
  off_p = wave_sum(off_p);
  diag_p = wave_sum(diag_p);
  sent_p = wave_sum(sent_p);
  const int wid = tid >> 6, lane = tid & 63;
  if (lane == 0) { r0[wid] = off_p; r1[wid] = diag_p; r2[wid] = sent_p; }
  __syncthreads();
  if (tid == 0) {
    const float psb = ps_b[0];
    fin[0] = r0[0] + r0[1] + r0[2] + r0[3] + psb;
    fin[1] = r1[0] + r1[1] + r1[2] + r1[3] + psb;
    fin[2] = r2[0] + r2[1] + r2[2] + r2[3];
  }
  __syncthreads();
  const float s_off = fin[0], s_diag = fin[1], sent = fin[2];
  if (tid < 129) {
    float v;
    if (tid == 128) v = sent;
    else {
      v = (tid == t) ? s_diag : s_off;
      if (src_mask[b * 128 + tid] == 0) v = NEGV;
    }
    out0[(size_t)bt * 129 + tid] = v;
  }
}

// ---------------- launch ----------------
extern "C" void kernel_launch(void* const* d_in, const int* in_sizes, int n_in,
                              void* d_out, int out_size, void* d_ws, size_t ws_size,
                              hipStream_t stream) {
  const int* src_ids   = (const int*)d_in[0];
  const int* src_mask  = (const int*)d_in[1];
  const int* cmask     = (const int*)d_in[2];
  const float* emb     = (const float*)d_in[3];
  const float* Wih_f   = (const float*)d_in[4];
  const float* Whh_f   = (const float*)d_in[5];
  const float* b_f     = (const float*)d_in[6];
  const float* Wih_b   = (const float*)d_in[7];
  const float* Whh_b   = (const float*)d_in[8];
  const float* b_b     = (const float*)d_in[9];
  const float* Wih_d   = (const float*)d_in[10];
  const float* Whh_d   = (const float*)d_in[11];
  const float* b_d     = (const float*)d_in[12];
  const float* W1      = (const float*)d_in[13];
  const float* W2      = (const float*)d_in[14];
  const float* v_att   = (const float*)d_in[15];
  const float* comb_W  = (const float*)d_in[16];
  const float* comb_b  = (const float*)d_in[17];
  const float* vocab_W = (const float*)d_in[18];
  const float* vocab_b = (const float*)d_in[19];
  const float* Wg_W    = (const float*)d_in[20];
  const float* Wg_b    = (const float*)d_in[21];
  const float* ptr_W   = (const float*)d_in[22];
  const float* ptr_b   = (const float*)d_in[23];
  const float* ps_W    = (const float*)d_in[24];
  const float* ps_b    = (const float*)d_in[25];
  (void)in_sizes; (void)n_in; (void)out_size; (void)ws_size;

  char* wsb = (char*)d_ws;
  size_t o = 0;
  auto alloc = [&](size_t bytes) { char* p = wsb + o; o = (o + bytes + 255) & ~(size_t)255; return p; };
  __hip_bfloat16* xb      = (__hip_bfloat16*)alloc((size_t)BN_ * E_ * 2);
  __hip_bfloat16* xproj16 = (__hip_bfloat16*)alloc((size_t)3 * BN_ * 2048 * 2);
  __hip_bfloat16* ehsb    = (__hip_bfloat16*)alloc((size_t)BN_ * 1024 * 2);
  __hip_bfloat16* ehsT    = (__hip_bfloat16*)alloc((size_t)16 * 1024 * 128 * 2);
  __hip_bfloat16* catb    = (__hip_bfloat16*)alloc((size_t)BN_ * 1536 * 2);
  float* dterm            = (float*)alloc((size_t)BN_ * 512 * 4);
  __hip_bfloat16* etT     = (__hip_bfloat16*)alloc((size_t)16 * 512 * 128 * 2);
  __hip_bfloat16* alphab  = (__hip_bfloat16*)alloc((size_t)BN_ * 128 * 2);
  __hip_bfloat16* combb   = (__hip_bfloat16*)alloc((size_t)BN_ * 512 * 2);
  float* wgout            = (float*)alloc((size_t)BN_ * 512 * 4);
  float* baseb            = (float*)alloc((size_t)BN_ * 128 * 4);
  __hip_bfloat16* hbuf    = (__hip_bfloat16*)alloc((size_t)3 * 128 * 8192 * 2);
  __hip_bfloat16* wihf16  = (__hip_bfloat16*)alloc((size_t)2048 * 384 * 2);
  __hip_bfloat16* wihb16  = (__hip_bfloat16*)alloc((size_t)2048 * 384 * 2);
  __hip_bfloat16* wihd16  = (__hip_bfloat16*)alloc((size_t)2048 * 384 * 2);
  __hip_bfloat16* whh16   = (__hip_bfloat16*)alloc((size_t)3 * 2048 * 512 * 2);
  __hip_bfloat16* w1_16   = (__hip_bfloat16*)alloc((size_t)512 * 512 * 2);
  __hip_bfloat16* w2_16   = (__hip_bfloat16*)alloc((size_t)512 * 1024 * 2);
  __hip_bfloat16* combw16 = (__hip_bfloat16*)alloc((size_t)512 * 1536 * 2);
  __hip_bfloat16* vocw16  = (__hip_bfloat16*)alloc((size_t)8000 * 512 * 2);
  __hip_bfloat16* wgw16   = (__hip_bfloat16*)alloc((size_t)512 * 512 * 2);
  __hip_bfloat16* ptrw16  = (__hip_bfloat16*)alloc((size_t)128 * 512 * 2);

  float* out0 = (float*)d_out;
  float* out1 = out0 + (size_t)BN_ * 129;

  // sentinel-init per-step h buffers (0x7f7f bf16 ~ 6.7e38; |h|<1 never hits it)
  hipError_t e0 = hipMemsetAsync(hbuf, 0x7f, (size_t)3 * 128 * 8192 * 2, stream);
  (void)e0;
  embed_kernel<<<BN_, 256, 0, stream>>>(src_ids, emb, xb);

  CastArgs ca;
  const float* srcs[12] = {Wih_f, Wih_b, Wih_d, Whh_f, Whh_b, Whh_d,
                           W1, W2, comb_W, vocab_W, Wg_W, ptr_W};
  __hip_bfloat16* dsts[12] = {wihf16, wihb16, wihd16, whh16, whh16 + 2048 * 512,
                              whh16 + 2 * 2048 * 512, w1_16, w2_16, combw16,
                              vocw16, wgw16, ptrw16};
  int ns[12] = {2048 * 384, 2048 * 384, 2048 * 384, 2048 * 512, 2048 * 512,
                2048 * 512, 512 * 512, 512 * 1024, 512 * 1536, 8000 * 512,
                512 * 512, 128 * 512};
  int acc = 0;
  for (int k = 0; k < 12; ++k) {
    ca.s[k] = srcs[k];
    ca.d[k] = (unsigned long long)dsts[k];
    ca.base[k] = acc;
    acc += ns[k];
  }
  ca.total = acc;
  cast_kernel<<<2048, 256, 0, stream>>>(ca);

  // input projections (bias folded), bf16 out
  bgemm_kernel<0, false, 0><<<dim3(16, 16), 256, 0, stream>>>(
      xb, E_, wihf16, E_, b_f, nullptr, 0, xproj16, 2048, BN_, 2048, E_, nullptr, 0, 0, 0, 0);
  bgemm_kernel<0, false, 0><<<dim3(16, 16), 256, 0, stream>>>(
      xb, E_, wihb16, E_, b_b, nullptr, 0, xproj16 + (size_t)BN_ * 2048, 2048, BN_, 2048, E_, nullptr, 0, 0, 0, 0);
  bgemm_kernel<0, false, 0><<<dim3(16, 16), 256, 0, stream>>>(
      xb, E_, wihd16, E_, b_d, nullptr, 0, xproj16 + (size_t)2 * BN_ * 2048, 2048, BN_, 2048, E_, nullptr, 0, 0, 0, 0);

  hipError_t e1 = hipFuncSetAttribute((const void*)lstm_kernel,
                      hipFuncAttributeMaxDynamicSharedMemorySize, 82432);
  (void)e1;
  lstm_kernel<<<96, 256, 82432, stream>>>(xproj16, whh16, hbuf);

  scatter_kernel<<<384, 256, 0, stream>>>(hbuf, ehsb, ehsT, catb);

  // dterm = dec_h @ W1^T (f32) ; etT = transposed bf16 eterm
  bgemm_kernel<0, false, 0><<<dim3(4, 16), 256, 0, stream>>>(
      catb, 1536, w1_16, 512, nullptr, dterm, 512, nullptr, 0, BN_, 512, 512, nullptr, 0, 0, 0, 0);
  bgemm_kernel<0, false, 1><<<dim3(4, 16), 256, 0, stream>>>(
      ehsb, 1024, w2_16, 1024, nullptr, nullptr, 0, etT, 0, BN_, 512, 1024, nullptr, 0, 0, 0, 0);

  score_kernel<<<BN_, 256, 0, stream>>>(dterm, etT, v_att, src_mask, alphab);

  // context = alpha[b] @ ehsT[b]^T -> catb[:,512:1536] (batched over b)
  bgemm_kernel<0, false, 0><<<dim3(8, 1, 16), 256, 0, stream>>>(
      alphab, 128, ehsT, 128, nullptr, nullptr, 0, catb + 512, 1536,
      128, 1024, 128, nullptr, 0, 128 * 128, 1024 * 128, 128 * 1536);

  // combined = tanh(cat @ comb_W^T + comb_b) -> bf16
  bgemm_kernel<1, false, 0><<<dim3(4, 16), 256, 0, stream>>>(
      catb, 1536, combw16, 1536, comb_b, nullptr, 0, combb, 512, BN_, 512, 1536, nullptr, 0, 0, 0, 0);

  // vocab logits + confusionset mask
  bgemm_kernel<0, true, 0><<<dim3(63, 16), 256, 0, stream>>>(
      combb, 512, vocw16, 512, vocab_b, out1, V_, nullptr, 0, BN_, V_, 512, cmask, V_, 0, 0, 0);

  // wgout = tanh(comb @ Wg^T + b)
  bgemm_kernel<1, false, 0><<<dim3(4, 16), 256, 0, stream>>>(
      combb, 512, wgw16, 512, Wg_b, wgout, 512, nullptr, 0, BN_, 512, 512, nullptr, 0, 0, 0, 0);

  // base = comb @ ptr_W[:,:512]^T + ptr_b
  bgemm_kernel<0, false, 0><<<dim3(1, 16), 256, 0, stream>>>(
      combb, 512, ptrw16, 512, ptr_b, baseb, 128, nullptr, 0, BN_, 128, 512, nullptr, 0, 0, 0, 0);

  pointer_kernel<<<BN_, 256, 0, stream>>>(baseb, wgout, ptr_W, ps_W, ps_b, src_mask, out0);
}

// Round 8
// 657.719 us; speedup vs baseline: 3.5558x; 1.0576x over previous
//
#include <hip/hip_runtime.h>
#include <hip/hip_bf16.h>
#include <math.h>

#define NEGV -1000000000.0f

static constexpr int B_ = 16, N_ = 128, BN_ = 2048;
static constexpr int E_ = 384, V_ = 8000;

typedef __attribute__((ext_vector_type(8))) short short8v;
typedef __attribute__((ext_vector_type(4))) float f32x4;

// ---------------- helpers ----------------
__device__ inline float wave_sum(float v) {
#pragma unroll
  for (int o = 32; o; o >>= 1) v += __shfl_xor(v, o);
  return v;
}
__device__ inline float wave_max(float v) {
#pragma unroll
  for (int o = 32; o; o >>= 1) v = fmaxf(v, __shfl_xor(v, o));
  return v;
}
__device__ inline float fast_tanh(float x) {
  return 1.f - 2.f / (1.f + __expf(2.f * x));
}
__device__ inline float fast_sig(float x) {
  return 1.f / (1.f + __expf(-x));
}
__device__ inline int ok16(const f32x4& f) {
  const unsigned a = __builtin_bit_cast(unsigned, f[0]);
  const unsigned b = __builtin_bit_cast(unsigned, f[1]);
  const unsigned c = __builtin_bit_cast(unsigned, f[2]);
  const unsigned d = __builtin_bit_cast(unsigned, f[3]);
  int r = 1;
  r &= ((a & 0xffffu) != 0x7f7fu) & ((a >> 16) != 0x7f7fu);
  r &= ((b & 0xffffu) != 0x7f7fu) & ((b >> 16) != 0x7f7fu);
  r &= ((c & 0xffffu) != 0x7f7fu) & ((c >> 16) != 0x7f7fu);
  r &= ((d & 0xffffu) != 0x7f7fu) & ((d >> 16) != 0x7f7fu);
  return r;
}
__device__ __forceinline__ void gl16(const void* g, void* l) {
  __builtin_amdgcn_global_load_lds((const __attribute__((address_space(1))) void*)g,
                                   (__attribute__((address_space(3))) void*)l, 16, 0, 0);
}

// ---------------- embedding gather -> bf16 ----------------
__global__ __launch_bounds__(256) void embed_kernel(
    const int* __restrict__ ids, const float* __restrict__ emb,
    __hip_bfloat16* __restrict__ xb) {
  const int row = blockIdx.x;
  const int id = ids[row];
  for (int e = threadIdx.x; e < E_; e += 256)
    xb[(size_t)row * E_ + e] = __float2bfloat16(emb[(size_t)id * E_ + e]);
}

// ---------------- multi-segment fp32 -> bf16 cast ----------------
struct CastArgs {
  const float* s[12];
  unsigned long long d[12];
  int base[12];
  int total;
};
__global__ __launch_bounds__(256) void cast_kernel(CastArgs a) {
  const int nq = a.total >> 2;
  for (int q = blockIdx.x * 256 + threadIdx.x; q < nq; q += gridDim.x * 256) {
    const int e = q << 2;
    int k = 11;
    while (e < a.base[k]) --k;
    const int i = e - a.base[k];
    __hip_bfloat16* dst = (__hip_bfloat16*)a.d[k] + i;
    if (k == 11) {  // ptr_W: pack [128][513] cols 0..511 -> [128][512]
      const int row = i >> 9, col = i & 511;
      const float* sp = a.s[k] + (size_t)row * 513 + col;
#pragma unroll
      for (int u = 0; u < 4; ++u) dst[u] = __float2bfloat16(sp[u]);
    } else {
      float4 v = *(const float4*)(a.s[k] + i);
      __hip_bfloat16 h0 = __float2bfloat16(v.x), h1 = __float2bfloat16(v.y);
      __hip_bfloat16 h2 = __float2bfloat16(v.z), h3 = __float2bfloat16(v.w);
      ushort4 u4 = {*(unsigned short*)&h0, *(unsigned short*)&h1,
                    *(unsigned short*)&h2, *(unsigned short*)&h3};
      *(ushort4*)dst = u4;
    }
  }
}

// ---------------- 128x128-tile bf16 MFMA GEMM (big GEMMs) ----------------
template <int ACT, bool MASK>
__global__ __launch_bounds__(256) void bgemm_kernel(
    const __hip_bfloat16* __restrict__ A, int lda,
    const __hip_bfloat16* __restrict__ W, int ldw,
    const float* __restrict__ bias,
    float* __restrict__ C, int ldc,
    __hip_bfloat16* __restrict__ Cb, int ldcb,
    int M, int N, int K,
    const int* __restrict__ mask, int ldm) {
  __shared__ __hip_bfloat16 Al[2][4096];
  __shared__ __hip_bfloat16 Bl[2][4096];
  const int tid = threadIdx.x;
  const int wid = tid >> 6, lane = tid & 63;
  const int m0 = blockIdx.y * 128, n0 = blockIdx.x * 128;
  const int nkt = K >> 5;
  const int rm = (wid >> 1) << 6, rn = (wid & 1) << 6;
  const int lrow = lane & 15, kq = lane >> 4;
  const int fs = ((lrow >> 1) & 3) << 4;

  f32x4 acc[4][4];
#pragma unroll
  for (int i = 0; i < 4; ++i)
#pragma unroll
    for (int j = 0; j < 4; ++j) acc[i][j] = {0.f, 0.f, 0.f, 0.f};

  auto stage = [&](int bi, int kt) {
#pragma unroll
    for (int c = 0; c < 2; ++c) {
      const int p = ((c * 4 + wid) << 6) + lane;
      const int row = p >> 2, cb = (p & 3) << 4;
      const int sw = ((row >> 1) & 3) << 4;
      const unsigned loff = (unsigned)__builtin_amdgcn_readfirstlane((c * 4 + wid) << 10);
      {
        const char* src = (const char*)A + ((size_t)(m0 + row) * lda + (size_t)kt * 32) * 2 + (cb ^ sw);
        gl16(src, (char*)&Al[bi][0] + loff);
      }
      {
        int gr = n0 + row;
        if (gr >= N) gr = N - 1;
        const char* src = (const char*)W + ((size_t)gr * ldw + (size_t)kt * 32) * 2 + (cb ^ sw);
        gl16(src, (char*)&Bl[bi][0] + loff);
      }
    }
  };
  auto compute = [&](int bi) {
    const char* Ab = (const char*)&Al[bi][0];
    const char* Bb = (const char*)&Bl[bi][0];
    const int roff = (kq << 4) ^ fs;
    short8v a[4], b[4];
#pragma unroll
    for (int i = 0; i < 4; ++i)
      a[i] = *(const short8v*)(Ab + (rm + i * 16 + lrow) * 64 + roff);
#pragma unroll
    for (int j = 0; j < 4; ++j)
      b[j] = *(const short8v*)(Bb + (rn + j * 16 + lrow) * 64 + roff);
#pragma unroll
    for (int i = 0; i < 4; ++i)
#pragma unroll
      for (int j = 0; j < 4; ++j)
        acc[i][j] = __builtin_amdgcn_mfma_f32_16x16x32_bf16(a[i], b[j], acc[i][j], 0, 0, 0);
  };

  stage(0, 0);
  for (int kt = 0; kt < nkt; ++kt) {
    __syncthreads();
    if (kt + 1 < nkt) stage((kt + 1) & 1, kt + 1);
    compute(kt & 1);
  }

#pragma unroll
  for (int i = 0; i < 4; ++i) {
#pragma unroll
    for (int r = 0; r < 4; ++r) {
      const int m = m0 + rm + i * 16 + kq * 4 + r;
#pragma unroll
      for (int j = 0; j < 4; ++j) {
        const int n = n0 + rn + j * 16 + lrow;
        if (n < N) {
          float v = acc[i][j][r] + (bias ? bias[n] : 0.f);
          if (ACT == 1) v = tanhf(v);
          if (MASK) {
            if (mask[(size_t)m * ldm + n] == 0) v = NEGV;
          }
          if (C) C[(size_t)m * ldc + n] = v;
          if (Cb) Cb[(size_t)m * ldcb + n] = __float2bfloat16(v);
        }
      }
    }
  }
}

// ---------------- 64x64-tile bf16 MFMA GEMM (small/medium GEMMs) ----------------
// TROUT: 0 normal, 1 etT transposed-out, 2 split wg(tanh,f32)/base(raw,f32)
template <int ACT, int TROUT>
__global__ __launch_bounds__(256) void bgemm64_kernel(
    const __hip_bfloat16* __restrict__ A, int lda,
    const __hip_bfloat16* __restrict__ W, int ldw,
    const float* __restrict__ bias, const float* __restrict__ bias2,
    float* __restrict__ C, int ldc, float* __restrict__ C2,
    __hip_bfloat16* __restrict__ Cb, int ldcb,
    int M, int N, int K,
    long aBs, long wBs, long cBs) {
  __shared__ __hip_bfloat16 Al[2][2048];
  __shared__ __hip_bfloat16 Bl[2][2048];
  A += (size_t)blockIdx.z * aBs;
  W += (size_t)blockIdx.z * wBs;
  const int tid = threadIdx.x;
  const int wid = tid >> 6, lane = tid & 63;
  const int m0 = blockIdx.y * 64, n0 = blockIdx.x * 64;
  const int nkt = K >> 5;
  const int rm = (wid >> 1) << 5, rn = (wid & 1) << 5;
  const int lrow = lane & 15, kq = lane >> 4;
  const int fs = ((lrow >> 1) & 3) << 4;

  f32x4 acc[2][2];
#pragma unroll
  for (int i = 0; i < 2; ++i)
#pragma unroll
    for (int j = 0; j < 2; ++j) acc[i][j] = {0.f, 0.f, 0.f, 0.f};

  auto stage = [&](int bi, int kt) {
    const int p = tid;
    const int row = p >> 2, cb = (p & 3) << 4;
    const int sw = ((row >> 1) & 3) << 4;
    const unsigned loff = (unsigned)__builtin_amdgcn_readfirstlane(wid << 10);
    {
      const char* src = (const char*)A + ((size_t)(m0 + row) * lda + (size_t)kt * 32) * 2 + (cb ^ sw);
      gl16(src, (char*)&Al[bi][0] + loff);
    }
    {
      const char* src = (const char*)W + ((size_t)(n0 + row) * ldw + (size_t)kt * 32) * 2 + (cb ^ sw);
      gl16(src, (char*)&Bl[bi][0] + loff);
    }
  };
  auto compute = [&](int bi) {
    const char* Ab = (const char*)&Al[bi][0];
    const char* Bb = (const char*)&Bl[bi][0];
    const int roff = (kq << 4) ^ fs;
    short8v a[2], b[2];
#pragma unroll
    for (int i = 0; i < 2; ++i)
      a[i] = *(const short8v*)(Ab + (rm + i * 16 + lrow) * 64 + roff);
#pragma unroll
    for (int j = 0; j < 2; ++j)
      b[j] = *(const short8v*)(Bb + (rn + j * 16 + lrow) * 64 + roff);
#pragma unroll
    for (int i = 0; i < 2; ++i)
#pragma unroll
      for (int j = 0; j < 2; ++j)
        acc[i][j] = __builtin_amdgcn_mfma_f32_16x16x32_bf16(a[i], b[j], acc[i][j], 0, 0, 0);
  };

  stage(0, 0);
  for (int kt = 0; kt < nkt; ++kt) {
    __syncthreads();
    if (kt + 1 < nkt) stage((kt + 1) & 1, kt + 1);
    compute(kt & 1);
  }

#pragma unroll
  for (int i = 0; i < 2; ++i) {
#pragma unroll
    for (int r = 0; r < 4; ++r) {
      const int m = m0 + rm + i * 16 + kq * 4 + r;
#pragma unroll
      for (int j = 0; j < 2; ++j) {
        const int n = n0 + rn + j * 16 + lrow;
        float v = acc[i][j][r];
        if (TROUT == 2) {
          if (n < 512) {
            C[(size_t)m * ldc + n] = tanhf(v + bias[n]);
          } else {
            C2[(size_t)m * 128 + (n - 512)] = v + bias2[n - 512];
          }
        } else {
          v += (bias ? bias[n] : 0.f);
          if (ACT == 1) v = tanhf(v);
          if (TROUT == 1) {
            Cb[(((size_t)(m >> 7) * 512 + n) << 7) + (m & 127)] = __float2bfloat16(v);
          } else {
            if (C) C[(size_t)m * ldc + n] = v;
            if (Cb) Cb[(size_t)m * ldcb + n + (size_t)blockIdx.z * cBs] = __float2bfloat16(v);
          }
        }
      }
    }
  }
}

// ---------------- fused 3-LSTM recurrence ----------------
// grid 96 = 3 lstm x 32 slices. Single-RT poll: each thread loads its whole
// 64B line (4x dwordx4, one vmcnt) and checks ALL 32 shorts vs sentinel
// (tear-proof; |h|<1 so 0x7f7f impossible). 2 barriers/step.
// dyn LDS: W 64KB + h 16KB + hout 512B = 82432 B.
__global__ __launch_bounds__(256) void lstm_kernel(
    const __hip_bfloat16* __restrict__ xp16,   // [3][2048][2048]
    const __hip_bfloat16* __restrict__ whh16,  // [3][2048][512]
    __hip_bfloat16* __restrict__ hbuf) {       // [3][128][32][16b][16d]
  const int l = blockIdx.x >> 5, g = blockIdx.x & 31;
  const int tid = threadIdx.x, lane = tid & 63, wid = tid >> 6;
  extern __shared__ char sm[];
  char* smW = sm;                                   // 65536
  char* smH = sm + 65536;                           // 16384
  __hip_bfloat16* hout = (__hip_bfloat16*)(sm + 65536 + 16384);  // 512

  // load weights, reordered dim-major: LDS row lr = d_local*4 + gate
  const __hip_bfloat16* wsrc = whh16 + (size_t)l * 2048 * 512;
  for (int p = tid; p < 4096; p += 256) {
    const int r = p >> 6, cb = (p & 63) << 4;
    const int grow = (r & 3) * 512 + (g << 4) + (r >> 2);
    float4 v = *(const float4*)((const char*)(wsrc + (size_t)grow * 512) + cb);
    *(float4*)(smW + r * 1024 + (cb ^ ((r & 7) << 4))) = v;
  }

  const int lrow = lane & 15, kq = lane >> 4;
  const int swz = (lrow & 7) << 4;
  const char* aB = smW + (wid * 16 + lrow) * 1024;
  const char* bB = smH + lrow * 1024;
  const int dl16 = wid * 4 + kq;   // this lane's dim within block
  const int dg = (g << 4) + dl16;  // global dim
  const int bb = lrow;             // this lane's batch
  const bool rev = (l == 1);
  const __hip_bfloat16* xl = xp16 + (size_t)l * 2048 * 2048;
  __hip_bfloat16* hb_l = hbuf + (size_t)l * 128 * 8192;
  // staging geometry: this thread owns one 64B line of the 16KB h image
  const int gq = tid >> 3;            // source block g' of my line
  const int b0 = (tid & 7) * 2;       // first of 2 batches in my line
  const int gb = gq * 32;             // byte offset of d0 within batch row
  const int sw0 = (b0 & 7) << 4, sw1 = ((b0 + 1) & 7) << 4;
  float c = 0.f;

  for (int s = 0; s < 128; ++s) {
    const int t = rev ? 127 - s : s;
    const size_t xro = (size_t)(bb * 128 + t) * 2048 + dg;
    const float xgi = __bfloat162float(xl[xro]);
    const float xgf = __bfloat162float(xl[xro + 512]);
    const float xgg = __bfloat162float(xl[xro + 1024]);
    const float xgo = __bfloat162float(xl[xro + 1536]);

    if (s > 0) {
      if (gq != g) {  // own region injected directly last step
        const char* hsrc = (const char*)(hb_l + (size_t)(s - 1) * 8192);
        const unsigned loff = (unsigned)(tid * 64);
        f32x4 q0, q1, q2, q3;
        while (true) {
          asm volatile(
              "global_load_dwordx4 %0, %4, %5 sc0 sc1\n\t"
              "global_load_dwordx4 %1, %4, %5 offset:16 sc0 sc1\n\t"
              "global_load_dwordx4 %2, %4, %5 offset:32 sc0 sc1\n\t"
              "global_load_dwordx4 %3, %4, %5 offset:48 sc0 sc1\n\t"
              "s_waitcnt vmcnt(0)"
              : "=&v"(q0), "=&v"(q1), "=&v"(q2), "=&v"(q3)
              : "v"(loff), "s"(hsrc)
              : "memory");
          if (ok16(q0) & ok16(q1) & ok16(q2) & ok16(q3)) break;
          __builtin_amdgcn_s_sleep(1);
        }
        *(f32x4*)(smH + b0 * 1024 + (gb ^ sw0)) = q0;
        *(f32x4*)(smH + b0 * 1024 + ((gb + 16) ^ sw0)) = q1;
        *(f32x4*)(smH + (b0 + 1) * 1024 + (gb ^ sw1)) = q2;
        *(f32x4*)(smH + (b0 + 1) * 1024 + ((gb + 16) ^ sw1)) = q3;
      }
    } else {
      const f32x4 z = {0.f, 0.f, 0.f, 0.f};
      *(f32x4*)(smH + b0 * 1024 + (gb ^ sw0)) = z;
      *(f32x4*)(smH + b0 * 1024 + ((gb + 16) ^ sw0)) = z;
      *(f32x4*)(smH + (b0 + 1) * 1024 + (gb ^ sw1)) = z;
      *(f32x4*)(smH + (b0 + 1) * 1024 + ((gb + 16) ^ sw1)) = z;
    }
    __syncthreads();  // A: smH fully staged (incl. prev-step inject)

    f32x4 acc0 = {0.f, 0.f, 0.f, 0.f}, acc1 = {0.f, 0.f, 0.f, 0.f};
#pragma unroll
    for (int kt = 0; kt < 16; kt += 2) {
      const int off0 = ((kt * 64 + (kq << 4)) ^ swz);
      const int off1 = (((kt + 1) * 64 + (kq << 4)) ^ swz);
      short8v a0 = *(const short8v*)(aB + off0);
      short8v b0v = *(const short8v*)(bB + off0);
      short8v a1 = *(const short8v*)(aB + off1);
      short8v b1v = *(const short8v*)(bB + off1);
      acc0 = __builtin_amdgcn_mfma_f32_16x16x32_bf16(a0, b0v, acc0, 0, 0, 0);
      acc1 = __builtin_amdgcn_mfma_f32_16x16x32_bf16(a1, b1v, acc1, 0, 0, 0);
    }
    const f32x4 acc = acc0 + acc1;  // acc[r] = gate r for (dg, bb)

    const float gi = acc[0] + xgi;
    const float gf = acc[1] + xgf;
    const float gg = acc[2] + xgg;
    const float go = acc[3] + xgo;
    c = fmaf(fast_sig(gf), c, fast_sig(gi) * fast_tanh(gg));
    const float h = fast_sig(go) * fast_tanh(c);
    __hip_bfloat16 hb16 = __float2bfloat16(h);
    const unsigned short hraw = *(unsigned short*)&hb16;
    hout[bb * 16 + dl16] = hb16;  // pack for wave0 burst
    __syncthreads();  // B: all MFMA reads done + hout complete
    // direct LDS inject of own region for next step (safe after B)
    *(unsigned short*)(smH + bb * 1024 +
                       ((((g << 4) + dl16) * 2) ^ ((bb & 7) << 4))) = hraw;
    if (tid < 32) {
      f32x4 hv4 = *(const f32x4*)((const char*)hout + tid * 16);
      char* hdst = (char*)(hb_l + (size_t)s * 8192);
      asm volatile("global_store_dwordx4 %0, %1, %2 sc0 sc1"
                   :: "v"((unsigned)((g << 9) + tid * 16)), "v"(hv4), "s"(hdst)
                   : "memory");
    }
    // no drain: store ack folds into next step's spin vmcnt
  }
}

// ---------------- scatter: hbuf -> ehsb / ehsT / catb ----------------
__global__ __launch_bounds__(256) void scatter_kernel(
    const __hip_bfloat16* __restrict__ hbuf,
    __hip_bfloat16* __restrict__ ehsb, __hip_bfloat16* __restrict__ ehsT,
    __hip_bfloat16* __restrict__ catb) {
  const int bid = blockIdx.x;
  const int l = bid >> 7, b = (bid >> 3) & 15, dgrp = bid & 7;
  const int tid = threadIdx.x;
  __shared__ unsigned short tile[64][130];
  const int t4 = tid >> 6, dl = tid & 63;
  const bool rev = (l == 1);
  const char* hb = (const char*)(hbuf + (size_t)l * 128 * 8192);
  const unsigned lineoff = (unsigned)((dgrp * 4 + (dl >> 4)) * 512 + b * 32 + (dl & 15) * 2);
  for (int u = 0; u < 8; ++u) {
    const int tbase = t4 * 4 + u * 16;
    unsigned o[4];
#pragma unroll
    for (int w = 0; w < 4; ++w) {
      const int t = tbase + w;
      const int s = rev ? 127 - t : t;
      o[w] = (unsigned)(s * 16384) + lineoff;
    }
    unsigned h0, h1, h2, h3;
    asm volatile(
        "global_load_ushort %0, %4, %8 sc0 sc1\n\t"
        "global_load_ushort %1, %5, %8 sc0 sc1\n\t"
        "global_load_ushort %2, %6, %8 sc0 sc1\n\t"
        "global_load_ushort %3, %7, %8 sc0 sc1\n\t"
        "s_waitcnt vmcnt(0)"
        : "=&v"(h0), "=&v"(h1), "=&v"(h2), "=&v"(h3)
        : "v"(o[0]), "v"(o[1]), "v"(o[2]), "v"(o[3]), "s"(hb)
        : "memory");
    tile[dl][tbase] = (unsigned short)h0;
    tile[dl][tbase + 1] = (unsigned short)h1;
    tile[dl][tbase + 2] = (unsigned short)h2;
    tile[dl][tbase + 3] = (unsigned short)h3;
  }
  __syncthreads();
  if (l < 2) {
    const int r = tid >> 2, seg = tid & 3;
    ushort4* dstT = (ushort4*)(ehsT + ((size_t)b * 1024 + l * 512 + dgrp * 64 + r) * 128 + seg * 32);
    const unsigned short* srcT = &tile[r][seg * 32];
#pragma unroll
    for (int q = 0; q < 8; ++q) dstT[q] = *(const ushort4*)(srcT + q * 4);
    const int t2 = tid >> 1, half = tid & 1;
    unsigned short buf[32];
#pragma unroll
    for (int q = 0; q < 32; ++q) buf[q] = tile[half * 32 + q][t2];
    ushort4* dstB = (ushort4*)(ehsb + ((size_t)(b * 128 + t2)) * 1024 + l * 512 + dgrp * 64 + half * 32);
#pragma unroll
    for (int q = 0; q < 8; ++q) dstB[q] = *(const ushort4*)(buf + q * 4);
  } else {
    const int t2 = tid >> 1, half = tid & 1;
    unsigned short buf[32];
#pragma unroll
    for (int q = 0; q < 32; ++q) buf[q] = tile[half * 32 + q][t2];
    ushort4* dstB = (ushort4*)(catb + ((size_t)(b * 128 + t2)) * 1536 + dgrp * 64 + half * 32);
#pragma unroll
    for (int q = 0; q < 8; ++q) dstB[q] = *(const ushort4*)(buf + q * 4);
  }
}

// ---------------- score + softmax -> alpha; 4 t's per block ----------------
__global__ __launch_bounds__(256) void score_kernel(
    const float* __restrict__ dterm, const __hip_bfloat16* __restrict__ etT,
    const float* __restrict__ v_att, const int* __restrict__ src_mask,
    __hip_bfloat16* __restrict__ alphab) {
  const int b = blockIdx.x >> 5, tg = blockIdx.x & 31;
  const int t0 = tg * 4;
  const int tid = threadIdx.x;
  __shared__ float dt[4][512], vs[512], red[4][4][128], al[4][128];
  for (int i = tid; i < 2048; i += 256)
    dt[i >> 9][i & 511] = dterm[((size_t)(b * 128 + t0 + (i >> 9))) * 512 + (i & 511)];
  vs[tid] = v_att[tid];
  vs[tid + 256] = v_att[256 + tid];
  __syncthreads();
  const int n0 = (tid & 63) << 1, ah = tid >> 6;
  {
    const __hip_bfloat16* ep = etT + (((size_t)b * 512 + ah * 128) << 7) + n0;
    const float* vp = vs + ah * 128;
    const float* dp0 = &dt[0][ah * 128];
    const float* dp1 = &dt[1][ah * 128];
    const float* dp2 = &dt[2][ah * 128];
    const float* dp3 = &dt[3][ah * 128];
    float p00 = 0, p01 = 0, p10 = 0, p11 = 0, p20 = 0, p21 = 0, p30 = 0, p31 = 0;
    for (int a = 0; a < 128; ++a) {
      const unsigned u = *(const unsigned*)(ep + ((size_t)a << 7));
      unsigned u0 = u << 16, u1 = u & 0xffff0000u;
      const float e0 = __builtin_bit_cast(float, u0);
      const float e1 = __builtin_bit_cast(float, u1);
      const float va = vp[a];
      p00 = fmaf(va, fast_tanh(dp0[a] + e0), p00);
      p01 = fmaf(va, fast_tanh(dp0[a] + e1), p01);
      p10 = fmaf(va, fast_tanh(dp1[a] + e0), p10);
      p11 = fmaf(va, fast_tanh(dp1[a] + e1), p11);
      p20 = fmaf(va, fast_tanh(dp2[a] + e0), p20);
      p21 = fmaf(va, fast_tanh(dp2[a] + e1), p21);
      p30 = fmaf(va, fast_tanh(dp3[a] + e0), p30);
      p31 = fmaf(va, fast_tanh(dp3[a] + e1), p31);
    }
    red[0][ah][n0] = p00; red[0][ah][n0 + 1] = p01;
    red[1][ah][n0] = p10; red[1][ah][n0 + 1] = p11;
    red[2][ah][n0] = p20; red[2][ah][n0 + 1] = p21;
    red[3][ah][n0] = p30; red[3][ah][n0 + 1] = p31;
  }
  __syncthreads();
#pragma unroll
  for (int tp = 0; tp < 2; ++tp) {
    const int tt = tp * 2 + (tid >> 7);
    const int n = tid & 127;
    float sc = red[tt][0][n] + red[tt][1][n] + red[tt][2][n] + red[tt][3][n];
    if (src_mask[b * 128 + n] == 0) sc = NEGV;
    al[tt][n] = sc;
  }
  __syncthreads();
  {
    const int tt = tid >> 6, lane = tid & 63;
    const float v0 = al[tt][lane], v1 = al[tt][lane + 64];
    const float m = wave_max(fmaxf(v0, v1));
    const float e0 = __expf(v0 - m), e1 = __expf(v1 - m);
    const float inv = 1.f / wave_sum(e0 + e1);
    __hip_bfloat16* ap = alphab + ((size_t)(b * 128 + t0 + tt)) * 128;
    ap[lane] = __float2bfloat16(e0 * inv);
    ap[lane + 64] = __float2bfloat16(e1 * inv);
  }
}

// ---------------- pointer head assembly ----------------
__global__ __launch_bounds__(256) void pointer_kernel(
    const float* __restrict__ base, const float* __restrict__ wgout,
    const float* __restrict__ ptr_W, const float* __restrict__ ps_W,
    const float* __restrict__ ps_b, const int* __restrict__ src_mask,
    float* __restrict__ out0) {
  const int bt = blockIdx.x;
  const int b = bt >> 7, t = bt & 127;
  const int tid = threadIdx.x;
  __shared__ float r0[4], r1[4], r2[4], fin[3];
  float off_p = 0.f, diag_p = 0.f, sent_p;
  if (tid < 128) {
    const float ba = base[(size_t)bt * 128 + tid];
    const float pw = ps_W[tid];
    off_p = tanhf(ba) * pw;
    diag_p = tanhf(ba + ptr_W[tid * 513 + 512]) * pw;
  }
  sent_p = wgout[(size_t)bt * 512 + tid] + wgout[(size_t)bt * 512 + 256 + tid];
  off_p = wave_sum(off_p);
  diag_p = wave_sum(diag_p);
  sent_p = wave_sum(sent_p);
  const int wid = tid >> 6, lane = tid & 63;
  if (lane == 0) { r0[wid] = off_p; r1[wid] = diag_p; r2[wid] = sent_p; }
  __syncthreads();
  if (tid == 0) {
    const float psb = ps_b[0];
    fin[0] = r0[0] + r0[1] + r0[2] + r0[3] + psb;
    fin[1] = r1[0] + r1[1] + r1[2] + r1[3] + psb;
    fin[2] = r2[0] + r2[1] + r2[2] + r2[3];
  }
  __syncthreads();
  const float s_off = fin[0], s_diag = fin[1], sent = fin[2];
  if (tid < 129) {
    float v;
    if (tid == 128) v = sent;
    else {
      v = (tid == t) ? s_diag : s_off;
      if (src_mask[b * 128 + tid] == 0) v = NEGV;
    }
    out0[(size_t)bt * 129 + tid] = v;
  }
}

// ---------------- launch ----------------
extern "C" void kernel_launch(void* const* d_in, const int* in_sizes, int n_in,
                              void* d_out, int out_size, void* d_ws, size_t ws_size,
                              hipStream_t stream) {
  const int* src_ids   = (const int*)d_in[0];
  const int* src_mask  = (const int*)d_in[1];
  const int* cmask     = (const int*)d_in[2];
  const float* emb     = (const float*)d_in[3];
  const float* Wih_f   = (const float*)d_in[4];
  const float* Whh_f   = (const float*)d_in[5];
  const float* b_f     = (const float*)d_in[6];
  const float* Wih_b   = (const float*)d_in[7];
  const float* Whh_b   = (const float*)d_in[8];
  const float* b_b     = (const float*)d_in[9];
  const float* Wih_d   = (const float*)d_in[10];
  const float* Whh_d   = (const float*)d_in[11];
  const float* b_d     = (const float*)d_in[12];
  const float* W1      = (const float*)d_in[13];
  const float* W2      = (const float*)d_in[14];
  const float* v_att   = (const float*)d_in[15];
  const float* comb_W  = (const float*)d_in[16];
  const float* comb_b  = (const float*)d_in[17];
  const float* vocab_W = (const float*)d_in[18];
  const float* vocab_b = (const float*)d_in[19];
  const float* Wg_W    = (const float*)d_in[20];
  const float* Wg_b    = (const float*)d_in[21];
  const float* ptr_W   = (const float*)d_in[22];
  const float* ptr_b   = (const float*)d_in[23];
  const float* ps_W    = (const float*)d_in[24];
  const float* ps_b    = (const float*)d_in[25];
  (void)in_sizes; (void)n_in; (void)out_size; (void)ws_size;

  char* wsb = (char*)d_ws;
  size_t o = 0;
  auto alloc = [&](size_t bytes) { char* p = wsb + o; o = (o + bytes + 255) & ~(size_t)255; return p; };
  __hip_bfloat16* xb      = (__hip_bfloat16*)alloc((size_t)BN_ * E_ * 2);
  __hip_bfloat16* xproj16 = (__hip_bfloat16*)alloc((size_t)3 * BN_ * 2048 * 2);
  __hip_bfloat16* ehsb    = (__hip_bfloat16*)alloc((size_t)BN_ * 1024 * 2);
  __hip_bfloat16* ehsT    = (__hip_bfloat16*)alloc((size_t)16 * 1024 * 128 * 2);
  __hip_bfloat16* catb    = (__hip_bfloat16*)alloc((size_t)BN_ * 1536 * 2);
  float* dterm            = (float*)alloc((size_t)BN_ * 512 * 4);
  __hip_bfloat16* etT     = (__hip_bfloat16*)alloc((size_t)16 * 512 * 128 * 2);
  __hip_bfloat16* alphab  = (__hip_bfloat16*)alloc((size_t)BN_ * 128 * 2);
  __hip_bfloat16* combb   = (__hip_bfloat16*)alloc((size_t)BN_ * 512 * 2);
  float* wgout            = (float*)alloc((size_t)BN_ * 512 * 4);
  float* baseb            = (float*)alloc((size_t)BN_ * 128 * 4);
  __hip_bfloat16* hbuf    = (__hip_bfloat16*)alloc((size_t)3 * 128 * 8192 * 2);
  __hip_bfloat16* wihf16  = (__hip_bfloat16*)alloc((size_t)2048 * 384 * 2);
  __hip_bfloat16* wihb16  = (__hip_bfloat16*)alloc((size_t)2048 * 384 * 2);
  __hip_bfloat16* wihd16  = (__hip_bfloat16*)alloc((size_t)2048 * 384 * 2);
  __hip_bfloat16* whh16   = (__hip_bfloat16*)alloc((size_t)3 * 2048 * 512 * 2);
  __hip_bfloat16* w1_16   = (__hip_bfloat16*)alloc((size_t)512 * 512 * 2);
  __hip_bfloat16* w2_16   = (__hip_bfloat16*)alloc((size_t)512 * 1024 * 2);
  __hip_bfloat16* combw16 = (__hip_bfloat16*)alloc((size_t)512 * 1536 * 2);
  __hip_bfloat16* vocw16  = (__hip_bfloat16*)alloc((size_t)8000 * 512 * 2);
  __hip_bfloat16* wgw16   = (__hip_bfloat16*)alloc((size_t)512 * 512 * 2);   // 640x512 with ptrw16
  __hip_bfloat16* ptrw16  = (__hip_bfloat16*)alloc((size_t)128 * 512 * 2);   // contiguous after wgw16

  float* out0 = (float*)d_out;
  float* out1 = out0 + (size_t)BN_ * 129;

  // sentinel-init per-step h buffers (0x7f7f bf16 ~ 6.7e38; |h|<1 never hits it)
  hipError_t e0 = hipMemsetAsync(hbuf, 0x7f, (size_t)3 * 128 * 8192 * 2, stream);
  (void)e0;
  embed_kernel<<<BN_, 256, 0, stream>>>(src_ids, emb, xb);

  CastArgs ca;
  const float* srcs[12] = {Wih_f, Wih_b, Wih_d, Whh_f, Whh_b, Whh_d,
                           W1, W2, comb_W, vocab_W, Wg_W, ptr_W};
  __hip_bfloat16* dsts[12] = {wihf16, wihb16, wihd16, whh16, whh16 + 2048 * 512,
                              whh16 + 2 * 2048 * 512, w1_16, w2_16, combw16,
                              vocw16, wgw16, ptrw16};
  int ns[12] = {2048 * 384, 2048 * 384, 2048 * 384, 2048 * 512, 2048 * 512,
                2048 * 512, 512 * 512, 512 * 1024, 512 * 1536, 8000 * 512,
                512 * 512, 128 * 512};
  int acc = 0;
  for (int k = 0; k < 12; ++k) {
    ca.s[k] = srcs[k];
    ca.d[k] = (unsigned long long)dsts[k];
    ca.base[k] = acc;
    acc += ns[k];
  }
  ca.total = acc;
  cast_kernel<<<2048, 256, 0, stream>>>(ca);

  // input projections (bias folded), bf16 out — 128-tile, grid 256 blocks each
  bgemm_kernel<0, false><<<dim3(16, 16), 256, 0, stream>>>(
      xb, E_, wihf16, E_, b_f, nullptr, 0, xproj16, 2048, BN_, 2048, E_, nullptr, 0);
  bgemm_kernel<0, false><<<dim3(16, 16), 256, 0, stream>>>(
      xb, E_, wihb16, E_, b_b, nullptr, 0, xproj16 + (size_t)BN_ * 2048, 2048, BN_, 2048, E_, nullptr, 0);
  bgemm_kernel<0, false><<<dim3(16, 16), 256, 0, stream>>>(
      xb, E_, wihd16, E_, b_d, nullptr, 0, xproj16 + (size_t)2 * BN_ * 2048, 2048, BN_, 2048, E_, nullptr, 0);

  hipError_t e1 = hipFuncSetAttribute((const void*)lstm_kernel,
                      hipFuncAttributeMaxDynamicSharedMemorySize, 82432);
  (void)e1;
  lstm_kernel<<<96, 256, 82432, stream>>>(xproj16, whh16, hbuf);

  scatter_kernel<<<384, 256, 0, stream>>>(hbuf, ehsb, ehsT, catb);

  // dterm = dec_h @ W1^T (f32) ; etT = transposed bf16 eterm — 64-tile
  bgemm64_kernel<0, 0><<<dim3(8, 32), 256, 0, stream>>>(
      catb, 1536, w1_16, 512, nullptr, nullptr, dterm, 512, nullptr, nullptr, 0,
      BN_, 512, 512, 0, 0, 0);
  bgemm64_kernel<0, 1><<<dim3(8, 32), 256, 0, stream>>>(
      ehsb, 1024, w2_16, 1024, nullptr, nullptr, nullptr, 0, nullptr, etT, 0,
      BN_, 512, 1024, 0, 0, 0);

  score_kernel<<<16 * 32, 256, 0, stream>>>(dterm, etT, v_att, src_mask, alphab);

  // context = alpha[b] @ ehsT[b]^T -> catb[:,512:1536] (batched over b, 64-tile)
  bgemm64_kernel<0, 0><<<dim3(16, 2, 16), 256, 0, stream>>>(
      alphab, 128, ehsT, 128, nullptr, nullptr, nullptr, 0, nullptr,
      catb + 512, 1536, 128, 1024, 128, 128 * 128, 1024 * 128, 128 * 1536);

  // combined = tanh(cat @ comb_W^T + comb_b) -> bf16 (64-tile)
  bgemm64_kernel<1, 0><<<dim3(8, 32), 256, 0, stream>>>(
      catb, 1536, combw16, 1536, comb_b, nullptr, nullptr, 0, nullptr,
      combb, 512, BN_, 512, 1536, 0, 0, 0);

  // vocab logits + confusionset mask (128-tile)
  bgemm_kernel<0, true><<<dim3(63, 16), 256, 0, stream>>>(
      combb, 512, vocw16, 512, vocab_b, out1, V_, nullptr, 0, BN_, V_, 512, cmask, V_);

  // fused: wgout = tanh(comb @ Wg^T + b) [cols 0-511] ; base = comb @ ptrW^T + ptr_b [cols 512-639]
  bgemm64_kernel<0, 2><<<dim3(10, 32), 256, 0, stream>>>(
      combb, 512, wgw16, 512, Wg_b, ptr_b, wgout, 512, baseb, nullptr, 0,
      BN_, 640, 512, 0, 0, 0);

  pointer_kernel<<<BN_, 256, 0, stream>>>(baseb, wgout, ptr_W, ps_W, ps_b, src_mask, out0);
}